// Round 5
// baseline (1690.655 us; speedup 1.0000x reference)
//
#include <hip/hip_runtime.h>
#include <hip/hip_bf16.h>
#include <math.h>

// LinearAttentionLayerOptimized: B=4, T=2048, C=1024, H=16, N=64, L=128, E=1228
// Round 4: 1024-thread recurrence (16 waves), staggered segments, fused/batched GEMM
//          prologue (z-batched folds/transposes/stage2), a/d in bf16, ws ~225MB.

#define BB 4
#define TT 2048
#define CC 1024
#define HH 16
#define NN 64
#define LL 128
#define EE 1228
#define EPAD 1280
#define MM (BB*TT)          // 8192 rows
#define TCH 32
#define NSEG 4
#define WARMCH 4            // 128 warm-up steps; decay<=0.82 -> ~1e-11
#define DECAY_C_F 0.7408182206817179f

typedef __attribute__((ext_vector_type(8))) short s16x8;
typedef __attribute__((ext_vector_type(4))) float f32x4;

#define GLOAD_LDS16(gp, lp) \
    __builtin_amdgcn_global_load_lds((const __attribute__((address_space(1))) void*)(gp), \
                                     (__attribute__((address_space(3))) void*)(lp), 16, 0, 0)

// ---------------- z-batched two-pass bias folds ----------------
__global__ __launch_bounds__(256) void fold_pass1_z(
    const float* __restrict__ mu0, const float* __restrict__ mu1, const float* __restrict__ mu2,
    const float* __restrict__ W0,  const float* __restrict__ W1_, const float* __restrict__ W2_,
    float* __restrict__ partial, int ldW, int E, int ldP, int pslice) {
    const float* mu = blockIdx.z == 0 ? mu0 : (blockIdx.z == 1 ? mu1 : mu2);
    const float* W  = blockIdx.z == 0 ? W0  : (blockIdx.z == 1 ? W1_ : W2_);
    partial += (size_t)blockIdx.z * pslice;
    const int l = threadIdx.x & 63;
    const int e = blockIdx.x * 64 + l;
    const int pg = threadIdx.x >> 6;
    const int c0 = blockIdx.y * 64;
    float s = 0.f;
    if (e < E)
        for (int c = c0 + pg; c < c0 + 64; c += 4) s += mu[c] * W[(size_t)c * ldW + e];
    __shared__ float red[4][64];
    red[pg][l] = s;
    __syncthreads();
    if (pg == 0 && e < E)
        partial[(size_t)blockIdx.y * ldP + e] = red[0][l] + red[1][l] + red[2][l] + red[3][l];
}

__global__ void fold_pass2_z(const float* __restrict__ partial,
                             const float* b0, const float* b1, const float* b2,
                             float* __restrict__ outv,
                             int P, int ldP, int pslice, int E, int Epad, int oslice) {
    const float* bias = blockIdx.z == 0 ? b0 : (blockIdx.z == 1 ? b1 : b2);
    partial += (size_t)blockIdx.z * pslice;
    outv    += (size_t)blockIdx.z * oslice;
    int e = blockIdx.x * blockDim.x + threadIdx.x;
    if (e >= Epad) return;
    float s = 0.f;
    if (e < E) {
        s = bias ? bias[e] : 0.f;
        for (int p = 0; p < P; ++p) s += partial[(size_t)p * ldP + e];
    }
    outv[e] = s;
}

// ---------------- cast / z-batched transpose-cast ----------------
__global__ void cast_f32_bf16(const float* __restrict__ in, __hip_bfloat16* __restrict__ out, int n4) {
    int i = blockIdx.x * blockDim.x + threadIdx.x;
    if (i >= n4) return;
    float4 v = ((const float4*)in)[i];
    __hip_bfloat16 o[4] = {__float2bfloat16(v.x), __float2bfloat16(v.y),
                           __float2bfloat16(v.z), __float2bfloat16(v.w)};
    *(ulong1*)&out[i * 4] = *(ulong1*)o;
}

__global__ void transpose_cast_z(const float* s0, const float* s1, const float* s2,
                                 __hip_bfloat16* __restrict__ outT, size_t dslice,
                                 int Rin, int Cin, int Rpad, int Cpad) {
    const float* in = blockIdx.z == 0 ? s0 : (blockIdx.z == 1 ? s1 : s2);
    outT += (size_t)blockIdx.z * dslice;
    __shared__ float t[32][33];
    const int r0 = blockIdx.x * 32, c0 = blockIdx.y * 32;
    const int tx = threadIdx.x, ty = threadIdx.y;   // 32 x 8
    #pragma unroll
    for (int j = 0; j < 4; ++j) {
        int r = r0 + ty + j * 8, c = c0 + tx;
        t[ty + j * 8][tx] = (r < Rin && c < Cin) ? in[(size_t)r * Cin + c] : 0.f;
    }
    __syncthreads();
    #pragma unroll
    for (int j = 0; j < 4; ++j) {
        int c = c0 + ty + j * 8, r = r0 + tx;
        if (c < Cpad && r < Rpad) outT[(size_t)c * Rpad + r] = __float2bfloat16(t[tx][ty + j * 8]);
    }
}

// ---------------- bf16 MFMA GEMM (z-batched) ----------------
// C[M,N] = act(A[M,K] @ Bt[N,K]^T + bias[N]); z-offsets in ELEMENTS applied per blockIdx.z.
template<int ACT, int OBF, int PADZ>
__global__ __launch_bounds__(256) void gemm_mfma(const __hip_bfloat16* __restrict__ A,
                                                 const __hip_bfloat16* __restrict__ Bt,
                                                 const float* __restrict__ bias,
                                                 void* __restrict__ Cptr,
                                                 int M, int N, int K,
                                                 int ldA, int ldB, int ldC,
                                                 size_t zA, size_t zB, size_t zBias, size_t zC) {
    __shared__ __hip_bfloat16 As[128 * 32];
    __shared__ __hip_bfloat16 Bs[128 * 32];
    const int tid = threadIdx.x;
    const int wid = tid >> 6, lane = tid & 63;
    const int wm = wid >> 1, wn = wid & 1;
    const int bm = blockIdx.y * 128, bn = blockIdx.x * 128;
    A  += (size_t)blockIdx.z * zA;
    Bt += (size_t)blockIdx.z * zB;
    if (bias) bias += (size_t)blockIdx.z * zBias;
    const size_t zc = (size_t)blockIdx.z * zC;

    const __hip_bfloat16* srcA[2];
    const __hip_bfloat16* srcB[2];
    #pragma unroll
    for (int i = 0; i < 2; ++i) {
        int off = (wid * 2 + i) * 1024 + lane * 16;
        int r = off >> 6;
        int c = (off >> 4) & 3;
        int cs = c ^ ((r >> 1) & 3);
        srcA[i] = A  + (size_t)(bm + r) * ldA + cs * 8;
        srcB[i] = Bt + (size_t)(bn + r) * ldB + cs * 8;
    }

    f32x4 acc[4][4];
    #pragma unroll
    for (int i = 0; i < 4; ++i)
        #pragma unroll
        for (int j = 0; j < 4; ++j) acc[i][j] = (f32x4){0.f, 0.f, 0.f, 0.f};

    for (int k0 = 0; k0 < K; k0 += 32) {
        #pragma unroll
        for (int i = 0; i < 2; ++i) {
            GLOAD_LDS16(srcA[i] + k0, (char*)As + (wid * 2 + i) * 1024);
            GLOAD_LDS16(srcB[i] + k0, (char*)Bs + (wid * 2 + i) * 1024);
        }
        __syncthreads();
        s16x8 af[4], bfr[4];
        #pragma unroll
        for (int mi = 0; mi < 4; ++mi) {
            int r = wm * 64 + mi * 16 + (lane & 15);
            int c = (lane >> 4) ^ ((r >> 1) & 3);
            af[mi] = *(const s16x8*)((const char*)As + r * 64 + c * 16);
        }
        #pragma unroll
        for (int ni = 0; ni < 4; ++ni) {
            int r = wn * 64 + ni * 16 + (lane & 15);
            int c = (lane >> 4) ^ ((r >> 1) & 3);
            bfr[ni] = *(const s16x8*)((const char*)Bs + r * 64 + c * 16);
        }
        #pragma unroll
        for (int mi = 0; mi < 4; ++mi)
            #pragma unroll
            for (int ni = 0; ni < 4; ++ni)
                acc[mi][ni] = __builtin_amdgcn_mfma_f32_16x16x32_bf16(af[mi], bfr[ni], acc[mi][ni], 0, 0, 0);
        __syncthreads();
    }

    #pragma unroll
    for (int ni = 0; ni < 4; ++ni) {
        const int col = bn + wn * 64 + ni * 16 + (lane & 15);
        const bool valid = (col < N);
        const float bc = (valid && bias) ? bias[col] : 0.f;
        #pragma unroll
        for (int mi = 0; mi < 4; ++mi) {
            #pragma unroll
            for (int reg = 0; reg < 4; ++reg) {
                const int row = bm + wm * 64 + mi * 16 + (lane >> 4) * 4 + reg;
                float y = 0.f;
                if (valid) {
                    float x = acc[mi][ni][reg] + bc;
                    if (ACT == 1)      y = 0.5f * x * (1.0f + erff(x * 0.7071067811865475f));
                    else if (ACT == 2) y = 1.0f / (1.0f + expf(-x));
                    else if (ACT == 3) { float sg = 1.0f / (1.0f + expf(-tanhf(x))); y = expf(-DECAY_C_F * sg); }
                    else               y = x;
                }
                if (valid || PADZ) {
                    if (OBF) ((__hip_bfloat16*)Cptr)[zc + (size_t)row * ldC + col] = __float2bfloat16(y);
                    else     ((float*)Cptr)[zc + (size_t)row * ldC + col] = y;
                }
            }
        }
    }
}

// ---------------- segment-parallel chunked recurrence (1024 threads, 16 waves) ----------------
#define NW 16
#define P_T0(i,j)   pool[0     + (i)*68 + (j)]
#define P_WT(i,j)   pool[4352  + (i)*68 + (j)]
#define P_KP(i,j)   pool[6528  + (i)*68 + (j)]
#define P_P2t(i,j)  pool[6528  + (i)*36 + (j)]   // aliases KP (dead after phase2)
#define P_NU(i,j)   pool[8704  + (i)*68 + (j)]
#define P_GRt(i,j)  pool[8704  + (i)*36 + (j)]   // aliases NU (dead after phase2)
#define P_RKM(i,j)  pool[10880 + (i)*68 + (j)]
#define P_RRM(i,j)  pool[13056 + (i)*68 + (j)]
#define P_GM(i,j)   pool[15232 + (i)*68 + (j)]
#define P_GMT(i,j)  pool[17408 + (i)*36 + (j)]
#define P_KPT(i,j)  pool[19712 + (i)*36 + (j)]
#define P_NUT(i,j)  pool[22016 + (i)*36 + (j)]
#define P_RKMT(i,j) pool[24320 + (i)*36 + (j)]
#define P_DCT(i,j)  pool[26624 + (i)*36 + (j)]
#define P_AT(i,j)   pool[28928 + (i)*36 + (j)]
#define P_BM(i,j)   pool[30080 + (i)*36 + (j)]
#define P_SEG(i,j)  pool[31232 + (i)*64 + (j)]
#define LD4(expr)   (*(const float4*)&(expr))

__global__ __launch_bounds__(1024, 4) void recurrence_chunked(
    const float* __restrict__ kbuf, const __hip_bfloat16* __restrict__ iclr,
    const __hip_bfloat16* __restrict__ dbuf, const float* __restrict__ vbuf,
    const float* __restrict__ rbuf,
    const float* __restrict__ rem_mult, const float* __restrict__ iclr_mix,
    const float* __restrict__ bonus_mult, float* __restrict__ outb) {
    __shared__ float pool[31488];   // 123 KB
    const int bh = blockIdx.x & 63, seg = blockIdx.x >> 6;
    const int b = bh >> 4, h = bh & 15;
    const int tid = threadIdx.x, lane = tid & 63, wid = tid >> 6;
    const size_t gbase = ((size_t)b * TT) * CC + (size_t)h * NN;

    for (int i = tid; i < 4352; i += 1024) pool[i] = 0.f;   // T0 = 0 at segment start
    const int c0 = tid & 63;
    const float remc = rem_mult[h * NN + c0];
    const float mixc = iclr_mix[h * NN + c0];
    __syncthreads();

    // staggered segments: lengths {19,15,15,15}; warm-up 4 chunks for seg>0 -> 19 chunks/block
    const int cout0 = (seg == 0) ? 0 : 19 + (seg - 1) * 15;
    const int ce    = cout0 + ((seg == 0) ? 19 : 15);
    const int cb    = (seg == 0) ? 0 : cout0 - WARMCH;

    for (int chk = cb; chk < ce; ++chk) {
        const bool emit = (chk >= cout0);
        const int tg0 = chk * TCH;
        // ---- load & elementwise ----
        #pragma unroll
        for (int i = 0; i < 2; ++i) {
            int idx = tid + 1024 * i;
            int t = idx >> 6, c = idx & 63;
            size_t off = gbase + (size_t)(tg0 + t) * CC + c;
            float kx = kbuf[off];
            float ax = __bfloat162float(iclr[off]);
            float rk = kx * (1.f + (ax - 1.f) * mixc);
            P_WT(t, c) = ax;
            P_KP(t, c) = kx * remc;
            P_RKM(t, c) = rk; P_RKMT(c, t) = rk;
            P_NU(t, c) = vbuf[off];
            if (emit) P_RRM(t, c) = rbuf[off];
            P_DCT(c, t) = __bfloat162float(dbuf[off]);
        }
        __syncthreads();
        // ---- row norms: 32 rows over 16 waves ----
        #pragma unroll
        for (int rr = 0; rr < 2; ++rr) {
            int t = wid + rr * 16;
            float v = P_KP(t, lane);
            float ss = v * v;
            #pragma unroll
            for (int s = 32; s; s >>= 1) ss += __shfl_xor(ss, s);
            float kn = v / fmaxf(sqrtf(ss), 1e-12f);
            P_KP(t, lane) = kn;
            P_WT(t, lane) = P_WT(t, lane) * kn;
        }
        __syncthreads();
        // ---- segmented cumprod + scaled quantities (256 threads) ----
        float lc[8];
        int ccs = tid & 63, sgm = (tid >> 6) & 3, t0s = sgm * 8;
        if (tid < 256) {
            float pp = 1.f;
            #pragma unroll
            for (int j = 0; j < 8; ++j) { pp *= P_DCT(ccs, t0s + j); lc[j] = pp; }
            P_SEG(sgm, ccs) = pp;
        }
        __syncthreads();
        if (tid < 256) {
            float m = 1.f;
            for (int s = 0; s < sgm; ++s) m *= P_SEG(s, ccs);
            float dcprev = m;
            #pragma unroll
            for (int j = 0; j < 8; ++j) {
                int t = t0s + j;
                float dcur = m * lc[j];
                P_WT(t, ccs) *= dcprev;
                float inv = 1.f / dcur;
                float kap = P_KP(t, ccs) * inv; P_KP(t, ccs) = kap; P_KPT(ccs, t) = kap;
                float nu  = P_NU(t, ccs) * inv; P_NU(t, ccs) = nu;  P_NUT(ccs, t) = nu;
                P_DCT(ccs, t) = dcur;
                dcprev = dcur;
            }
        }
        __syncthreads();
        // ---- phase2: AT, BM, WT.T0 -> GM (64 tiles over 16 waves) ----
        for (int tile = wid; tile < 64; tile += NW) {
            if (tile < 16) {
                int s = (tile >> 2) * 8 + (lane >> 3), t = (tile & 3) * 8 + (lane & 7);
                float acc = 0.f;
                #pragma unroll
                for (int kc = 0; kc < 16; ++kc) {
                    float4 a = LD4(P_KP(s, kc * 4));
                    float4 bb = LD4(P_WT(t, kc * 4));
                    acc += a.x * bb.x + a.y * bb.y + a.z * bb.z + a.w * bb.w;
                }
                P_AT(s, t) = (s < t) ? acc : 0.f;
            } else if (tile < 32) {
                int t = ((tile - 16) >> 2) * 8 + (lane >> 3), s = ((tile - 16) & 3) * 8 + (lane & 7);
                float acc = 0.f;
                #pragma unroll
                for (int kc = 0; kc < 16; ++kc) {
                    float4 a = LD4(P_WT(t, kc * 4));
                    float4 bb = LD4(P_NU(s, kc * 4));
                    acc += a.x * bb.x + a.y * bb.y + a.z * bb.z + a.w * bb.w;
                }
                P_BM(t, s) = (s < t) ? acc : 0.f;
            } else {
                int tt = tile - 32;
                int t = (tt >> 3) * 8 + (lane >> 3), q = (tt & 7) * 8 + (lane & 7);
                float acc = 0.f;
                #pragma unroll
                for (int j4 = 0; j4 < 16; ++j4) {
                    float4 a = LD4(P_WT(t, j4 * 4));
                    acc += a.x * P_T0(j4 * 4 + 0, q) + a.y * P_T0(j4 * 4 + 1, q)
                         + a.z * P_T0(j4 * 4 + 2, q) + a.w * P_T0(j4 * 4 + 3, q);
                }
                P_GM(t, q) = acc;
            }
        }
        __syncthreads();
        // ---- phase3: GM += BM . RKM (32 tiles) ----
        for (int tile = wid; tile < 32; tile += NW) {
            int t = (tile >> 3) * 8 + (lane >> 3), q = (tile & 7) * 8 + (lane & 7);
            float acc = 0.f;
            #pragma unroll
            for (int s4 = 0; s4 < 8; ++s4) {
                float4 a = LD4(P_BM(t, s4 * 4));
                acc += a.x * P_RKM(s4 * 4 + 0, q) + a.y * P_RKM(s4 * 4 + 1, q)
                     + a.z * P_RKM(s4 * 4 + 2, q) + a.w * P_RKM(s4 * 4 + 3, q);
            }
            P_GM(t, q) += acc;
        }
        __syncthreads();
        // ---- phase4: wave0 forward substitution || waves1-15: P2t (emit only) ----
        if (wid == 0) {
            float g[32];
            #pragma unroll
            for (int t = 0; t < 32; ++t) g[t] = P_GM(t, lane);
            #pragma unroll
            for (int s = 0; s < 31; ++s) {
                #pragma unroll
                for (int t = s + 1; t < 32; ++t) g[t] -= P_AT(s, t) * g[s];
            }
            #pragma unroll
            for (int t = 0; t < 32; ++t) { P_GM(t, lane) = g[t]; P_GMT(lane, t) = g[t]; }
        } else if (emit) {
            for (int tile = wid - 1; tile < 16; tile += (NW - 1)) {
                int t = (tile >> 2) * 8 + (lane >> 3), s = (tile & 3) * 8 + (lane & 7);
                float acc = 0.f;
                #pragma unroll
                for (int kc = 0; kc < 16; ++kc) {
                    float4 a = LD4(P_RRM(t, kc * 4));
                    float4 bb = LD4(P_RKM(s, kc * 4));
                    acc += a.x * bb.x + a.y * bb.y + a.z * bb.z + a.w * bb.w;
                }
                P_P2t(t, s) = (s <= t) ? acc : 0.f;
            }
        }
        __syncthreads();
        if (emit) {
            // ---- phase5: GRt[t][s] = g_s . r_t (16 tiles) ----
            for (int tile = wid; tile < 16; tile += NW) {
                int t = (tile >> 2) * 8 + (lane >> 3), s = (tile & 3) * 8 + (lane & 7);
                float acc = 0.f;
                #pragma unroll
                for (int kc = 0; kc < 16; ++kc) {
                    float4 a = LD4(P_RRM(t, kc * 4));
                    float4 bb = LD4(P_GM(s, kc * 4));
                    acc += a.x * bb.x + a.y * bb.y + a.z * bb.z + a.w * bb.w;
                }
                P_GRt(t, s) = (s <= t) ? acc : 0.f;
            }
            __syncthreads();
            // ---- phase6a: outputs (32 tiles) ----
            for (int tile = wid; tile < 32; tile += NW) {
                int i = (tile >> 2) * 8 + (lane >> 3), t = (tile & 3) * 8 + (lane & 7);
                float a1 = 0.f, a2 = 0.f, a3 = 0.f;
                #pragma unroll
                for (int j4 = 0; j4 < 16; ++j4) {
                    float4 a = LD4(P_T0(i, j4 * 4));
                    float4 bb = LD4(P_RRM(t, j4 * 4));
                    a1 += a.x * bb.x + a.y * bb.y + a.z * bb.z + a.w * bb.w;
                }
                #pragma unroll
                for (int s4 = 0; s4 < 8; ++s4) {
                    float4 a = LD4(P_NUT(i, s4 * 4));
                    float4 bb = LD4(P_P2t(t, s4 * 4));
                    a2 += a.x * bb.x + a.y * bb.y + a.z * bb.z + a.w * bb.w;
                    float4 c = LD4(P_KPT(i, s4 * 4));
                    float4 d = LD4(P_GRt(t, s4 * 4));
                    a3 += c.x * d.x + c.y * d.y + c.z * d.z + c.w * d.w;
                }
                float diag = 0.2f * bonus_mult[h * NN + i] * P_NUT(i, t) * P_P2t(t, t);
                outb[gbase + (size_t)(tg0 + t) * CC + i] = P_DCT(i, t) * (a1 + a2 + diag - a3);
            }
            __syncthreads();
        }
        // ---- phase6b: T0 <- dc_end * (T0 - Kap^T G + Nu^T RK) (64 tiles) ----
        for (int tile = wid; tile < 64; tile += NW) {
            int pr = (tile >> 3) * 8 + (lane >> 3), q = (tile & 7) * 8 + (lane & 7);
            float a1 = 0.f, a2 = 0.f;
            #pragma unroll
            for (int s4 = 0; s4 < 8; ++s4) {
                float4 a = LD4(P_KPT(pr, s4 * 4));
                float4 bb = LD4(P_GMT(q, s4 * 4));
                a1 += a.x * bb.x + a.y * bb.y + a.z * bb.z + a.w * bb.w;
                float4 c = LD4(P_NUT(pr, s4 * 4));
                float4 d = LD4(P_RKMT(q, s4 * 4));
                a2 += c.x * d.x + c.y * d.y + c.z * d.z + c.w * d.w;
            }
            P_T0(pr, q) = P_DCT(pr, 31) * (P_T0(pr, q) - a1 + a2);
        }
        __syncthreads();
    }
}

// ---------------- LayerNorm * gate (bf16 out) ----------------
__global__ __launch_bounds__(256) void ln_gate_kernel(const float* __restrict__ x,
                                                      const __hip_bfloat16* __restrict__ gate,
                                                      const float* __restrict__ g,
                                                      const float* __restrict__ bv,
                                                      __hip_bfloat16* __restrict__ y) {
    const int row = blockIdx.x;
    const float* xr = x + (size_t)row * CC;
    float v[4];
    float s = 0.f;
    #pragma unroll
    for (int j = 0; j < 4; ++j) { v[j] = xr[threadIdx.x + 256 * j]; s += v[j]; }
    __shared__ float red[4], red2[4];
    #pragma unroll
    for (int o = 32; o; o >>= 1) s += __shfl_xor(s, o);
    if ((threadIdx.x & 63) == 0) red[threadIdx.x >> 6] = s;
    __syncthreads();
    const float mean = (red[0] + red[1] + red[2] + red[3]) * (1.f / CC);
    float vs = 0.f;
    #pragma unroll
    for (int j = 0; j < 4; ++j) { float d = v[j] - mean; vs += d * d; }
    #pragma unroll
    for (int o = 32; o; o >>= 1) vs += __shfl_xor(vs, o);
    if ((threadIdx.x & 63) == 0) red2[threadIdx.x >> 6] = vs;
    __syncthreads();
    const float var = (red2[0] + red2[1] + red2[2] + red2[3]) * (1.f / CC);
    const float rstd = rsqrtf(var + 1e-6f);
    #pragma unroll
    for (int j = 0; j < 4; ++j) {
        const int cc = threadIdx.x + 256 * j;
        float o_ = (v[j] - mean) * rstd * g[cc] + bv[cc];
        float gt = __bfloat162float(gate[(size_t)row * CC + cc]);
        y[(size_t)row * CC + cc] = __float2bfloat16(o_ * gt);
    }
}

// ---------------- launch ----------------
extern "C" void kernel_launch(void* const* d_in, const int* in_sizes, int n_in,
                              void* d_out, int out_size, void* d_ws, size_t ws_size,
                              hipStream_t stream) {
    const float* q        = (const float*)d_in[0];
    const float* mu_r     = (const float*)d_in[4];
    const float* mu_k     = (const float*)d_in[5];
    const float* mu_v     = (const float*)d_in[6];
    const float* mu_g     = (const float*)d_in[7];
    const float* mu_a     = (const float*)d_in[8];
    const float* mu_d     = (const float*)d_in[9];
    const float* dA       = (const float*)d_in[10];
    const float* dB       = (const float*)d_in[11];
    const float* db       = (const float*)d_in[12];
    const float* aA       = (const float*)d_in[13];
    const float* aB       = (const float*)d_in[14];
    const float* ab       = (const float*)d_in[15];
    const float* gA       = (const float*)d_in[16];
    const float* gB       = (const float*)d_in[17];
    const float* rW1      = (const float*)d_in[18];
    const float* rb1      = (const float*)d_in[19];
    const float* rW2      = (const float*)d_in[20];
    const float* rb2      = (const float*)d_in[21];
    const float* kW1      = (const float*)d_in[22];
    const float* kb1      = (const float*)d_in[23];
    const float* kW2      = (const float*)d_in[24];
    const float* kb2      = (const float*)d_in[25];
    const float* vW1      = (const float*)d_in[26];
    const float* vb1      = (const float*)d_in[27];
    const float* vW2      = (const float*)d_in[28];
    const float* vb2      = (const float*)d_in[29];
    const float* oW1      = (const float*)d_in[30];
    const float* ob1      = (const float*)d_in[31];
    const float* oW2      = (const float*)d_in[32];
    const float* ob2      = (const float*)d_in[33];
    const float* rem_mult = (const float*)d_in[34];
    const float* iclr_mix = (const float*)d_in[35];
    const float* bonus_mult = (const float*)d_in[36];
    const float* ln_g     = (const float*)d_in[37];
    const float* ln_b     = (const float*)d_in[38];
    float* out = (float*)d_out;

    // ---- workspace arena (~225 MB) ----
    char* p = (char*)d_ws;
    auto alloc = [&](size_t bytes) { char* r = p; p += (bytes + 255) & ~(size_t)255; return r; };
    float* fb_all  = (float*)alloc((size_t)3 * EPAD * 4);   // folded stage-1 biases r,k,v (pad-zeroed)
    float* c2_all  = (float*)alloc((size_t)3 * CC * 4);     // folded LoRA-B biases g,a,d
    float* lt_all  = (float*)alloc((size_t)3 * LL * 4);     // folded LoRA-A temps
    float* cb2_all = (float*)alloc((size_t)3 * CC * 4);     // rb2,kb2,vb2 gathered
    __hip_bfloat16* qb      = (__hip_bfloat16*)alloc((size_t)MM * CC * 2);       // q bf16; later ln_out
    __hip_bfloat16* W1T_all = (__hip_bfloat16*)alloc((size_t)3 * EPAD * CC * 2); // r,k,v W1^T
    __hip_bfloat16* W2T_all = (__hip_bfloat16*)alloc((size_t)3 * CC * EPAD * 2); // r,k,v W2^T
    __hip_bfloat16* Hb      = (__hip_bfloat16*)alloc((size_t)MM * 2 * EPAD * 2); // fused H (r,k); v reuses slice0
    float*          rkv     = (float*)alloc((size_t)3 * MM * CC * 4);            // r,k,v fp32
    __hip_bfloat16* abuf    = (__hip_bfloat16*)alloc((size_t)MM * CC * 2);       // iclr bf16
    __hip_bfloat16* dbuf    = (__hip_bfloat16*)alloc((size_t)MM * CC * 2);       // decay bf16
    __hip_bfloat16* gbuf    = (__hip_bfloat16*)alloc((size_t)MM * CC * 2);       // gate bf16
    float* rbuf = rkv;
    float* kbuf = rkv + (size_t)MM * CC;
    float* vbuf = rkv + (size_t)2 * MM * CC;
    // time-multiplexed tenants of the rkv arena:
    float*          pp      = rkv;                                         // fold partials (dies before transposes? no—before stage2; folds precede AT writes below)
    __hip_bfloat16* AT_all  = (__hip_bfloat16*)((char*)rkv + (1 << 18));   // LoRA A^T (after folds done with pp region? disjoint: pp=192KB < 256KB offset)
    __hip_bfloat16* BT_all  = (__hip_bfloat16*)((char*)rkv + (1 << 18) + 786432);
    __hip_bfloat16* oW1T    = (__hip_bfloat16*)rkv;                        // written after recurrence
    __hip_bfloat16* oW2T    = (__hip_bfloat16*)((char*)rkv + 4194304);
    __hip_bfloat16* tgad    = Hb;                                          // LoRA intermediates [M][384]

    const dim3 blk(256);
    const dim3 tblk(32, 8);

    // gather stage-2 biases (device-to-device, capture-safe)
    hipMemcpyAsync(cb2_all,          rb2, CC * 4, hipMemcpyDeviceToDevice, stream);
    hipMemcpyAsync(cb2_all + CC,     kb2, CC * 4, hipMemcpyDeviceToDevice, stream);
    hipMemcpyAsync(cb2_all + 2 * CC, vb2, CC * 4, hipMemcpyDeviceToDevice, stream);

    // ---- folds (use pp scratch inside rkv; must precede AT/BT transposes) ----
    fold_pass1_z<<<dim3(20, 16, 3), blk, 0, stream>>>(mu_r, mu_k, mu_v, rW1, kW1, vW1,
                                                      pp, EE, EE, EPAD, 16 * EPAD);
    fold_pass2_z<<<dim3(5, 1, 3), blk, 0, stream>>>(pp, rb1, kb1, vb1, fb_all,
                                                    16, EPAD, 16 * EPAD, EE, EPAD, EPAD);
    fold_pass1_z<<<dim3(2, 16, 3), blk, 0, stream>>>(mu_g, mu_a, mu_d, gA, aA, dA,
                                                     pp, LL, LL, EPAD, 16 * EPAD);
    fold_pass2_z<<<dim3(1, 1, 3), dim3(128), 0, stream>>>(pp, nullptr, nullptr, nullptr, lt_all,
                                                          16, EPAD, 16 * EPAD, LL, LL, LL);
    fold_pass1_z<<<dim3(16, 2, 3), blk, 0, stream>>>(lt_all, lt_all + LL, lt_all + 2 * LL, gB, aB, dB,
                                                     pp, CC, CC, EPAD, 16 * EPAD);
    fold_pass2_z<<<dim3(4, 1, 3), blk, 0, stream>>>(pp, nullptr, ab, db, c2_all,
                                                    2, EPAD, 16 * EPAD, CC, CC, CC);

    // ---- transposes (AT/BT land in rkv after pp is dead) ----
    transpose_cast_z<<<dim3(32, 40, 3), tblk, 0, stream>>>(rW1, kW1, vW1, W1T_all,
                                                           (size_t)EPAD * CC, CC, EE, CC, EPAD);
    transpose_cast_z<<<dim3(40, 32, 3), tblk, 0, stream>>>(rW2, kW2, vW2, W2T_all,
                                                           (size_t)CC * EPAD, EE, CC, EPAD, CC);
    transpose_cast_z<<<dim3(32, 4, 3), tblk, 0, stream>>>(gA, aA, dA, AT_all,
                                                          (size_t)LL * CC, CC, LL, CC, LL);
    transpose_cast_z<<<dim3(4, 32, 3), tblk, 0, stream>>>(gB, aB, dB, BT_all,
                                                          (size_t)CC * LL, LL, CC, LL, CC);

    // ---- cast q ----
    cast_f32_bf16<<<dim3(MM * CC / 4 / 256), blk, 0, stream>>>(q, qb, MM * CC / 4);

    // ---- LoRA A-stage fused (N=384) -> tgad (aliases Hb) ----
    gemm_mfma<0,1,0><<<dim3(3, 64, 1), blk, 0, stream>>>(qb, AT_all, nullptr, tgad,
                                                         MM, 384, CC, CC, CC, 384, 0, 0, 0, 0);
    // ---- LoRA B-stage: gate(sig,bf16), iclr(sig,bf16), decay(decay,bf16) ----
    gemm_mfma<2,1,0><<<dim3(8, 64, 1), blk, 0, stream>>>(tgad,       BT_all,               c2_all,          gbuf,
                                                         MM, CC, LL, 384, LL, CC, 0, 0, 0, 0);
    gemm_mfma<2,1,0><<<dim3(8, 64, 1), blk, 0, stream>>>(tgad + LL,  BT_all + (size_t)CC * LL,  c2_all + CC,     abuf,
                                                         MM, CC, LL, 384, LL, CC, 0, 0, 0, 0);
    gemm_mfma<3,1,0><<<dim3(8, 64, 1), blk, 0, stream>>>(tgad + 2 * LL, BT_all + (size_t)2 * CC * LL, c2_all + 2 * CC, dbuf,
                                                         MM, CC, LL, 384, LL, CC, 0, 0, 0, 0);

    // ---- MLP r,k fused stage-1 (N=2560), then z-batched stage-2 ----
    gemm_mfma<1,1,0><<<dim3(20, 64, 1), blk, 0, stream>>>(qb, W1T_all, fb_all, Hb,
                                                          MM, 2 * EPAD, CC, CC, CC, 2 * EPAD, 0, 0, 0, 0);
    gemm_mfma<0,0,0><<<dim3(8, 64, 2), blk, 0, stream>>>(Hb, W2T_all, cb2_all, rkv,
                                                         MM, CC, EPAD, 2 * EPAD, EPAD, CC,
                                                         EPAD, (size_t)CC * EPAD, CC, (size_t)MM * CC);
    // ---- MLP v: stage-1 into Hb slice0, stage-2 -> vbuf ----
    gemm_mfma<1,1,0><<<dim3(10, 64, 1), blk, 0, stream>>>(qb, W1T_all + (size_t)2 * EPAD * CC, fb_all + 2 * EPAD, Hb,
                                                          MM, EPAD, CC, CC, CC, EPAD, 0, 0, 0, 0);
    gemm_mfma<0,0,0><<<dim3(8, 64, 1), blk, 0, stream>>>(Hb, W2T_all + (size_t)2 * CC * EPAD, cb2_all + 2 * CC, vbuf,
                                                         MM, CC, EPAD, EPAD, EPAD, CC, 0, 0, 0, 0);

    // ---- recurrence (256 blocks x 1024 threads) -> d_out scratch ----
    recurrence_chunked<<<dim3(BB * HH * NSEG), dim3(1024), 0, stream>>>(
        kbuf, abuf, dbuf, vbuf, rbuf, rem_mult, iclr_mix, bonus_mult, out);

    // ---- o-weight transposes into rkv (r/k/v dead after recurrence) ----
    transpose_cast_z<<<dim3(32, 40, 1), tblk, 0, stream>>>(oW1, oW1, oW1, oW1T,
                                                           0, CC, EE, CC, EPAD);
    transpose_cast_z<<<dim3(40, 32, 1), tblk, 0, stream>>>(oW2, oW2, oW2, oW2T,
                                                           0, EE, CC, EPAD, CC);

    // ---- LN * gate -> qb (bf16) ----
    ln_gate_kernel<<<dim3(MM), blk, 0, stream>>>(out, gbuf, ln_g, ln_b, qb);

    // ---- output MLP ----
    gemm_mfma<1,1,1><<<dim3(10, 64, 1), blk, 0, stream>>>(qb, oW1T, ob1, Hb,
                                                          MM, EE, CC, CC, CC, EPAD, 0, 0, 0, 0);
    gemm_mfma<0,0,0><<<dim3(8, 64, 1), blk, 0, stream>>>(Hb, oW2T, ob2, out,
                                                         MM, CC, EPAD, EPAD, EPAD, CC, 0, 0, 0, 0);
}

// Round 6
// 1690.334 us; speedup vs baseline: 1.0002x; 1.0002x over previous
//
#include <hip/hip_runtime.h>
#include <hip/hip_bf16.h>
#include <math.h>

// LinearAttentionLayerOptimized: B=4, T=2048, C=1024, H=16, N=64, L=128, E=1228
// Round 5: fix round-4 spill regression. __launch_bounds__(1024, 1) so the
// allocator gets the full 128-VGPR budget of a single resident 16-wave block
// (round 4's (1024,4) drove it to 64 VGPRs -> g[32] spilled -> 2.3 GB scratch
// traffic). Everything else identical to round 4.

#define BB 4
#define TT 2048
#define CC 1024
#define HH 16
#define NN 64
#define LL 128
#define EE 1228
#define EPAD 1280
#define MM (BB*TT)          // 8192 rows
#define TCH 32
#define NSEG 4
#define WARMCH 4            // 128 warm-up steps; decay<=0.82 -> ~1e-11
#define DECAY_C_F 0.7408182206817179f

typedef __attribute__((ext_vector_type(8))) short s16x8;
typedef __attribute__((ext_vector_type(4))) float f32x4;

#define GLOAD_LDS16(gp, lp) \
    __builtin_amdgcn_global_load_lds((const __attribute__((address_space(1))) void*)(gp), \
                                     (__attribute__((address_space(3))) void*)(lp), 16, 0, 0)

// ---------------- z-batched two-pass bias folds ----------------
__global__ __launch_bounds__(256) void fold_pass1_z(
    const float* __restrict__ mu0, const float* __restrict__ mu1, const float* __restrict__ mu2,
    const float* __restrict__ W0,  const float* __restrict__ W1_, const float* __restrict__ W2_,
    float* __restrict__ partial, int ldW, int E, int ldP, int pslice) {
    const float* mu = blockIdx.z == 0 ? mu0 : (blockIdx.z == 1 ? mu1 : mu2);
    const float* W  = blockIdx.z == 0 ? W0  : (blockIdx.z == 1 ? W1_ : W2_);
    partial += (size_t)blockIdx.z * pslice;
    const int l = threadIdx.x & 63;
    const int e = blockIdx.x * 64 + l;
    const int pg = threadIdx.x >> 6;
    const int c0 = blockIdx.y * 64;
    float s = 0.f;
    if (e < E)
        for (int c = c0 + pg; c < c0 + 64; c += 4) s += mu[c] * W[(size_t)c * ldW + e];
    __shared__ float red[4][64];
    red[pg][l] = s;
    __syncthreads();
    if (pg == 0 && e < E)
        partial[(size_t)blockIdx.y * ldP + e] = red[0][l] + red[1][l] + red[2][l] + red[3][l];
}

__global__ void fold_pass2_z(const float* __restrict__ partial,
                             const float* b0, const float* b1, const float* b2,
                             float* __restrict__ outv,
                             int P, int ldP, int pslice, int E, int Epad, int oslice) {
    const float* bias = blockIdx.z == 0 ? b0 : (blockIdx.z == 1 ? b1 : b2);
    partial += (size_t)blockIdx.z * pslice;
    outv    += (size_t)blockIdx.z * oslice;
    int e = blockIdx.x * blockDim.x + threadIdx.x;
    if (e >= Epad) return;
    float s = 0.f;
    if (e < E) {
        s = bias ? bias[e] : 0.f;
        for (int p = 0; p < P; ++p) s += partial[(size_t)p * ldP + e];
    }
    outv[e] = s;
}

// ---------------- cast / z-batched transpose-cast ----------------
__global__ void cast_f32_bf16(const float* __restrict__ in, __hip_bfloat16* __restrict__ out, int n4) {
    int i = blockIdx.x * blockDim.x + threadIdx.x;
    if (i >= n4) return;
    float4 v = ((const float4*)in)[i];
    __hip_bfloat16 o[4] = {__float2bfloat16(v.x), __float2bfloat16(v.y),
                           __float2bfloat16(v.z), __float2bfloat16(v.w)};
    *(ulong1*)&out[i * 4] = *(ulong1*)o;
}

__global__ void transpose_cast_z(const float* s0, const float* s1, const float* s2,
                                 __hip_bfloat16* __restrict__ outT, size_t dslice,
                                 int Rin, int Cin, int Rpad, int Cpad) {
    const float* in = blockIdx.z == 0 ? s0 : (blockIdx.z == 1 ? s1 : s2);
    outT += (size_t)blockIdx.z * dslice;
    __shared__ float t[32][33];
    const int r0 = blockIdx.x * 32, c0 = blockIdx.y * 32;
    const int tx = threadIdx.x, ty = threadIdx.y;   // 32 x 8
    #pragma unroll
    for (int j = 0; j < 4; ++j) {
        int r = r0 + ty + j * 8, c = c0 + tx;
        t[ty + j * 8][tx] = (r < Rin && c < Cin) ? in[(size_t)r * Cin + c] : 0.f;
    }
    __syncthreads();
    #pragma unroll
    for (int j = 0; j < 4; ++j) {
        int c = c0 + ty + j * 8, r = r0 + tx;
        if (c < Cpad && r < Rpad) outT[(size_t)c * Rpad + r] = __float2bfloat16(t[tx][ty + j * 8]);
    }
}

// ---------------- bf16 MFMA GEMM (z-batched) ----------------
template<int ACT, int OBF, int PADZ>
__global__ __launch_bounds__(256) void gemm_mfma(const __hip_bfloat16* __restrict__ A,
                                                 const __hip_bfloat16* __restrict__ Bt,
                                                 const float* __restrict__ bias,
                                                 void* __restrict__ Cptr,
                                                 int M, int N, int K,
                                                 int ldA, int ldB, int ldC,
                                                 size_t zA, size_t zB, size_t zBias, size_t zC) {
    __shared__ __hip_bfloat16 As[128 * 32];
    __shared__ __hip_bfloat16 Bs[128 * 32];
    const int tid = threadIdx.x;
    const int wid = tid >> 6, lane = tid & 63;
    const int wm = wid >> 1, wn = wid & 1;
    const int bm = blockIdx.y * 128, bn = blockIdx.x * 128;
    A  += (size_t)blockIdx.z * zA;
    Bt += (size_t)blockIdx.z * zB;
    if (bias) bias += (size_t)blockIdx.z * zBias;
    const size_t zc = (size_t)blockIdx.z * zC;

    const __hip_bfloat16* srcA[2];
    const __hip_bfloat16* srcB[2];
    #pragma unroll
    for (int i = 0; i < 2; ++i) {
        int off = (wid * 2 + i) * 1024 + lane * 16;
        int r = off >> 6;
        int c = (off >> 4) & 3;
        int cs = c ^ ((r >> 1) & 3);
        srcA[i] = A  + (size_t)(bm + r) * ldA + cs * 8;
        srcB[i] = Bt + (size_t)(bn + r) * ldB + cs * 8;
    }

    f32x4 acc[4][4];
    #pragma unroll
    for (int i = 0; i < 4; ++i)
        #pragma unroll
        for (int j = 0; j < 4; ++j) acc[i][j] = (f32x4){0.f, 0.f, 0.f, 0.f};

    for (int k0 = 0; k0 < K; k0 += 32) {
        #pragma unroll
        for (int i = 0; i < 2; ++i) {
            GLOAD_LDS16(srcA[i] + k0, (char*)As + (wid * 2 + i) * 1024);
            GLOAD_LDS16(srcB[i] + k0, (char*)Bs + (wid * 2 + i) * 1024);
        }
        __syncthreads();
        s16x8 af[4], bfr[4];
        #pragma unroll
        for (int mi = 0; mi < 4; ++mi) {
            int r = wm * 64 + mi * 16 + (lane & 15);
            int c = (lane >> 4) ^ ((r >> 1) & 3);
            af[mi] = *(const s16x8*)((const char*)As + r * 64 + c * 16);
        }
        #pragma unroll
        for (int ni = 0; ni < 4; ++ni) {
            int r = wn * 64 + ni * 16 + (lane & 15);
            int c = (lane >> 4) ^ ((r >> 1) & 3);
            bfr[ni] = *(const s16x8*)((const char*)Bs + r * 64 + c * 16);
        }
        #pragma unroll
        for (int mi = 0; mi < 4; ++mi)
            #pragma unroll
            for (int ni = 0; ni < 4; ++ni)
                acc[mi][ni] = __builtin_amdgcn_mfma_f32_16x16x32_bf16(af[mi], bfr[ni], acc[mi][ni], 0, 0, 0);
        __syncthreads();
    }

    #pragma unroll
    for (int ni = 0; ni < 4; ++ni) {
        const int col = bn + wn * 64 + ni * 16 + (lane & 15);
        const bool valid = (col < N);
        const float bc = (valid && bias) ? bias[col] : 0.f;
        #pragma unroll
        for (int mi = 0; mi < 4; ++mi) {
            #pragma unroll
            for (int reg = 0; reg < 4; ++reg) {
                const int row = bm + wm * 64 + mi * 16 + (lane >> 4) * 4 + reg;
                float y = 0.f;
                if (valid) {
                    float x = acc[mi][ni][reg] + bc;
                    if (ACT == 1)      y = 0.5f * x * (1.0f + erff(x * 0.7071067811865475f));
                    else if (ACT == 2) y = 1.0f / (1.0f + expf(-x));
                    else if (ACT == 3) { float sg = 1.0f / (1.0f + expf(-tanhf(x))); y = expf(-DECAY_C_F * sg); }
                    else               y = x;
                }
                if (valid || PADZ) {
                    if (OBF) ((__hip_bfloat16*)Cptr)[zc + (size_t)row * ldC + col] = __float2bfloat16(y);
                    else     ((float*)Cptr)[zc + (size_t)row * ldC + col] = y;
                }
            }
        }
    }
}

// ---------------- segment-parallel chunked recurrence (1024 threads, 16 waves) ----------------
#define NW 16
#define P_T0(i,j)   pool[0     + (i)*68 + (j)]
#define P_WT(i,j)   pool[4352  + (i)*68 + (j)]
#define P_KP(i,j)   pool[6528  + (i)*68 + (j)]
#define P_P2t(i,j)  pool[6528  + (i)*36 + (j)]   // aliases KP (dead after phase2)
#define P_NU(i,j)   pool[8704  + (i)*68 + (j)]
#define P_GRt(i,j)  pool[8704  + (i)*36 + (j)]   // aliases NU (dead after phase2)
#define P_RKM(i,j)  pool[10880 + (i)*68 + (j)]
#define P_RRM(i,j)  pool[13056 + (i)*68 + (j)]
#define P_GM(i,j)   pool[15232 + (i)*68 + (j)]
#define P_GMT(i,j)  pool[17408 + (i)*36 + (j)]
#define P_KPT(i,j)  pool[19712 + (i)*36 + (j)]
#define P_NUT(i,j)  pool[22016 + (i)*36 + (j)]
#define P_RKMT(i,j) pool[24320 + (i)*36 + (j)]
#define P_DCT(i,j)  pool[26624 + (i)*36 + (j)]
#define P_AT(i,j)   pool[28928 + (i)*36 + (j)]
#define P_BM(i,j)   pool[30080 + (i)*36 + (j)]
#define P_SEG(i,j)  pool[31232 + (i)*64 + (j)]
#define LD4(expr)   (*(const float4*)&(expr))

__global__ __launch_bounds__(1024, 1) void recurrence_chunked(
    const float* __restrict__ kbuf, const __hip_bfloat16* __restrict__ iclr,
    const __hip_bfloat16* __restrict__ dbuf, const float* __restrict__ vbuf,
    const float* __restrict__ rbuf,
    const float* __restrict__ rem_mult, const float* __restrict__ iclr_mix,
    const float* __restrict__ bonus_mult, float* __restrict__ outb) {
    __shared__ float pool[31488];   // 123 KB
    const int bh = blockIdx.x & 63, seg = blockIdx.x >> 6;
    const int b = bh >> 4, h = bh & 15;
    const int tid = threadIdx.x, lane = tid & 63, wid = tid >> 6;
    const size_t gbase = ((size_t)b * TT) * CC + (size_t)h * NN;

    for (int i = tid; i < 4352; i += 1024) pool[i] = 0.f;   // T0 = 0 at segment start
    const int c0 = tid & 63;
    const float remc = rem_mult[h * NN + c0];
    const float mixc = iclr_mix[h * NN + c0];
    __syncthreads();

    // staggered segments: lengths {19,15,15,15}; warm-up 4 chunks for seg>0 -> 19 chunks/block
    const int cout0 = (seg == 0) ? 0 : 19 + (seg - 1) * 15;
    const int ce    = cout0 + ((seg == 0) ? 19 : 15);
    const int cb    = (seg == 0) ? 0 : cout0 - WARMCH;

    for (int chk = cb; chk < ce; ++chk) {
        const bool emit = (chk >= cout0);
        const int tg0 = chk * TCH;
        // ---- load & elementwise ----
        #pragma unroll
        for (int i = 0; i < 2; ++i) {
            int idx = tid + 1024 * i;
            int t = idx >> 6, c = idx & 63;
            size_t off = gbase + (size_t)(tg0 + t) * CC + c;
            float kx = kbuf[off];
            float ax = __bfloat162float(iclr[off]);
            float rk = kx * (1.f + (ax - 1.f) * mixc);
            P_WT(t, c) = ax;
            P_KP(t, c) = kx * remc;
            P_RKM(t, c) = rk; P_RKMT(c, t) = rk;
            P_NU(t, c) = vbuf[off];
            if (emit) P_RRM(t, c) = rbuf[off];
            P_DCT(c, t) = __bfloat162float(dbuf[off]);
        }
        __syncthreads();
        // ---- row norms: 32 rows over 16 waves ----
        #pragma unroll
        for (int rr = 0; rr < 2; ++rr) {
            int t = wid + rr * 16;
            float v = P_KP(t, lane);
            float ss = v * v;
            #pragma unroll
            for (int s = 32; s; s >>= 1) ss += __shfl_xor(ss, s);
            float kn = v / fmaxf(sqrtf(ss), 1e-12f);
            P_KP(t, lane) = kn;
            P_WT(t, lane) = P_WT(t, lane) * kn;
        }
        __syncthreads();
        // ---- segmented cumprod + scaled quantities (256 threads) ----
        float lc[8];
        int ccs = tid & 63, sgm = (tid >> 6) & 3, t0s = sgm * 8;
        if (tid < 256) {
            float pp = 1.f;
            #pragma unroll
            for (int j = 0; j < 8; ++j) { pp *= P_DCT(ccs, t0s + j); lc[j] = pp; }
            P_SEG(sgm, ccs) = pp;
        }
        __syncthreads();
        if (tid < 256) {
            float m = 1.f;
            for (int s = 0; s < sgm; ++s) m *= P_SEG(s, ccs);
            float dcprev = m;
            #pragma unroll
            for (int j = 0; j < 8; ++j) {
                int t = t0s + j;
                float dcur = m * lc[j];
                P_WT(t, ccs) *= dcprev;
                float inv = 1.f / dcur;
                float kap = P_KP(t, ccs) * inv; P_KP(t, ccs) = kap; P_KPT(ccs, t) = kap;
                float nu  = P_NU(t, ccs) * inv; P_NU(t, ccs) = nu;  P_NUT(ccs, t) = nu;
                P_DCT(ccs, t) = dcur;
                dcprev = dcur;
            }
        }
        __syncthreads();
        // ---- phase2: AT, BM, WT.T0 -> GM (64 tiles over 16 waves) ----
        for (int tile = wid; tile < 64; tile += NW) {
            if (tile < 16) {
                int s = (tile >> 2) * 8 + (lane >> 3), t = (tile & 3) * 8 + (lane & 7);
                float acc = 0.f;
                #pragma unroll
                for (int kc = 0; kc < 16; ++kc) {
                    float4 a = LD4(P_KP(s, kc * 4));
                    float4 bb = LD4(P_WT(t, kc * 4));
                    acc += a.x * bb.x + a.y * bb.y + a.z * bb.z + a.w * bb.w;
                }
                P_AT(s, t) = (s < t) ? acc : 0.f;
            } else if (tile < 32) {
                int t = ((tile - 16) >> 2) * 8 + (lane >> 3), s = ((tile - 16) & 3) * 8 + (lane & 7);
                float acc = 0.f;
                #pragma unroll
                for (int kc = 0; kc < 16; ++kc) {
                    float4 a = LD4(P_WT(t, kc * 4));
                    float4 bb = LD4(P_NU(s, kc * 4));
                    acc += a.x * bb.x + a.y * bb.y + a.z * bb.z + a.w * bb.w;
                }
                P_BM(t, s) = (s < t) ? acc : 0.f;
            } else {
                int tt = tile - 32;
                int t = (tt >> 3) * 8 + (lane >> 3), q = (tt & 7) * 8 + (lane & 7);
                float acc = 0.f;
                #pragma unroll
                for (int j4 = 0; j4 < 16; ++j4) {
                    float4 a = LD4(P_WT(t, j4 * 4));
                    acc += a.x * P_T0(j4 * 4 + 0, q) + a.y * P_T0(j4 * 4 + 1, q)
                         + a.z * P_T0(j4 * 4 + 2, q) + a.w * P_T0(j4 * 4 + 3, q);
                }
                P_GM(t, q) = acc;
            }
        }
        __syncthreads();
        // ---- phase3: GM += BM . RKM (32 tiles) ----
        for (int tile = wid; tile < 32; tile += NW) {
            int t = (tile >> 3) * 8 + (lane >> 3), q = (tile & 7) * 8 + (lane & 7);
            float acc = 0.f;
            #pragma unroll
            for (int s4 = 0; s4 < 8; ++s4) {
                float4 a = LD4(P_BM(t, s4 * 4));
                acc += a.x * P_RKM(s4 * 4 + 0, q) + a.y * P_RKM(s4 * 4 + 1, q)
                     + a.z * P_RKM(s4 * 4 + 2, q) + a.w * P_RKM(s4 * 4 + 3, q);
            }
            P_GM(t, q) += acc;
        }
        __syncthreads();
        // ---- phase4: wave0 forward substitution || waves1-15: P2t (emit only) ----
        if (wid == 0) {
            float g[32];
            #pragma unroll
            for (int t = 0; t < 32; ++t) g[t] = P_GM(t, lane);
            #pragma unroll
            for (int s = 0; s < 31; ++s) {
                #pragma unroll
                for (int t = s + 1; t < 32; ++t) g[t] -= P_AT(s, t) * g[s];
            }
            #pragma unroll
            for (int t = 0; t < 32; ++t) { P_GM(t, lane) = g[t]; P_GMT(lane, t) = g[t]; }
        } else if (emit) {
            for (int tile = wid - 1; tile < 16; tile += (NW - 1)) {
                int t = (tile >> 2) * 8 + (lane >> 3), s = (tile & 3) * 8 + (lane & 7);
                float acc = 0.f;
                #pragma unroll
                for (int kc = 0; kc < 16; ++kc) {
                    float4 a = LD4(P_RRM(t, kc * 4));
                    float4 bb = LD4(P_RKM(s, kc * 4));
                    acc += a.x * bb.x + a.y * bb.y + a.z * bb.z + a.w * bb.w;
                }
                P_P2t(t, s) = (s <= t) ? acc : 0.f;
            }
        }
        __syncthreads();
        if (emit) {
            // ---- phase5: GRt[t][s] = g_s . r_t (16 tiles) ----
            for (int tile = wid; tile < 16; tile += NW) {
                int t = (tile >> 2) * 8 + (lane >> 3), s = (tile & 3) * 8 + (lane & 7);
                float acc = 0.f;
                #pragma unroll
                for (int kc = 0; kc < 16; ++kc) {
                    float4 a = LD4(P_RRM(t, kc * 4));
                    float4 bb = LD4(P_GM(s, kc * 4));
                    acc += a.x * bb.x + a.y * bb.y + a.z * bb.z + a.w * bb.w;
                }
                P_GRt(t, s) = (s <= t) ? acc : 0.f;
            }
            __syncthreads();
            // ---- phase6a: outputs (32 tiles) ----
            for (int tile = wid; tile < 32; tile += NW) {
                int i = (tile >> 2) * 8 + (lane >> 3), t = (tile & 3) * 8 + (lane & 7);
                float a1 = 0.f, a2 = 0.f, a3 = 0.f;
                #pragma unroll
                for (int j4 = 0; j4 < 16; ++j4) {
                    float4 a = LD4(P_T0(i, j4 * 4));
                    float4 bb = LD4(P_RRM(t, j4 * 4));
                    a1 += a.x * bb.x + a.y * bb.y + a.z * bb.z + a.w * bb.w;
                }
                #pragma unroll
                for (int s4 = 0; s4 < 8; ++s4) {
                    float4 a = LD4(P_NUT(i, s4 * 4));
                    float4 bb = LD4(P_P2t(t, s4 * 4));
                    a2 += a.x * bb.x + a.y * bb.y + a.z * bb.z + a.w * bb.w;
                    float4 c = LD4(P_KPT(i, s4 * 4));
                    float4 d = LD4(P_GRt(t, s4 * 4));
                    a3 += c.x * d.x + c.y * d.y + c.z * d.z + c.w * d.w;
                }
                float diag = 0.2f * bonus_mult[h * NN + i] * P_NUT(i, t) * P_P2t(t, t);
                outb[gbase + (size_t)(tg0 + t) * CC + i] = P_DCT(i, t) * (a1 + a2 + diag - a3);
            }
            __syncthreads();
        }
        // ---- phase6b: T0 <- dc_end * (T0 - Kap^T G + Nu^T RK) (64 tiles) ----
        for (int tile = wid; tile < 64; tile += NW) {
            int pr = (tile >> 3) * 8 + (lane >> 3), q = (tile & 7) * 8 + (lane & 7);
            float a1 = 0.f, a2 = 0.f;
            #pragma unroll
            for (int s4 = 0; s4 < 8; ++s4) {
                float4 a = LD4(P_KPT(pr, s4 * 4));
                float4 bb = LD4(P_GMT(q, s4 * 4));
                a1 += a.x * bb.x + a.y * bb.y + a.z * bb.z + a.w * bb.w;
                float4 c = LD4(P_NUT(pr, s4 * 4));
                float4 d = LD4(P_RKMT(q, s4 * 4));
                a2 += c.x * d.x + c.y * d.y + c.z * d.z + c.w * d.w;
            }
            P_T0(pr, q) = P_DCT(pr, 31) * (P_T0(pr, q) - a1 + a2);
        }
        __syncthreads();
    }
}

// ---------------- LayerNorm * gate (bf16 out) ----------------
__global__ __launch_bounds__(256) void ln_gate_kernel(const float* __restrict__ x,
                                                      const __hip_bfloat16* __restrict__ gate,
                                                      const float* __restrict__ g,
                                                      const float* __restrict__ bv,
                                                      __hip_bfloat16* __restrict__ y) {
    const int row = blockIdx.x;
    const float* xr = x + (size_t)row * CC;
    float v[4];
    float s = 0.f;
    #pragma unroll
    for (int j = 0; j < 4; ++j) { v[j] = xr[threadIdx.x + 256 * j]; s += v[j]; }
    __shared__ float red[4], red2[4];
    #pragma unroll
    for (int o = 32; o; o >>= 1) s += __shfl_xor(s, o);
    if ((threadIdx.x & 63) == 0) red[threadIdx.x >> 6] = s;
    __syncthreads();
    const float mean = (red[0] + red[1] + red[2] + red[3]) * (1.f / CC);
    float vs = 0.f;
    #pragma unroll
    for (int j = 0; j < 4; ++j) { float d = v[j] - mean; vs += d * d; }
    #pragma unroll
    for (int o = 32; o; o >>= 1) vs += __shfl_xor(vs, o);
    if ((threadIdx.x & 63) == 0) red2[threadIdx.x >> 6] = vs;
    __syncthreads();
    const float var = (red2[0] + red2[1] + red2[2] + red2[3]) * (1.f / CC);
    const float rstd = rsqrtf(var + 1e-6f);
    #pragma unroll
    for (int j = 0; j < 4; ++j) {
        const int cc = threadIdx.x + 256 * j;
        float o_ = (v[j] - mean) * rstd * g[cc] + bv[cc];
        float gt = __bfloat162float(gate[(size_t)row * CC + cc]);
        y[(size_t)row * CC + cc] = __float2bfloat16(o_ * gt);
    }
}

// ---------------- launch ----------------
extern "C" void kernel_launch(void* const* d_in, const int* in_sizes, int n_in,
                              void* d_out, int out_size, void* d_ws, size_t ws_size,
                              hipStream_t stream) {
    const float* q        = (const float*)d_in[0];
    const float* mu_r     = (const float*)d_in[4];
    const float* mu_k     = (const float*)d_in[5];
    const float* mu_v     = (const float*)d_in[6];
    const float* mu_g     = (const float*)d_in[7];
    const float* mu_a     = (const float*)d_in[8];
    const float* mu_d     = (const float*)d_in[9];
    const float* dA       = (const float*)d_in[10];
    const float* dB       = (const float*)d_in[11];
    const float* db       = (const float*)d_in[12];
    const float* aA       = (const float*)d_in[13];
    const float* aB       = (const float*)d_in[14];
    const float* ab       = (const float*)d_in[15];
    const float* gA       = (const float*)d_in[16];
    const float* gB       = (const float*)d_in[17];
    const float* rW1      = (const float*)d_in[18];
    const float* rb1      = (const float*)d_in[19];
    const float* rW2      = (const float*)d_in[20];
    const float* rb2      = (const float*)d_in[21];
    const float* kW1      = (const float*)d_in[22];
    const float* kb1      = (const float*)d_in[23];
    const float* kW2      = (const float*)d_in[24];
    const float* kb2      = (const float*)d_in[25];
    const float* vW1      = (const float*)d_in[26];
    const float* vb1      = (const float*)d_in[27];
    const float* vW2      = (const float*)d_in[28];
    const float* vb2      = (const float*)d_in[29];
    const float* oW1      = (const float*)d_in[30];
    const float* ob1      = (const float*)d_in[31];
    const float* oW2      = (const float*)d_in[32];
    const float* ob2      = (const float*)d_in[33];
    const float* rem_mult = (const float*)d_in[34];
    const float* iclr_mix = (const float*)d_in[35];
    const float* bonus_mult = (const float*)d_in[36];
    const float* ln_g     = (const float*)d_in[37];
    const float* ln_b     = (const float*)d_in[38];
    float* out = (float*)d_out;

    // ---- workspace arena (~225 MB) ----
    char* p = (char*)d_ws;
    auto alloc = [&](size_t bytes) { char* r = p; p += (bytes + 255) & ~(size_t)255; return r; };
    float* fb_all  = (float*)alloc((size_t)3 * EPAD * 4);   // folded stage-1 biases r,k,v (pad-zeroed)
    float* c2_all  = (float*)alloc((size_t)3 * CC * 4);     // folded LoRA-B biases g,a,d
    float* lt_all  = (float*)alloc((size_t)3 * LL * 4);     // folded LoRA-A temps
    float* cb2_all = (float*)alloc((size_t)3 * CC * 4);     // rb2,kb2,vb2 gathered
    __hip_bfloat16* qb      = (__hip_bfloat16*)alloc((size_t)MM * CC * 2);       // q bf16; later ln_out
    __hip_bfloat16* W1T_all = (__hip_bfloat16*)alloc((size_t)3 * EPAD * CC * 2); // r,k,v W1^T
    __hip_bfloat16* W2T_all = (__hip_bfloat16*)alloc((size_t)3 * CC * EPAD * 2); // r,k,v W2^T
    __hip_bfloat16* Hb      = (__hip_bfloat16*)alloc((size_t)MM * 2 * EPAD * 2); // fused H (r,k); v reuses slice0
    float*          rkv     = (float*)alloc((size_t)3 * MM * CC * 4);            // r,k,v fp32
    __hip_bfloat16* abuf    = (__hip_bfloat16*)alloc((size_t)MM * CC * 2);       // iclr bf16
    __hip_bfloat16* dbuf    = (__hip_bfloat16*)alloc((size_t)MM * CC * 2);       // decay bf16
    __hip_bfloat16* gbuf    = (__hip_bfloat16*)alloc((size_t)MM * CC * 2);       // gate bf16
    float* rbuf = rkv;
    float* kbuf = rkv + (size_t)MM * CC;
    float* vbuf = rkv + (size_t)2 * MM * CC;
    // time-multiplexed tenants of the rkv arena:
    float*          pp      = rkv;                                         // fold partials (240 KB, dies before AT/BT)
    __hip_bfloat16* AT_all  = (__hip_bfloat16*)((char*)rkv + (1 << 18));   // LoRA A^T
    __hip_bfloat16* BT_all  = (__hip_bfloat16*)((char*)rkv + (1 << 18) + 786432);
    __hip_bfloat16* oW1T    = (__hip_bfloat16*)rkv;                        // written after recurrence
    __hip_bfloat16* oW2T    = (__hip_bfloat16*)((char*)rkv + 4194304);
    __hip_bfloat16* tgad    = Hb;                                          // LoRA intermediates [M][384]

    const dim3 blk(256);
    const dim3 tblk(32, 8);

    // gather stage-2 biases (device-to-device, capture-safe)
    hipMemcpyAsync(cb2_all,          rb2, CC * 4, hipMemcpyDeviceToDevice, stream);
    hipMemcpyAsync(cb2_all + CC,     kb2, CC * 4, hipMemcpyDeviceToDevice, stream);
    hipMemcpyAsync(cb2_all + 2 * CC, vb2, CC * 4, hipMemcpyDeviceToDevice, stream);

    // ---- folds (use pp scratch inside rkv; must precede AT/BT transposes) ----
    fold_pass1_z<<<dim3(20, 16, 3), blk, 0, stream>>>(mu_r, mu_k, mu_v, rW1, kW1, vW1,
                                                      pp, EE, EE, EPAD, 16 * EPAD);
    fold_pass2_z<<<dim3(5, 1, 3), blk, 0, stream>>>(pp, rb1, kb1, vb1, fb_all,
                                                    16, EPAD, 16 * EPAD, EE, EPAD, EPAD);
    fold_pass1_z<<<dim3(2, 16, 3), blk, 0, stream>>>(mu_g, mu_a, mu_d, gA, aA, dA,
                                                     pp, LL, LL, EPAD, 16 * EPAD);
    fold_pass2_z<<<dim3(1, 1, 3), dim3(128), 0, stream>>>(pp, nullptr, nullptr, nullptr, lt_all,
                                                          16, EPAD, 16 * EPAD, LL, LL, LL);
    fold_pass1_z<<<dim3(16, 2, 3), blk, 0, stream>>>(lt_all, lt_all + LL, lt_all + 2 * LL, gB, aB, dB,
                                                     pp, CC, CC, EPAD, 16 * EPAD);
    fold_pass2_z<<<dim3(4, 1, 3), blk, 0, stream>>>(pp, nullptr, ab, db, c2_all,
                                                    2, EPAD, 16 * EPAD, CC, CC, CC);

    // ---- transposes (AT/BT land in rkv after pp is dead) ----
    transpose_cast_z<<<dim3(32, 40, 3), tblk, 0, stream>>>(rW1, kW1, vW1, W1T_all,
                                                           (size_t)EPAD * CC, CC, EE, CC, EPAD);
    transpose_cast_z<<<dim3(40, 32, 3), tblk, 0, stream>>>(rW2, kW2, vW2, W2T_all,
                                                           (size_t)CC * EPAD, EE, CC, EPAD, CC);
    transpose_cast_z<<<dim3(32, 4, 3), tblk, 0, stream>>>(gA, aA, dA, AT_all,
                                                          (size_t)LL * CC, CC, LL, CC, LL);
    transpose_cast_z<<<dim3(4, 32, 3), tblk, 0, stream>>>(gB, aB, dB, BT_all,
                                                          (size_t)CC * LL, LL, CC, LL, CC);

    // ---- cast q ----
    cast_f32_bf16<<<dim3(MM * CC / 4 / 256), blk, 0, stream>>>(q, qb, MM * CC / 4);

    // ---- LoRA A-stage fused (N=384) -> tgad (aliases Hb) ----
    gemm_mfma<0,1,0><<<dim3(3, 64, 1), blk, 0, stream>>>(qb, AT_all, nullptr, tgad,
                                                         MM, 384, CC, CC, CC, 384, 0, 0, 0, 0);
    // ---- LoRA B-stage: gate(sig,bf16), iclr(sig,bf16), decay(decay,bf16) ----
    gemm_mfma<2,1,0><<<dim3(8, 64, 1), blk, 0, stream>>>(tgad,       BT_all,               c2_all,          gbuf,
                                                         MM, CC, LL, 384, LL, CC, 0, 0, 0, 0);
    gemm_mfma<2,1,0><<<dim3(8, 64, 1), blk, 0, stream>>>(tgad + LL,  BT_all + (size_t)CC * LL,  c2_all + CC,     abuf,
                                                         MM, CC, LL, 384, LL, CC, 0, 0, 0, 0);
    gemm_mfma<3,1,0><<<dim3(8, 64, 1), blk, 0, stream>>>(tgad + 2 * LL, BT_all + (size_t)2 * CC * LL, c2_all + 2 * CC, dbuf,
                                                         MM, CC, LL, 384, LL, CC, 0, 0, 0, 0);

    // ---- MLP r,k fused stage-1 (N=2560), then z-batched stage-2 ----
    gemm_mfma<1,1,0><<<dim3(20, 64, 1), blk, 0, stream>>>(qb, W1T_all, fb_all, Hb,
                                                          MM, 2 * EPAD, CC, CC, CC, 2 * EPAD, 0, 0, 0, 0);
    gemm_mfma<0,0,0><<<dim3(8, 64, 2), blk, 0, stream>>>(Hb, W2T_all, cb2_all, rkv,
                                                         MM, CC, EPAD, 2 * EPAD, EPAD, CC,
                                                         EPAD, (size_t)CC * EPAD, CC, (size_t)MM * CC);
    // ---- MLP v: stage-1 into Hb slice0, stage-2 -> vbuf ----
    gemm_mfma<1,1,0><<<dim3(10, 64, 1), blk, 0, stream>>>(qb, W1T_all + (size_t)2 * EPAD * CC, fb_all + 2 * EPAD, Hb,
                                                          MM, EPAD, CC, CC, CC, EPAD, 0, 0, 0, 0);
    gemm_mfma<0,0,0><<<dim3(8, 64, 1), blk, 0, stream>>>(Hb, W2T_all + (size_t)2 * CC * EPAD, cb2_all + 2 * CC, vbuf,
                                                         MM, CC, EPAD, EPAD, EPAD, CC, 0, 0, 0, 0);

    // ---- recurrence (256 blocks x 1024 threads) -> d_out scratch ----
    recurrence_chunked<<<dim3(BB * HH * NSEG), dim3(1024), 0, stream>>>(
        kbuf, abuf, dbuf, vbuf, rbuf, rem_mult, iclr_mix, bonus_mult, out);

    // ---- o-weight transposes into rkv (r/k/v dead after recurrence) ----
    transpose_cast_z<<<dim3(32, 40, 1), tblk, 0, stream>>>(oW1, oW1, oW1, oW1T,
                                                           0, CC, EE, CC, EPAD);
    transpose_cast_z<<<dim3(40, 32, 1), tblk, 0, stream>>>(oW2, oW2, oW2, oW2T,
                                                           0, EE, CC, EPAD, CC);

    // ---- LN * gate -> qb (bf16) ----
    ln_gate_kernel<<<dim3(MM), blk, 0, stream>>>(out, gbuf, ln_g, ln_b, qb);

    // ---- output MLP ----
    gemm_mfma<1,1,1><<<dim3(10, 64, 1), blk, 0, stream>>>(qb, oW1T, ob1, Hb,
                                                          MM, EE, CC, CC, CC, EPAD, 0, 0, 0, 0);
    gemm_mfma<0,0,0><<<dim3(8, 64, 1), blk, 0, stream>>>(Hb, oW2T, ob2, out,
                                                         MM, CC, EPAD, EPAD, EPAD, CC, 0, 0, 0, 0);
}

// Round 7
// 1685.211 us; speedup vs baseline: 1.0032x; 1.0030x over previous
//
#include <hip/hip_runtime.h>
#include <hip/hip_bf16.h>
#include <math.h>

// LinearAttentionLayerOptimized: B=4, T=2048, C=1024, H=16, N=64, L=128, E=1228
// Round 6: kill the spill structurally. Round 4/5 showed hipcc pins 1024-thread
// blocks at 64 VGPRs (launch_bounds min-occupancy hints ignored), spilling
// wave0's g[32] -> 2.5 GB scratch traffic. Fix: (a) blocked 16+16 forward
// substitution so the solve needs only g[16] (fits 64 VGPRs), with the A21
// update parallelized over all 16 waves; (b) amdgpu_waves_per_eu(4,4) to ask
// for the 128-VGPR budget that the 1-block/CU LDS footprint already implies.

#define BB 4
#define TT 2048
#define CC 1024
#define HH 16
#define NN 64
#define LL 128
#define EE 1228
#define EPAD 1280
#define MM (BB*TT)          // 8192 rows
#define TCH 32
#define NSEG 4
#define WARMCH 4            // 128 warm-up steps; decay<=0.82 -> ~1e-11
#define DECAY_C_F 0.7408182206817179f

typedef __attribute__((ext_vector_type(8))) short s16x8;
typedef __attribute__((ext_vector_type(4))) float f32x4;

#define GLOAD_LDS16(gp, lp) \
    __builtin_amdgcn_global_load_lds((const __attribute__((address_space(1))) void*)(gp), \
                                     (__attribute__((address_space(3))) void*)(lp), 16, 0, 0)

// ---------------- z-batched two-pass bias folds ----------------
__global__ __launch_bounds__(256) void fold_pass1_z(
    const float* __restrict__ mu0, const float* __restrict__ mu1, const float* __restrict__ mu2,
    const float* __restrict__ W0,  const float* __restrict__ W1_, const float* __restrict__ W2_,
    float* __restrict__ partial, int ldW, int E, int ldP, int pslice) {
    const float* mu = blockIdx.z == 0 ? mu0 : (blockIdx.z == 1 ? mu1 : mu2);
    const float* W  = blockIdx.z == 0 ? W0  : (blockIdx.z == 1 ? W1_ : W2_);
    partial += (size_t)blockIdx.z * pslice;
    const int l = threadIdx.x & 63;
    const int e = blockIdx.x * 64 + l;
    const int pg = threadIdx.x >> 6;
    const int c0 = blockIdx.y * 64;
    float s = 0.f;
    if (e < E)
        for (int c = c0 + pg; c < c0 + 64; c += 4) s += mu[c] * W[(size_t)c * ldW + e];
    __shared__ float red[4][64];
    red[pg][l] = s;
    __syncthreads();
    if (pg == 0 && e < E)
        partial[(size_t)blockIdx.y * ldP + e] = red[0][l] + red[1][l] + red[2][l] + red[3][l];
}

__global__ void fold_pass2_z(const float* __restrict__ partial,
                             const float* b0, const float* b1, const float* b2,
                             float* __restrict__ outv,
                             int P, int ldP, int pslice, int E, int Epad, int oslice) {
    const float* bias = blockIdx.z == 0 ? b0 : (blockIdx.z == 1 ? b1 : b2);
    partial += (size_t)blockIdx.z * pslice;
    outv    += (size_t)blockIdx.z * oslice;
    int e = blockIdx.x * blockDim.x + threadIdx.x;
    if (e >= Epad) return;
    float s = 0.f;
    if (e < E) {
        s = bias ? bias[e] : 0.f;
        for (int p = 0; p < P; ++p) s += partial[(size_t)p * ldP + e];
    }
    outv[e] = s;
}

// ---------------- cast / z-batched transpose-cast ----------------
__global__ void cast_f32_bf16(const float* __restrict__ in, __hip_bfloat16* __restrict__ out, int n4) {
    int i = blockIdx.x * blockDim.x + threadIdx.x;
    if (i >= n4) return;
    float4 v = ((const float4*)in)[i];
    __hip_bfloat16 o[4] = {__float2bfloat16(v.x), __float2bfloat16(v.y),
                           __float2bfloat16(v.z), __float2bfloat16(v.w)};
    *(ulong1*)&out[i * 4] = *(ulong1*)o;
}

__global__ void transpose_cast_z(const float* s0, const float* s1, const float* s2,
                                 __hip_bfloat16* __restrict__ outT, size_t dslice,
                                 int Rin, int Cin, int Rpad, int Cpad) {
    const float* in = blockIdx.z == 0 ? s0 : (blockIdx.z == 1 ? s1 : s2);
    outT += (size_t)blockIdx.z * dslice;
    __shared__ float t[32][33];
    const int r0 = blockIdx.x * 32, c0 = blockIdx.y * 32;
    const int tx = threadIdx.x, ty = threadIdx.y;   // 32 x 8
    #pragma unroll
    for (int j = 0; j < 4; ++j) {
        int r = r0 + ty + j * 8, c = c0 + tx;
        t[ty + j * 8][tx] = (r < Rin && c < Cin) ? in[(size_t)r * Cin + c] : 0.f;
    }
    __syncthreads();
    #pragma unroll
    for (int j = 0; j < 4; ++j) {
        int c = c0 + ty + j * 8, r = r0 + tx;
        if (c < Cpad && r < Rpad) outT[(size_t)c * Rpad + r] = __float2bfloat16(t[tx][ty + j * 8]);
    }
}

// ---------------- bf16 MFMA GEMM (z-batched) ----------------
template<int ACT, int OBF, int PADZ>
__global__ __launch_bounds__(256) void gemm_mfma(const __hip_bfloat16* __restrict__ A,
                                                 const __hip_bfloat16* __restrict__ Bt,
                                                 const float* __restrict__ bias,
                                                 void* __restrict__ Cptr,
                                                 int M, int N, int K,
                                                 int ldA, int ldB, int ldC,
                                                 size_t zA, size_t zB, size_t zBias, size_t zC) {
    __shared__ __hip_bfloat16 As[128 * 32];
    __shared__ __hip_bfloat16 Bs[128 * 32];
    const int tid = threadIdx.x;
    const int wid = tid >> 6, lane = tid & 63;
    const int wm = wid >> 1, wn = wid & 1;
    const int bm = blockIdx.y * 128, bn = blockIdx.x * 128;
    A  += (size_t)blockIdx.z * zA;
    Bt += (size_t)blockIdx.z * zB;
    if (bias) bias += (size_t)blockIdx.z * zBias;
    const size_t zc = (size_t)blockIdx.z * zC;

    const __hip_bfloat16* srcA[2];
    const __hip_bfloat16* srcB[2];
    #pragma unroll
    for (int i = 0; i < 2; ++i) {
        int off = (wid * 2 + i) * 1024 + lane * 16;
        int r = off >> 6;
        int c = (off >> 4) & 3;
        int cs = c ^ ((r >> 1) & 3);
        srcA[i] = A  + (size_t)(bm + r) * ldA + cs * 8;
        srcB[i] = Bt + (size_t)(bn + r) * ldB + cs * 8;
    }

    f32x4 acc[4][4];
    #pragma unroll
    for (int i = 0; i < 4; ++i)
        #pragma unroll
        for (int j = 0; j < 4; ++j) acc[i][j] = (f32x4){0.f, 0.f, 0.f, 0.f};

    for (int k0 = 0; k0 < K; k0 += 32) {
        #pragma unroll
        for (int i = 0; i < 2; ++i) {
            GLOAD_LDS16(srcA[i] + k0, (char*)As + (wid * 2 + i) * 1024);
            GLOAD_LDS16(srcB[i] + k0, (char*)Bs + (wid * 2 + i) * 1024);
        }
        __syncthreads();
        s16x8 af[4], bfr[4];
        #pragma unroll
        for (int mi = 0; mi < 4; ++mi) {
            int r = wm * 64 + mi * 16 + (lane & 15);
            int c = (lane >> 4) ^ ((r >> 1) & 3);
            af[mi] = *(const s16x8*)((const char*)As + r * 64 + c * 16);
        }
        #pragma unroll
        for (int ni = 0; ni < 4; ++ni) {
            int r = wn * 64 + ni * 16 + (lane & 15);
            int c = (lane >> 4) ^ ((r >> 1) & 3);
            bfr[ni] = *(const s16x8*)((const char*)Bs + r * 64 + c * 16);
        }
        #pragma unroll
        for (int mi = 0; mi < 4; ++mi)
            #pragma unroll
            for (int ni = 0; ni < 4; ++ni)
                acc[mi][ni] = __builtin_amdgcn_mfma_f32_16x16x32_bf16(af[mi], bfr[ni], acc[mi][ni], 0, 0, 0);
        __syncthreads();
    }

    #pragma unroll
    for (int ni = 0; ni < 4; ++ni) {
        const int col = bn + wn * 64 + ni * 16 + (lane & 15);
        const bool valid = (col < N);
        const float bc = (valid && bias) ? bias[col] : 0.f;
        #pragma unroll
        for (int mi = 0; mi < 4; ++mi) {
            #pragma unroll
            for (int reg = 0; reg < 4; ++reg) {
                const int row = bm + wm * 64 + mi * 16 + (lane >> 4) * 4 + reg;
                float y = 0.f;
                if (valid) {
                    float x = acc[mi][ni][reg] + bc;
                    if (ACT == 1)      y = 0.5f * x * (1.0f + erff(x * 0.7071067811865475f));
                    else if (ACT == 2) y = 1.0f / (1.0f + expf(-x));
                    else if (ACT == 3) { float sg = 1.0f / (1.0f + expf(-tanhf(x))); y = expf(-DECAY_C_F * sg); }
                    else               y = x;
                }
                if (valid || PADZ) {
                    if (OBF) ((__hip_bfloat16*)Cptr)[zc + (size_t)row * ldC + col] = __float2bfloat16(y);
                    else     ((float*)Cptr)[zc + (size_t)row * ldC + col] = y;
                }
            }
        }
    }
}

// ---------------- segment-parallel chunked recurrence (1024 threads, 16 waves) ----------------
#define NW 16
#define P_T0(i,j)   pool[0     + (i)*68 + (j)]
#define P_WT(i,j)   pool[4352  + (i)*68 + (j)]
#define P_KP(i,j)   pool[6528  + (i)*68 + (j)]
#define P_P2t(i,j)  pool[6528  + (i)*36 + (j)]   // aliases KP (dead after phase2)
#define P_NU(i,j)   pool[8704  + (i)*68 + (j)]
#define P_GRt(i,j)  pool[8704  + (i)*36 + (j)]   // aliases NU (dead after phase2)
#define P_RKM(i,j)  pool[10880 + (i)*68 + (j)]
#define P_RRM(i,j)  pool[13056 + (i)*68 + (j)]
#define P_GM(i,j)   pool[15232 + (i)*68 + (j)]
#define P_GMT(i,j)  pool[17408 + (i)*36 + (j)]
#define P_KPT(i,j)  pool[19712 + (i)*36 + (j)]
#define P_NUT(i,j)  pool[22016 + (i)*36 + (j)]
#define P_RKMT(i,j) pool[24320 + (i)*36 + (j)]
#define P_DCT(i,j)  pool[26624 + (i)*36 + (j)]
#define P_AT(i,j)   pool[28928 + (i)*36 + (j)]
#define P_BM(i,j)   pool[30080 + (i)*36 + (j)]
#define P_SEG(i,j)  pool[31232 + (i)*64 + (j)]
#define LD4(expr)   (*(const float4*)&(expr))

__global__ __launch_bounds__(1024)
__attribute__((amdgpu_waves_per_eu(4, 4)))
void recurrence_chunked(
    const float* __restrict__ kbuf, const __hip_bfloat16* __restrict__ iclr,
    const __hip_bfloat16* __restrict__ dbuf, const float* __restrict__ vbuf,
    const float* __restrict__ rbuf,
    const float* __restrict__ rem_mult, const float* __restrict__ iclr_mix,
    const float* __restrict__ bonus_mult, float* __restrict__ outb) {
    __shared__ float pool[31488];   // 123 KB
    const int bh = blockIdx.x & 63, seg = blockIdx.x >> 6;
    const int b = bh >> 4, h = bh & 15;
    const int tid = threadIdx.x, lane = tid & 63, wid = tid >> 6;
    const size_t gbase = ((size_t)b * TT) * CC + (size_t)h * NN;

    for (int i = tid; i < 4352; i += 1024) pool[i] = 0.f;   // T0 = 0 at segment start
    const int c0 = tid & 63;
    const float remc = rem_mult[h * NN + c0];
    const float mixc = iclr_mix[h * NN + c0];
    __syncthreads();

    // staggered segments: lengths {19,15,15,15}; warm-up 4 chunks for seg>0 -> 19 chunks/block
    const int cout0 = (seg == 0) ? 0 : 19 + (seg - 1) * 15;
    const int ce    = cout0 + ((seg == 0) ? 19 : 15);
    const int cb    = (seg == 0) ? 0 : cout0 - WARMCH;

    for (int chk = cb; chk < ce; ++chk) {
        const bool emit = (chk >= cout0);
        const int tg0 = chk * TCH;
        // ---- load & elementwise ----
        #pragma unroll
        for (int i = 0; i < 2; ++i) {
            int idx = tid + 1024 * i;
            int t = idx >> 6, c = idx & 63;
            size_t off = gbase + (size_t)(tg0 + t) * CC + c;
            float kx = kbuf[off];
            float ax = __bfloat162float(iclr[off]);
            float rk = kx * (1.f + (ax - 1.f) * mixc);
            P_WT(t, c) = ax;
            P_KP(t, c) = kx * remc;
            P_RKM(t, c) = rk; P_RKMT(c, t) = rk;
            P_NU(t, c) = vbuf[off];
            if (emit) P_RRM(t, c) = rbuf[off];
            P_DCT(c, t) = __bfloat162float(dbuf[off]);
        }
        __syncthreads();
        // ---- row norms: 32 rows over 16 waves ----
        #pragma unroll
        for (int rr = 0; rr < 2; ++rr) {
            int t = wid + rr * 16;
            float v = P_KP(t, lane);
            float ss = v * v;
            #pragma unroll
            for (int s = 32; s; s >>= 1) ss += __shfl_xor(ss, s);
            float kn = v / fmaxf(sqrtf(ss), 1e-12f);
            P_KP(t, lane) = kn;
            P_WT(t, lane) = P_WT(t, lane) * kn;
        }
        __syncthreads();
        // ---- segmented cumprod + scaled quantities (256 threads) ----
        float lc[8];
        int ccs = tid & 63, sgm = (tid >> 6) & 3, t0s = sgm * 8;
        if (tid < 256) {
            float pp = 1.f;
            #pragma unroll
            for (int j = 0; j < 8; ++j) { pp *= P_DCT(ccs, t0s + j); lc[j] = pp; }
            P_SEG(sgm, ccs) = pp;
        }
        __syncthreads();
        if (tid < 256) {
            float m = 1.f;
            for (int s = 0; s < sgm; ++s) m *= P_SEG(s, ccs);
            float dcprev = m;
            #pragma unroll
            for (int j = 0; j < 8; ++j) {
                int t = t0s + j;
                float dcur = m * lc[j];
                P_WT(t, ccs) *= dcprev;
                float inv = 1.f / dcur;
                float kap = P_KP(t, ccs) * inv; P_KP(t, ccs) = kap; P_KPT(ccs, t) = kap;
                float nu  = P_NU(t, ccs) * inv; P_NU(t, ccs) = nu;  P_NUT(ccs, t) = nu;
                P_DCT(ccs, t) = dcur;
                dcprev = dcur;
            }
        }
        __syncthreads();
        // ---- phase2: AT, BM, WT.T0 -> GM (64 tiles over 16 waves) ----
        for (int tile = wid; tile < 64; tile += NW) {
            if (tile < 16) {
                int s = (tile >> 2) * 8 + (lane >> 3), t = (tile & 3) * 8 + (lane & 7);
                float acc = 0.f;
                #pragma unroll
                for (int kc = 0; kc < 16; ++kc) {
                    float4 a = LD4(P_KP(s, kc * 4));
                    float4 bb = LD4(P_WT(t, kc * 4));
                    acc += a.x * bb.x + a.y * bb.y + a.z * bb.z + a.w * bb.w;
                }
                P_AT(s, t) = (s < t) ? acc : 0.f;
            } else if (tile < 32) {
                int t = ((tile - 16) >> 2) * 8 + (lane >> 3), s = ((tile - 16) & 3) * 8 + (lane & 7);
                float acc = 0.f;
                #pragma unroll
                for (int kc = 0; kc < 16; ++kc) {
                    float4 a = LD4(P_WT(t, kc * 4));
                    float4 bb = LD4(P_NU(s, kc * 4));
                    acc += a.x * bb.x + a.y * bb.y + a.z * bb.z + a.w * bb.w;
                }
                P_BM(t, s) = (s < t) ? acc : 0.f;
            } else {
                int tt = tile - 32;
                int t = (tt >> 3) * 8 + (lane >> 3), q = (tt & 7) * 8 + (lane & 7);
                float acc = 0.f;
                #pragma unroll
                for (int j4 = 0; j4 < 16; ++j4) {
                    float4 a = LD4(P_WT(t, j4 * 4));
                    acc += a.x * P_T0(j4 * 4 + 0, q) + a.y * P_T0(j4 * 4 + 1, q)
                         + a.z * P_T0(j4 * 4 + 2, q) + a.w * P_T0(j4 * 4 + 3, q);
                }
                P_GM(t, q) = acc;
            }
        }
        __syncthreads();
        // ---- phase3: GM += BM . RKM (32 tiles) ----
        for (int tile = wid; tile < 32; tile += NW) {
            int t = (tile >> 3) * 8 + (lane >> 3), q = (tile & 7) * 8 + (lane & 7);
            float acc = 0.f;
            #pragma unroll
            for (int s4 = 0; s4 < 8; ++s4) {
                float4 a = LD4(P_BM(t, s4 * 4));
                acc += a.x * P_RKM(s4 * 4 + 0, q) + a.y * P_RKM(s4 * 4 + 1, q)
                     + a.z * P_RKM(s4 * 4 + 2, q) + a.w * P_RKM(s4 * 4 + 3, q);
            }
            P_GM(t, q) += acc;
        }
        __syncthreads();
        // ---- phase4a: wave0 solves rows 0..15 (g[16], no spill) || waves1-15: P2t (emit) ----
        if (wid == 0) {
            float g[16];
            #pragma unroll
            for (int t = 0; t < 16; ++t) g[t] = P_GM(t, lane);
            #pragma unroll
            for (int s = 0; s < 15; ++s) {
                #pragma unroll
                for (int t = s + 1; t < 16; ++t) g[t] -= P_AT(s, t) * g[s];
            }
            #pragma unroll
            for (int t = 0; t < 16; ++t) { P_GM(t, lane) = g[t]; P_GMT(lane, t) = g[t]; }
        } else if (emit) {
            for (int tile = wid - 1; tile < 16; tile += (NW - 1)) {   // P2t[t][s] = rk_s . r_t
                int t = (tile >> 2) * 8 + (lane >> 3), s = (tile & 3) * 8 + (lane & 7);
                float acc = 0.f;
                #pragma unroll
                for (int kc = 0; kc < 16; ++kc) {
                    float4 a = LD4(P_RRM(t, kc * 4));
                    float4 bb = LD4(P_RKM(s, kc * 4));
                    acc += a.x * bb.x + a.y * bb.y + a.z * bb.z + a.w * bb.w;
                }
                P_P2t(t, s) = (s <= t) ? acc : 0.f;
            }
        }
        __syncthreads();
        // ---- phase4b: A21 update, GM(t,:) -= sum_{s<16} AT(s,t)*GM(s,:), t=16..31 (16 tiles) ----
        {
            int tile = wid;
            int t = 16 + (tile >> 3) * 8 + (lane >> 3), q = (tile & 7) * 8 + (lane & 7);
            float acc = 0.f;
            #pragma unroll
            for (int s = 0; s < 16; ++s) acc += P_AT(s, t) * P_GM(s, q);
            P_GM(t, q) -= acc;
        }
        __syncthreads();
        // ---- phase4c: wave0 solves rows 16..31 || waves1-8: phase5 tiles with s<16 (emit) ----
        if (wid == 0) {
            float g[16];
            #pragma unroll
            for (int t = 0; t < 16; ++t) g[t] = P_GM(16 + t, lane);
            #pragma unroll
            for (int s = 0; s < 15; ++s) {
                #pragma unroll
                for (int t = s + 1; t < 16; ++t) g[t] -= P_AT(16 + s, 16 + t) * g[s];
            }
            #pragma unroll
            for (int t = 0; t < 16; ++t) { P_GM(16 + t, lane) = g[t]; P_GMT(lane, 16 + t) = g[t]; }
        } else if (emit && wid <= 8) {
            // GRt[t][s] = g_s . r_t for s-block 0..1 (rows s<16 of GM are final)
            int tb = (wid - 1) >> 1, sb = (wid - 1) & 1;
            int t = tb * 8 + (lane >> 3), s = sb * 8 + (lane & 7);
            float acc = 0.f;
            #pragma unroll
            for (int kc = 0; kc < 16; ++kc) {
                float4 a = LD4(P_RRM(t, kc * 4));
                float4 bb = LD4(P_GM(s, kc * 4));
                acc += a.x * bb.x + a.y * bb.y + a.z * bb.z + a.w * bb.w;
            }
            P_GRt(t, s) = (s <= t) ? acc : 0.f;
        }
        __syncthreads();
        if (emit) {
            // ---- phase5b: GRt tiles with s>=16 (8 tiles on waves 0..7) ----
            if (wid < 8) {
                int tb = wid >> 1, sb = 2 + (wid & 1);
                int t = tb * 8 + (lane >> 3), s = sb * 8 + (lane & 7);
                float acc = 0.f;
                #pragma unroll
                for (int kc = 0; kc < 16; ++kc) {
                    float4 a = LD4(P_RRM(t, kc * 4));
                    float4 bb = LD4(P_GM(s, kc * 4));
                    acc += a.x * bb.x + a.y * bb.y + a.z * bb.z + a.w * bb.w;
                }
                P_GRt(t, s) = (s <= t) ? acc : 0.f;
            }
            __syncthreads();
            // ---- phase6a: outputs (32 tiles) ----
            for (int tile = wid; tile < 32; tile += NW) {
                int i = (tile >> 2) * 8 + (lane >> 3), t = (tile & 3) * 8 + (lane & 7);
                float a1 = 0.f, a2 = 0.f, a3 = 0.f;
                #pragma unroll
                for (int j4 = 0; j4 < 16; ++j4) {
                    float4 a = LD4(P_T0(i, j4 * 4));
                    float4 bb = LD4(P_RRM(t, j4 * 4));
                    a1 += a.x * bb.x + a.y * bb.y + a.z * bb.z + a.w * bb.w;
                }
                #pragma unroll
                for (int s4 = 0; s4 < 8; ++s4) {
                    float4 a = LD4(P_NUT(i, s4 * 4));
                    float4 bb = LD4(P_P2t(t, s4 * 4));
                    a2 += a.x * bb.x + a.y * bb.y + a.z * bb.z + a.w * bb.w;
                    float4 c = LD4(P_KPT(i, s4 * 4));
                    float4 d = LD4(P_GRt(t, s4 * 4));
                    a3 += c.x * d.x + c.y * d.y + c.z * d.z + c.w * d.w;
                }
                float diag = 0.2f * bonus_mult[h * NN + i] * P_NUT(i, t) * P_P2t(t, t);
                outb[gbase + (size_t)(tg0 + t) * CC + i] = P_DCT(i, t) * (a1 + a2 + diag - a3);
            }
            __syncthreads();
        }
        // ---- phase6b: T0 <- dc_end * (T0 - Kap^T G + Nu^T RK) (64 tiles) ----
        for (int tile = wid; tile < 64; tile += NW) {
            int pr = (tile >> 3) * 8 + (lane >> 3), q = (tile & 7) * 8 + (lane & 7);
            float a1 = 0.f, a2 = 0.f;
            #pragma unroll
            for (int s4 = 0; s4 < 8; ++s4) {
                float4 a = LD4(P_KPT(pr, s4 * 4));
                float4 bb = LD4(P_GMT(q, s4 * 4));
                a1 += a.x * bb.x + a.y * bb.y + a.z * bb.z + a.w * bb.w;
                float4 c = LD4(P_NUT(pr, s4 * 4));
                float4 d = LD4(P_RKMT(q, s4 * 4));
                a2 += c.x * d.x + c.y * d.y + c.z * d.z + c.w * d.w;
            }
            P_T0(pr, q) = P_DCT(pr, 31) * (P_T0(pr, q) - a1 + a2);
        }
        __syncthreads();
    }
}

// ---------------- LayerNorm * gate (bf16 out) ----------------
__global__ __launch_bounds__(256) void ln_gate_kernel(const float* __restrict__ x,
                                                      const __hip_bfloat16* __restrict__ gate,
                                                      const float* __restrict__ g,
                                                      const float* __restrict__ bv,
                                                      __hip_bfloat16* __restrict__ y) {
    const int row = blockIdx.x;
    const float* xr = x + (size_t)row * CC;
    float v[4];
    float s = 0.f;
    #pragma unroll
    for (int j = 0; j < 4; ++j) { v[j] = xr[threadIdx.x + 256 * j]; s += v[j]; }
    __shared__ float red[4], red2[4];
    #pragma unroll
    for (int o = 32; o; o >>= 1) s += __shfl_xor(s, o);
    if ((threadIdx.x & 63) == 0) red[threadIdx.x >> 6] = s;
    __syncthreads();
    const float mean = (red[0] + red[1] + red[2] + red[3]) * (1.f / CC);
    float vs = 0.f;
    #pragma unroll
    for (int j = 0; j < 4; ++j) { float d = v[j] - mean; vs += d * d; }
    #pragma unroll
    for (int o = 32; o; o >>= 1) vs += __shfl_xor(vs, o);
    if ((threadIdx.x & 63) == 0) red2[threadIdx.x >> 6] = vs;
    __syncthreads();
    const float var = (red2[0] + red2[1] + red2[2] + red2[3]) * (1.f / CC);
    const float rstd = rsqrtf(var + 1e-6f);
    #pragma unroll
    for (int j = 0; j < 4; ++j) {
        const int cc = threadIdx.x + 256 * j;
        float o_ = (v[j] - mean) * rstd * g[cc] + bv[cc];
        float gt = __bfloat162float(gate[(size_t)row * CC + cc]);
        y[(size_t)row * CC + cc] = __float2bfloat16(o_ * gt);
    }
}

// ---------------- launch ----------------
extern "C" void kernel_launch(void* const* d_in, const int* in_sizes, int n_in,
                              void* d_out, int out_size, void* d_ws, size_t ws_size,
                              hipStream_t stream) {
    const float* q        = (const float*)d_in[0];
    const float* mu_r     = (const float*)d_in[4];
    const float* mu_k     = (const float*)d_in[5];
    const float* mu_v     = (const float*)d_in[6];
    const float* mu_g     = (const float*)d_in[7];
    const float* mu_a     = (const float*)d_in[8];
    const float* mu_d     = (const float*)d_in[9];
    const float* dA       = (const float*)d_in[10];
    const float* dB       = (const float*)d_in[11];
    const float* db       = (const float*)d_in[12];
    const float* aA       = (const float*)d_in[13];
    const float* aB       = (const float*)d_in[14];
    const float* ab       = (const float*)d_in[15];
    const float* gA       = (const float*)d_in[16];
    const float* gB       = (const float*)d_in[17];
    const float* rW1      = (const float*)d_in[18];
    const float* rb1      = (const float*)d_in[19];
    const float* rW2      = (const float*)d_in[20];
    const float* rb2      = (const float*)d_in[21];
    const float* kW1      = (const float*)d_in[22];
    const float* kb1      = (const float*)d_in[23];
    const float* kW2      = (const float*)d_in[24];
    const float* kb2      = (const float*)d_in[25];
    const float* vW1      = (const float*)d_in[26];
    const float* vb1      = (const float*)d_in[27];
    const float* vW2      = (const float*)d_in[28];
    const float* vb2      = (const float*)d_in[29];
    const float* oW1      = (const float*)d_in[30];
    const float* ob1      = (const float*)d_in[31];
    const float* oW2      = (const float*)d_in[32];
    const float* ob2      = (const float*)d_in[33];
    const float* rem_mult = (const float*)d_in[34];
    const float* iclr_mix = (const float*)d_in[35];
    const float* bonus_mult = (const float*)d_in[36];
    const float* ln_g     = (const float*)d_in[37];
    const float* ln_b     = (const float*)d_in[38];
    float* out = (float*)d_out;

    // ---- workspace arena (~225 MB) ----
    char* p = (char*)d_ws;
    auto alloc = [&](size_t bytes) { char* r = p; p += (bytes + 255) & ~(size_t)255; return r; };
    float* fb_all  = (float*)alloc((size_t)3 * EPAD * 4);   // folded stage-1 biases r,k,v (pad-zeroed)
    float* c2_all  = (float*)alloc((size_t)3 * CC * 4);     // folded LoRA-B biases g,a,d
    float* lt_all  = (float*)alloc((size_t)3 * LL * 4);     // folded LoRA-A temps
    float* cb2_all = (float*)alloc((size_t)3 * CC * 4);     // rb2,kb2,vb2 gathered
    __hip_bfloat16* qb      = (__hip_bfloat16*)alloc((size_t)MM * CC * 2);       // q bf16; later ln_out
    __hip_bfloat16* W1T_all = (__hip_bfloat16*)alloc((size_t)3 * EPAD * CC * 2); // r,k,v W1^T
    __hip_bfloat16* W2T_all = (__hip_bfloat16*)alloc((size_t)3 * CC * EPAD * 2); // r,k,v W2^T
    __hip_bfloat16* Hb      = (__hip_bfloat16*)alloc((size_t)MM * 2 * EPAD * 2); // fused H (r,k); v reuses slice0
    float*          rkv     = (float*)alloc((size_t)3 * MM * CC * 4);            // r,k,v fp32
    __hip_bfloat16* abuf    = (__hip_bfloat16*)alloc((size_t)MM * CC * 2);       // iclr bf16
    __hip_bfloat16* dbuf    = (__hip_bfloat16*)alloc((size_t)MM * CC * 2);       // decay bf16
    __hip_bfloat16* gbuf    = (__hip_bfloat16*)alloc((size_t)MM * CC * 2);       // gate bf16
    float* rbuf = rkv;
    float* kbuf = rkv + (size_t)MM * CC;
    float* vbuf = rkv + (size_t)2 * MM * CC;
    // time-multiplexed tenants of the rkv arena:
    float*          pp      = rkv;                                         // fold partials (240 KB, dies before AT/BT)
    __hip_bfloat16* AT_all  = (__hip_bfloat16*)((char*)rkv + (1 << 18));   // LoRA A^T
    __hip_bfloat16* BT_all  = (__hip_bfloat16*)((char*)rkv + (1 << 18) + 786432);
    __hip_bfloat16* oW1T    = (__hip_bfloat16*)rkv;                        // written after recurrence
    __hip_bfloat16* oW2T    = (__hip_bfloat16*)((char*)rkv + 4194304);
    __hip_bfloat16* tgad    = Hb;                                          // LoRA intermediates [M][384]

    const dim3 blk(256);
    const dim3 tblk(32, 8);

    // gather stage-2 biases (device-to-device, capture-safe)
    hipMemcpyAsync(cb2_all,          rb2, CC * 4, hipMemcpyDeviceToDevice, stream);
    hipMemcpyAsync(cb2_all + CC,     kb2, CC * 4, hipMemcpyDeviceToDevice, stream);
    hipMemcpyAsync(cb2_all + 2 * CC, vb2, CC * 4, hipMemcpyDeviceToDevice, stream);

    // ---- folds (use pp scratch inside rkv; must precede AT/BT transposes) ----
    fold_pass1_z<<<dim3(20, 16, 3), blk, 0, stream>>>(mu_r, mu_k, mu_v, rW1, kW1, vW1,
                                                      pp, EE, EE, EPAD, 16 * EPAD);
    fold_pass2_z<<<dim3(5, 1, 3), blk, 0, stream>>>(pp, rb1, kb1, vb1, fb_all,
                                                    16, EPAD, 16 * EPAD, EE, EPAD, EPAD);
    fold_pass1_z<<<dim3(2, 16, 3), blk, 0, stream>>>(mu_g, mu_a, mu_d, gA, aA, dA,
                                                     pp, LL, LL, EPAD, 16 * EPAD);
    fold_pass2_z<<<dim3(1, 1, 3), dim3(128), 0, stream>>>(pp, nullptr, nullptr, nullptr, lt_all,
                                                          16, EPAD, 16 * EPAD, LL, LL, LL);
    fold_pass1_z<<<dim3(16, 2, 3), blk, 0, stream>>>(lt_all, lt_all + LL, lt_all + 2 * LL, gB, aB, dB,
                                                     pp, CC, CC, EPAD, 16 * EPAD);
    fold_pass2_z<<<dim3(4, 1, 3), blk, 0, stream>>>(pp, nullptr, ab, db, c2_all,
                                                    2, EPAD, 16 * EPAD, CC, CC, CC);

    // ---- transposes (AT/BT land in rkv after pp is dead) ----
    transpose_cast_z<<<dim3(32, 40, 3), tblk, 0, stream>>>(rW1, kW1, vW1, W1T_all,
                                                           (size_t)EPAD * CC, CC, EE, CC, EPAD);
    transpose_cast_z<<<dim3(40, 32, 3), tblk, 0, stream>>>(rW2, kW2, vW2, W2T_all,
                                                           (size_t)CC * EPAD, EE, CC, EPAD, CC);
    transpose_cast_z<<<dim3(32, 4, 3), tblk, 0, stream>>>(gA, aA, dA, AT_all,
                                                          (size_t)LL * CC, CC, LL, CC, LL);
    transpose_cast_z<<<dim3(4, 32, 3), tblk, 0, stream>>>(gB, aB, dB, BT_all,
                                                          (size_t)CC * LL, LL, CC, LL, CC);

    // ---- cast q ----
    cast_f32_bf16<<<dim3(MM * CC / 4 / 256), blk, 0, stream>>>(q, qb, MM * CC / 4);

    // ---- LoRA A-stage fused (N=384) -> tgad (aliases Hb) ----
    gemm_mfma<0,1,0><<<dim3(3, 64, 1), blk, 0, stream>>>(qb, AT_all, nullptr, tgad,
                                                         MM, 384, CC, CC, CC, 384, 0, 0, 0, 0);
    // ---- LoRA B-stage: gate(sig,bf16), iclr(sig,bf16), decay(decay,bf16) ----
    gemm_mfma<2,1,0><<<dim3(8, 64, 1), blk, 0, stream>>>(tgad,       BT_all,               c2_all,          gbuf,
                                                         MM, CC, LL, 384, LL, CC, 0, 0, 0, 0);
    gemm_mfma<2,1,0><<<dim3(8, 64, 1), blk, 0, stream>>>(tgad + LL,  BT_all + (size_t)CC * LL,  c2_all + CC,     abuf,
                                                         MM, CC, LL, 384, LL, CC, 0, 0, 0, 0);
    gemm_mfma<3,1,0><<<dim3(8, 64, 1), blk, 0, stream>>>(tgad + 2 * LL, BT_all + (size_t)2 * CC * LL, c2_all + 2 * CC, dbuf,
                                                         MM, CC, LL, 384, LL, CC, 0, 0, 0, 0);

    // ---- MLP r,k fused stage-1 (N=2560), then z-batched stage-2 ----
    gemm_mfma<1,1,0><<<dim3(20, 64, 1), blk, 0, stream>>>(qb, W1T_all, fb_all, Hb,
                                                          MM, 2 * EPAD, CC, CC, CC, 2 * EPAD, 0, 0, 0, 0);
    gemm_mfma<0,0,0><<<dim3(8, 64, 2), blk, 0, stream>>>(Hb, W2T_all, cb2_all, rkv,
                                                         MM, CC, EPAD, 2 * EPAD, EPAD, CC,
                                                         EPAD, (size_t)CC * EPAD, CC, (size_t)MM * CC);
    // ---- MLP v: stage-1 into Hb slice0, stage-2 -> vbuf ----
    gemm_mfma<1,1,0><<<dim3(10, 64, 1), blk, 0, stream>>>(qb, W1T_all + (size_t)2 * EPAD * CC, fb_all + 2 * EPAD, Hb,
                                                          MM, EPAD, CC, CC, CC, EPAD, 0, 0, 0, 0);
    gemm_mfma<0,0,0><<<dim3(8, 64, 1), blk, 0, stream>>>(Hb, W2T_all + (size_t)2 * CC * EPAD, cb2_all + 2 * CC, vbuf,
                                                         MM, CC, EPAD, EPAD, EPAD, CC, 0, 0, 0, 0);

    // ---- recurrence (256 blocks x 1024 threads) -> d_out scratch ----
    recurrence_chunked<<<dim3(BB * HH * NSEG), dim3(1024), 0, stream>>>(
        kbuf, abuf, dbuf, vbuf, rbuf, rem_mult, iclr_mix, bonus_mult, out);

    // ---- o-weight transposes into rkv (r/k/v dead after recurrence) ----
    transpose_cast_z<<<dim3(32, 40, 1), tblk, 0, stream>>>(oW1, oW1, oW1, oW1T,
                                                           0, CC, EE, CC, EPAD);
    transpose_cast_z<<<dim3(40, 32, 1), tblk, 0, stream>>>(oW2, oW2, oW2, oW2T,
                                                           0, EE, CC, EPAD, CC);

    // ---- LN * gate -> qb (bf16) ----
    ln_gate_kernel<<<dim3(MM), blk, 0, stream>>>(out, gbuf, ln_g, ln_b, qb);

    // ---- output MLP ----
    gemm_mfma<1,1,1><<<dim3(10, 64, 1), blk, 0, stream>>>(qb, oW1T, ob1, Hb,
                                                          MM, EE, CC, CC, CC, EPAD, 0, 0, 0, 0);
    gemm_mfma<0,0,0><<<dim3(8, 64, 1), blk, 0, stream>>>(Hb, oW2T, ob2, out,
                                                         MM, CC, EPAD, EPAD, EPAD, CC, 0, 0, 0, 0);
}

// Round 8
// 1096.601 us; speedup vs baseline: 1.5417x; 1.5368x over previous
//
#include <hip/hip_runtime.h>
#include <hip/hip_bf16.h>
#include <math.h>

// LinearAttentionLayerOptimized: B=4, T=2048, C=1024, H=16, N=64, L=128, E=1228
// Round 7: recurrence reverted to the PROVEN 512-thread / 128-VGPR shape
// (round 3: no spill, 619us). 1024-thread blocks are unusable: hipcc pins them
// at 64 VGPRs (hints ignored; rounds 4-6) and the whole body spills (~2.5 GB
// scratch traffic). Kept from rounds 4-6: staggered segments {19,15,15,15},
// bf16 iclr/decay, fused/batched GEMM prologue.

#define BB 4
#define TT 2048
#define CC 1024
#define HH 16
#define NN 64
#define LL 128
#define EE 1228
#define EPAD 1280
#define MM (BB*TT)          // 8192 rows
#define TCH 32
#define NSEG 4
#define WARMCH 4            // 128 warm-up steps; decay<=0.82 -> ~1e-11
#define DECAY_C_F 0.7408182206817179f

typedef __attribute__((ext_vector_type(8))) short s16x8;
typedef __attribute__((ext_vector_type(4))) float f32x4;

#define GLOAD_LDS16(gp, lp) \
    __builtin_amdgcn_global_load_lds((const __attribute__((address_space(1))) void*)(gp), \
                                     (__attribute__((address_space(3))) void*)(lp), 16, 0, 0)

// ---------------- z-batched two-pass bias folds ----------------
__global__ __launch_bounds__(256) void fold_pass1_z(
    const float* __restrict__ mu0, const float* __restrict__ mu1, const float* __restrict__ mu2,
    const float* __restrict__ W0,  const float* __restrict__ W1_, const float* __restrict__ W2_,
    float* __restrict__ partial, int ldW, int E, int ldP, int pslice) {
    const float* mu = blockIdx.z == 0 ? mu0 : (blockIdx.z == 1 ? mu1 : mu2);
    const float* W  = blockIdx.z == 0 ? W0  : (blockIdx.z == 1 ? W1_ : W2_);
    partial += (size_t)blockIdx.z * pslice;
    const int l = threadIdx.x & 63;
    const int e = blockIdx.x * 64 + l;
    const int pg = threadIdx.x >> 6;
    const int c0 = blockIdx.y * 64;
    float s = 0.f;
    if (e < E)
        for (int c = c0 + pg; c < c0 + 64; c += 4) s += mu[c] * W[(size_t)c * ldW + e];
    __shared__ float red[4][64];
    red[pg][l] = s;
    __syncthreads();
    if (pg == 0 && e < E)
        partial[(size_t)blockIdx.y * ldP + e] = red[0][l] + red[1][l] + red[2][l] + red[3][l];
}

__global__ void fold_pass2_z(const float* __restrict__ partial,
                             const float* b0, const float* b1, const float* b2,
                             float* __restrict__ outv,
                             int P, int ldP, int pslice, int E, int Epad, int oslice) {
    const float* bias = blockIdx.z == 0 ? b0 : (blockIdx.z == 1 ? b1 : b2);
    partial += (size_t)blockIdx.z * pslice;
    outv    += (size_t)blockIdx.z * oslice;
    int e = blockIdx.x * blockDim.x + threadIdx.x;
    if (e >= Epad) return;
    float s = 0.f;
    if (e < E) {
        s = bias ? bias[e] : 0.f;
        for (int p = 0; p < P; ++p) s += partial[(size_t)p * ldP + e];
    }
    outv[e] = s;
}

// ---------------- cast / z-batched transpose-cast ----------------
__global__ void cast_f32_bf16(const float* __restrict__ in, __hip_bfloat16* __restrict__ out, int n4) {
    int i = blockIdx.x * blockDim.x + threadIdx.x;
    if (i >= n4) return;
    float4 v = ((const float4*)in)[i];
    __hip_bfloat16 o[4] = {__float2bfloat16(v.x), __float2bfloat16(v.y),
                           __float2bfloat16(v.z), __float2bfloat16(v.w)};
    *(ulong1*)&out[i * 4] = *(ulong1*)o;
}

__global__ void transpose_cast_z(const float* s0, const float* s1, const float* s2,
                                 __hip_bfloat16* __restrict__ outT, size_t dslice,
                                 int Rin, int Cin, int Rpad, int Cpad) {
    const float* in = blockIdx.z == 0 ? s0 : (blockIdx.z == 1 ? s1 : s2);
    outT += (size_t)blockIdx.z * dslice;
    __shared__ float t[32][33];
    const int r0 = blockIdx.x * 32, c0 = blockIdx.y * 32;
    const int tx = threadIdx.x, ty = threadIdx.y;   // 32 x 8
    #pragma unroll
    for (int j = 0; j < 4; ++j) {
        int r = r0 + ty + j * 8, c = c0 + tx;
        t[ty + j * 8][tx] = (r < Rin && c < Cin) ? in[(size_t)r * Cin + c] : 0.f;
    }
    __syncthreads();
    #pragma unroll
    for (int j = 0; j < 4; ++j) {
        int c = c0 + ty + j * 8, r = r0 + tx;
        if (c < Cpad && r < Rpad) outT[(size_t)c * Rpad + r] = __float2bfloat16(t[tx][ty + j * 8]);
    }
}

// ---------------- bf16 MFMA GEMM (z-batched) ----------------
template<int ACT, int OBF, int PADZ>
__global__ __launch_bounds__(256) void gemm_mfma(const __hip_bfloat16* __restrict__ A,
                                                 const __hip_bfloat16* __restrict__ Bt,
                                                 const float* __restrict__ bias,
                                                 void* __restrict__ Cptr,
                                                 int M, int N, int K,
                                                 int ldA, int ldB, int ldC,
                                                 size_t zA, size_t zB, size_t zBias, size_t zC) {
    __shared__ __hip_bfloat16 As[128 * 32];
    __shared__ __hip_bfloat16 Bs[128 * 32];
    const int tid = threadIdx.x;
    const int wid = tid >> 6, lane = tid & 63;
    const int wm = wid >> 1, wn = wid & 1;
    const int bm = blockIdx.y * 128, bn = blockIdx.x * 128;
    A  += (size_t)blockIdx.z * zA;
    Bt += (size_t)blockIdx.z * zB;
    if (bias) bias += (size_t)blockIdx.z * zBias;
    const size_t zc = (size_t)blockIdx.z * zC;

    const __hip_bfloat16* srcA[2];
    const __hip_bfloat16* srcB[2];
    #pragma unroll
    for (int i = 0; i < 2; ++i) {
        int off = (wid * 2 + i) * 1024 + lane * 16;
        int r = off >> 6;
        int c = (off >> 4) & 3;
        int cs = c ^ ((r >> 1) & 3);
        srcA[i] = A  + (size_t)(bm + r) * ldA + cs * 8;
        srcB[i] = Bt + (size_t)(bn + r) * ldB + cs * 8;
    }

    f32x4 acc[4][4];
    #pragma unroll
    for (int i = 0; i < 4; ++i)
        #pragma unroll
        for (int j = 0; j < 4; ++j) acc[i][j] = (f32x4){0.f, 0.f, 0.f, 0.f};

    for (int k0 = 0; k0 < K; k0 += 32) {
        #pragma unroll
        for (int i = 0; i < 2; ++i) {
            GLOAD_LDS16(srcA[i] + k0, (char*)As + (wid * 2 + i) * 1024);
            GLOAD_LDS16(srcB[i] + k0, (char*)Bs + (wid * 2 + i) * 1024);
        }
        __syncthreads();
        s16x8 af[4], bfr[4];
        #pragma unroll
        for (int mi = 0; mi < 4; ++mi) {
            int r = wm * 64 + mi * 16 + (lane & 15);
            int c = (lane >> 4) ^ ((r >> 1) & 3);
            af[mi] = *(const s16x8*)((const char*)As + r * 64 + c * 16);
        }
        #pragma unroll
        for (int ni = 0; ni < 4; ++ni) {
            int r = wn * 64 + ni * 16 + (lane & 15);
            int c = (lane >> 4) ^ ((r >> 1) & 3);
            bfr[ni] = *(const s16x8*)((const char*)Bs + r * 64 + c * 16);
        }
        #pragma unroll
        for (int mi = 0; mi < 4; ++mi)
            #pragma unroll
            for (int ni = 0; ni < 4; ++ni)
                acc[mi][ni] = __builtin_amdgcn_mfma_f32_16x16x32_bf16(af[mi], bfr[ni], acc[mi][ni], 0, 0, 0);
        __syncthreads();
    }

    #pragma unroll
    for (int ni = 0; ni < 4; ++ni) {
        const int col = bn + wn * 64 + ni * 16 + (lane & 15);
        const bool valid = (col < N);
        const float bc = (valid && bias) ? bias[col] : 0.f;
        #pragma unroll
        for (int mi = 0; mi < 4; ++mi) {
            #pragma unroll
            for (int reg = 0; reg < 4; ++reg) {
                const int row = bm + wm * 64 + mi * 16 + (lane >> 4) * 4 + reg;
                float y = 0.f;
                if (valid) {
                    float x = acc[mi][ni][reg] + bc;
                    if (ACT == 1)      y = 0.5f * x * (1.0f + erff(x * 0.7071067811865475f));
                    else if (ACT == 2) y = 1.0f / (1.0f + expf(-x));
                    else if (ACT == 3) { float sg = 1.0f / (1.0f + expf(-tanhf(x))); y = expf(-DECAY_C_F * sg); }
                    else               y = x;
                }
                if (valid || PADZ) {
                    if (OBF) ((__hip_bfloat16*)Cptr)[zc + (size_t)row * ldC + col] = __float2bfloat16(y);
                    else     ((float*)Cptr)[zc + (size_t)row * ldC + col] = y;
                }
            }
        }
    }
}

// ---------------- segment-parallel chunked recurrence (512 threads, 8 waves) ----------------
// PROVEN spill-free shape (round 3): 512 threads -> hipcc allocates 128 VGPRs.
#define P_T0(i,j)   pool[0     + (i)*68 + (j)]
#define P_WT(i,j)   pool[4352  + (i)*68 + (j)]
#define P_KP(i,j)   pool[6528  + (i)*68 + (j)]
#define P_P2t(i,j)  pool[6528  + (i)*36 + (j)]   // aliases KP (dead after phase2)
#define P_NU(i,j)   pool[8704  + (i)*68 + (j)]
#define P_GRt(i,j)  pool[8704  + (i)*36 + (j)]   // aliases NU (dead after phase2)
#define P_RKM(i,j)  pool[10880 + (i)*68 + (j)]
#define P_RRM(i,j)  pool[13056 + (i)*68 + (j)]
#define P_GM(i,j)   pool[15232 + (i)*68 + (j)]
#define P_GMT(i,j)  pool[17408 + (i)*36 + (j)]
#define P_KPT(i,j)  pool[19712 + (i)*36 + (j)]
#define P_NUT(i,j)  pool[22016 + (i)*36 + (j)]
#define P_RKMT(i,j) pool[24320 + (i)*36 + (j)]
#define P_DCT(i,j)  pool[26624 + (i)*36 + (j)]
#define P_AT(i,j)   pool[28928 + (i)*36 + (j)]
#define P_BM(i,j)   pool[30080 + (i)*36 + (j)]
#define P_SEG(i,j)  pool[31232 + (i)*64 + (j)]
#define LD4(expr)   (*(const float4*)&(expr))

__global__ __launch_bounds__(512) void recurrence_chunked(
    const float* __restrict__ kbuf, const __hip_bfloat16* __restrict__ iclr,
    const __hip_bfloat16* __restrict__ dbuf, const float* __restrict__ vbuf,
    const float* __restrict__ rbuf,
    const float* __restrict__ rem_mult, const float* __restrict__ iclr_mix,
    const float* __restrict__ bonus_mult, float* __restrict__ outb) {
    __shared__ float pool[31488];   // 123 KB
    const int bh = blockIdx.x & 63, seg = blockIdx.x >> 6;
    const int b = bh >> 4, h = bh & 15;
    const int tid = threadIdx.x, lane = tid & 63, wid = tid >> 6;
    const size_t gbase = ((size_t)b * TT) * CC + (size_t)h * NN;

    for (int i = tid; i < 4352; i += 512) pool[i] = 0.f;   // T0 = 0 at segment start
    const int c0 = tid & 63;
    const float remc = rem_mult[h * NN + c0];
    const float mixc = iclr_mix[h * NN + c0];
    __syncthreads();

    // staggered segments: lengths {19,15,15,15}; warm-up 4 chunks for seg>0 -> 19 chunks/block
    const int cout0 = (seg == 0) ? 0 : 19 + (seg - 1) * 15;
    const int ce    = cout0 + ((seg == 0) ? 19 : 15);
    const int cb    = (seg == 0) ? 0 : cout0 - WARMCH;

    for (int chk = cb; chk < ce; ++chk) {
        const bool emit = (chk >= cout0);
        const int tg0 = chk * TCH;
        // ---- load & elementwise ----
        #pragma unroll
        for (int i = 0; i < 4; ++i) {
            int idx = tid + 512 * i;
            int t = idx >> 6, c = idx & 63;
            size_t off = gbase + (size_t)(tg0 + t) * CC + c;
            float kx = kbuf[off];
            float ax = __bfloat162float(iclr[off]);
            float rk = kx * (1.f + (ax - 1.f) * mixc);
            P_WT(t, c) = ax;
            P_KP(t, c) = kx * remc;
            P_RKM(t, c) = rk; P_RKMT(c, t) = rk;
            P_NU(t, c) = vbuf[off];
            if (emit) P_RRM(t, c) = rbuf[off];
            P_DCT(c, t) = __bfloat162float(dbuf[off]);
        }
        __syncthreads();
        // ---- row norms ----
        #pragma unroll
        for (int rr = 0; rr < 4; ++rr) {
            int t = wid + rr * 8;
            float v = P_KP(t, lane);
            float ss = v * v;
            #pragma unroll
            for (int s = 32; s; s >>= 1) ss += __shfl_xor(ss, s);
            float kn = v / fmaxf(sqrtf(ss), 1e-12f);
            P_KP(t, lane) = kn;
            P_WT(t, lane) = P_WT(t, lane) * kn;
        }
        __syncthreads();
        // ---- segmented cumprod + scaled quantities (256 threads) ----
        float lc[8];
        int ccs = tid & 63, sgm = tid >> 6, t0s = (sgm & 3) * 8;
        if (tid < 256) {
            float pp = 1.f;
            #pragma unroll
            for (int j = 0; j < 8; ++j) { pp *= P_DCT(ccs, t0s + j); lc[j] = pp; }
            P_SEG(sgm, ccs) = pp;
        }
        __syncthreads();
        if (tid < 256) {
            float m = 1.f;
            for (int s = 0; s < sgm; ++s) m *= P_SEG(s, ccs);
            float dcprev = m;
            #pragma unroll
            for (int j = 0; j < 8; ++j) {
                int t = t0s + j;
                float dcur = m * lc[j];
                P_WT(t, ccs) *= dcprev;
                float inv = 1.f / dcur;
                float kap = P_KP(t, ccs) * inv; P_KP(t, ccs) = kap; P_KPT(ccs, t) = kap;
                float nu  = P_NU(t, ccs) * inv; P_NU(t, ccs) = nu;  P_NUT(ccs, t) = nu;
                P_DCT(ccs, t) = dcur;
                dcprev = dcur;
            }
        }
        __syncthreads();
        // ---- phase2: AT, BM, WT.T0 -> GM (64 tiles over 8 waves) ----
        for (int tile = wid; tile < 64; tile += 8) {
            if (tile < 16) {
                int s = (tile >> 2) * 8 + (lane >> 3), t = (tile & 3) * 8 + (lane & 7);
                float acc = 0.f;
                #pragma unroll
                for (int kc = 0; kc < 16; ++kc) {
                    float4 a = LD4(P_KP(s, kc * 4));
                    float4 bb = LD4(P_WT(t, kc * 4));
                    acc += a.x * bb.x + a.y * bb.y + a.z * bb.z + a.w * bb.w;
                }
                P_AT(s, t) = (s < t) ? acc : 0.f;
            } else if (tile < 32) {
                int t = ((tile - 16) >> 2) * 8 + (lane >> 3), s = ((tile - 16) & 3) * 8 + (lane & 7);
                float acc = 0.f;
                #pragma unroll
                for (int kc = 0; kc < 16; ++kc) {
                    float4 a = LD4(P_WT(t, kc * 4));
                    float4 bb = LD4(P_NU(s, kc * 4));
                    acc += a.x * bb.x + a.y * bb.y + a.z * bb.z + a.w * bb.w;
                }
                P_BM(t, s) = (s < t) ? acc : 0.f;
            } else {
                int tt = tile - 32;
                int t = (tt >> 3) * 8 + (lane >> 3), q = (tt & 7) * 8 + (lane & 7);
                float acc = 0.f;
                #pragma unroll
                for (int j4 = 0; j4 < 16; ++j4) {
                    float4 a = LD4(P_WT(t, j4 * 4));
                    acc += a.x * P_T0(j4 * 4 + 0, q) + a.y * P_T0(j4 * 4 + 1, q)
                         + a.z * P_T0(j4 * 4 + 2, q) + a.w * P_T0(j4 * 4 + 3, q);
                }
                P_GM(t, q) = acc;
            }
        }
        __syncthreads();
        // ---- phase3: GM += BM . RKM (32 tiles) ----
        for (int tile = wid; tile < 32; tile += 8) {
            int t = (tile >> 3) * 8 + (lane >> 3), q = (tile & 7) * 8 + (lane & 7);
            float acc = 0.f;
            #pragma unroll
            for (int s4 = 0; s4 < 8; ++s4) {
                float4 a = LD4(P_BM(t, s4 * 4));
                acc += a.x * P_RKM(s4 * 4 + 0, q) + a.y * P_RKM(s4 * 4 + 1, q)
                     + a.z * P_RKM(s4 * 4 + 2, q) + a.w * P_RKM(s4 * 4 + 3, q);
            }
            P_GM(t, q) += acc;
        }
        __syncthreads();
        // ---- phase4: wave0 forward substitution (g[32], 128 VGPR -> no spill)
        //      || waves1-7: P2t (emit only) ----
        if (wid == 0) {
            float g[32];
            #pragma unroll
            for (int t = 0; t < 32; ++t) g[t] = P_GM(t, lane);
            #pragma unroll
            for (int s = 0; s < 31; ++s) {
                #pragma unroll
                for (int t = s + 1; t < 32; ++t) g[t] -= P_AT(s, t) * g[s];
            }
            #pragma unroll
            for (int t = 0; t < 32; ++t) { P_GM(t, lane) = g[t]; P_GMT(lane, t) = g[t]; }
        } else if (emit) {
            for (int tile = wid - 1; tile < 16; tile += 7) {
                int t = (tile >> 2) * 8 + (lane >> 3), s = (tile & 3) * 8 + (lane & 7);
                float acc = 0.f;
                #pragma unroll
                for (int kc = 0; kc < 16; ++kc) {
                    float4 a = LD4(P_RRM(t, kc * 4));
                    float4 bb = LD4(P_RKM(s, kc * 4));
                    acc += a.x * bb.x + a.y * bb.y + a.z * bb.z + a.w * bb.w;
                }
                P_P2t(t, s) = (s <= t) ? acc : 0.f;
            }
        }
        __syncthreads();
        if (emit) {
            // ---- phase5: GRt[t][s] = g_s . r_t (16 tiles) ----
            for (int tile = wid; tile < 16; tile += 8) {
                int t = (tile >> 2) * 8 + (lane >> 3), s = (tile & 3) * 8 + (lane & 7);
                float acc = 0.f;
                #pragma unroll
                for (int kc = 0; kc < 16; ++kc) {
                    float4 a = LD4(P_RRM(t, kc * 4));
                    float4 bb = LD4(P_GM(s, kc * 4));
                    acc += a.x * bb.x + a.y * bb.y + a.z * bb.z + a.w * bb.w;
                }
                P_GRt(t, s) = (s <= t) ? acc : 0.f;
            }
            __syncthreads();
            // ---- phase6a: outputs (32 tiles) ----
            for (int tile = wid; tile < 32; tile += 8) {
                int i = (tile >> 2) * 8 + (lane >> 3), t = (tile & 3) * 8 + (lane & 7);
                float a1 = 0.f, a2 = 0.f, a3 = 0.f;
                #pragma unroll
                for (int j4 = 0; j4 < 16; ++j4) {
                    float4 a = LD4(P_T0(i, j4 * 4));
                    float4 bb = LD4(P_RRM(t, j4 * 4));
                    a1 += a.x * bb.x + a.y * bb.y + a.z * bb.z + a.w * bb.w;
                }
                #pragma unroll
                for (int s4 = 0; s4 < 8; ++s4) {
                    float4 a = LD4(P_NUT(i, s4 * 4));
                    float4 bb = LD4(P_P2t(t, s4 * 4));
                    a2 += a.x * bb.x + a.y * bb.y + a.z * bb.z + a.w * bb.w;
                    float4 c = LD4(P_KPT(i, s4 * 4));
                    float4 d = LD4(P_GRt(t, s4 * 4));
                    a3 += c.x * d.x + c.y * d.y + c.z * d.z + c.w * d.w;
                }
                float diag = 0.2f * bonus_mult[h * NN + i] * P_NUT(i, t) * P_P2t(t, t);
                outb[gbase + (size_t)(tg0 + t) * CC + i] = P_DCT(i, t) * (a1 + a2 + diag - a3);
            }
            __syncthreads();
        }
        // ---- phase6b: T0 <- dc_end * (T0 - Kap^T G + Nu^T RK) (64 tiles) ----
        for (int tile = wid; tile < 64; tile += 8) {
            int pr = (tile >> 3) * 8 + (lane >> 3), q = (tile & 7) * 8 + (lane & 7);
            float a1 = 0.f, a2 = 0.f;
            #pragma unroll
            for (int s4 = 0; s4 < 8; ++s4) {
                float4 a = LD4(P_KPT(pr, s4 * 4));
                float4 bb = LD4(P_GMT(q, s4 * 4));
                a1 += a.x * bb.x + a.y * bb.y + a.z * bb.z + a.w * bb.w;
                float4 c = LD4(P_NUT(pr, s4 * 4));
                float4 d = LD4(P_RKMT(q, s4 * 4));
                a2 += c.x * d.x + c.y * d.y + c.z * d.z + c.w * d.w;
            }
            P_T0(pr, q) = P_DCT(pr, 31) * (P_T0(pr, q) - a1 + a2);
        }
        __syncthreads();
    }
}

// ---------------- LayerNorm * gate (bf16 out) ----------------
__global__ __launch_bounds__(256) void ln_gate_kernel(const float* __restrict__ x,
                                                      const __hip_bfloat16* __restrict__ gate,
                                                      const float* __restrict__ g,
                                                      const float* __restrict__ bv,
                                                      __hip_bfloat16* __restrict__ y) {
    const int row = blockIdx.x;
    const float* xr = x + (size_t)row * CC;
    float v[4];
    float s = 0.f;
    #pragma unroll
    for (int j = 0; j < 4; ++j) { v[j] = xr[threadIdx.x + 256 * j]; s += v[j]; }
    __shared__ float red[4], red2[4];
    #pragma unroll
    for (int o = 32; o; o >>= 1) s += __shfl_xor(s, o);
    if ((threadIdx.x & 63) == 0) red[threadIdx.x >> 6] = s;
    __syncthreads();
    const float mean = (red[0] + red[1] + red[2] + red[3]) * (1.f / CC);
    float vs = 0.f;
    #pragma unroll
    for (int j = 0; j < 4; ++j) { float d = v[j] - mean; vs += d * d; }
    #pragma unroll
    for (int o = 32; o; o >>= 1) vs += __shfl_xor(vs, o);
    if ((threadIdx.x & 63) == 0) red2[threadIdx.x >> 6] = vs;
    __syncthreads();
    const float var = (red2[0] + red2[1] + red2[2] + red2[3]) * (1.f / CC);
    const float rstd = rsqrtf(var + 1e-6f);
    #pragma unroll
    for (int j = 0; j < 4; ++j) {
        const int cc = threadIdx.x + 256 * j;
        float o_ = (v[j] - mean) * rstd * g[cc] + bv[cc];
        float gt = __bfloat162float(gate[(size_t)row * CC + cc]);
        y[(size_t)row * CC + cc] = __float2bfloat16(o_ * gt);
    }
}

// ---------------- launch ----------------
extern "C" void kernel_launch(void* const* d_in, const int* in_sizes, int n_in,
                              void* d_out, int out_size, void* d_ws, size_t ws_size,
                              hipStream_t stream) {
    const float* q        = (const float*)d_in[0];
    const float* mu_r     = (const float*)d_in[4];
    const float* mu_k     = (const float*)d_in[5];
    const float* mu_v     = (const float*)d_in[6];
    const float* mu_g     = (const float*)d_in[7];
    const float* mu_a     = (const float*)d_in[8];
    const float* mu_d     = (const float*)d_in[9];
    const float* dA       = (const float*)d_in[10];
    const float* dB       = (const float*)d_in[11];
    const float* db       = (const float*)d_in[12];
    const float* aA       = (const float*)d_in[13];
    const float* aB       = (const float*)d_in[14];
    const float* ab       = (const float*)d_in[15];
    const float* gA       = (const float*)d_in[16];
    const float* gB       = (const float*)d_in[17];
    const float* rW1      = (const float*)d_in[18];
    const float* rb1      = (const float*)d_in[19];
    const float* rW2      = (const float*)d_in[20];
    const float* rb2      = (const float*)d_in[21];
    const float* kW1      = (const float*)d_in[22];
    const float* kb1      = (const float*)d_in[23];
    const float* kW2      = (const float*)d_in[24];
    const float* kb2      = (const float*)d_in[25];
    const float* vW1      = (const float*)d_in[26];
    const float* vb1      = (const float*)d_in[27];
    const float* vW2      = (const float*)d_in[28];
    const float* vb2      = (const float*)d_in[29];
    const float* oW1      = (const float*)d_in[30];
    const float* ob1      = (const float*)d_in[31];
    const float* oW2      = (const float*)d_in[32];
    const float* ob2      = (const float*)d_in[33];
    const float* rem_mult = (const float*)d_in[34];
    const float* iclr_mix = (const float*)d_in[35];
    const float* bonus_mult = (const float*)d_in[36];
    const float* ln_g     = (const float*)d_in[37];
    const float* ln_b     = (const float*)d_in[38];
    float* out = (float*)d_out;

    // ---- workspace arena (~225 MB) ----
    char* p = (char*)d_ws;
    auto alloc = [&](size_t bytes) { char* r = p; p += (bytes + 255) & ~(size_t)255; return r; };
    float* fb_all  = (float*)alloc((size_t)3 * EPAD * 4);   // folded stage-1 biases r,k,v (pad-zeroed)
    float* c2_all  = (float*)alloc((size_t)3 * CC * 4);     // folded LoRA-B biases g,a,d
    float* lt_all  = (float*)alloc((size_t)3 * LL * 4);     // folded LoRA-A temps
    float* cb2_all = (float*)alloc((size_t)3 * CC * 4);     // rb2,kb2,vb2 gathered
    __hip_bfloat16* qb      = (__hip_bfloat16*)alloc((size_t)MM * CC * 2);       // q bf16; later ln_out
    __hip_bfloat16* W1T_all = (__hip_bfloat16*)alloc((size_t)3 * EPAD * CC * 2); // r,k,v W1^T
    __hip_bfloat16* W2T_all = (__hip_bfloat16*)alloc((size_t)3 * CC * EPAD * 2); // r,k,v W2^T
    __hip_bfloat16* Hb      = (__hip_bfloat16*)alloc((size_t)MM * 2 * EPAD * 2); // fused H (r,k); v reuses slice0
    float*          rkv     = (float*)alloc((size_t)3 * MM * CC * 4);            // r,k,v fp32
    __hip_bfloat16* abuf    = (__hip_bfloat16*)alloc((size_t)MM * CC * 2);       // iclr bf16
    __hip_bfloat16* dbuf    = (__hip_bfloat16*)alloc((size_t)MM * CC * 2);       // decay bf16
    __hip_bfloat16* gbuf    = (__hip_bfloat16*)alloc((size_t)MM * CC * 2);       // gate bf16
    float* rbuf = rkv;
    float* kbuf = rkv + (size_t)MM * CC;
    float* vbuf = rkv + (size_t)2 * MM * CC;
    // time-multiplexed tenants of the rkv arena:
    float*          pp      = rkv;                                         // fold partials (240 KB, dies before AT/BT)
    __hip_bfloat16* AT_all  = (__hip_bfloat16*)((char*)rkv + (1 << 18));   // LoRA A^T
    __hip_bfloat16* BT_all  = (__hip_bfloat16*)((char*)rkv + (1 << 18) + 786432);
    __hip_bfloat16* oW1T    = (__hip_bfloat16*)rkv;                        // written after recurrence
    __hip_bfloat16* oW2T    = (__hip_bfloat16*)((char*)rkv + 4194304);
    __hip_bfloat16* tgad    = Hb;                                          // LoRA intermediates [M][384]

    const dim3 blk(256);
    const dim3 tblk(32, 8);

    // gather stage-2 biases (device-to-device, capture-safe)
    hipMemcpyAsync(cb2_all,          rb2, CC * 4, hipMemcpyDeviceToDevice, stream);
    hipMemcpyAsync(cb2_all + CC,     kb2, CC * 4, hipMemcpyDeviceToDevice, stream);
    hipMemcpyAsync(cb2_all + 2 * CC, vb2, CC * 4, hipMemcpyDeviceToDevice, stream);

    // ---- folds (use pp scratch inside rkv; must precede AT/BT transposes) ----
    fold_pass1_z<<<dim3(20, 16, 3), blk, 0, stream>>>(mu_r, mu_k, mu_v, rW1, kW1, vW1,
                                                      pp, EE, EE, EPAD, 16 * EPAD);
    fold_pass2_z<<<dim3(5, 1, 3), blk, 0, stream>>>(pp, rb1, kb1, vb1, fb_all,
                                                    16, EPAD, 16 * EPAD, EE, EPAD, EPAD);
    fold_pass1_z<<<dim3(2, 16, 3), blk, 0, stream>>>(mu_g, mu_a, mu_d, gA, aA, dA,
                                                     pp, LL, LL, EPAD, 16 * EPAD);
    fold_pass2_z<<<dim3(1, 1, 3), dim3(128), 0, stream>>>(pp, nullptr, nullptr, nullptr, lt_all,
                                                          16, EPAD, 16 * EPAD, LL, LL, LL);
    fold_pass1_z<<<dim3(16, 2, 3), blk, 0, stream>>>(lt_all, lt_all + LL, lt_all + 2 * LL, gB, aB, dB,
                                                     pp, CC, CC, EPAD, 16 * EPAD);
    fold_pass2_z<<<dim3(4, 1, 3), blk, 0, stream>>>(pp, nullptr, ab, db, c2_all,
                                                    2, EPAD, 16 * EPAD, CC, CC, CC);

    // ---- transposes (AT/BT land in rkv after pp is dead) ----
    transpose_cast_z<<<dim3(32, 40, 3), tblk, 0, stream>>>(rW1, kW1, vW1, W1T_all,
                                                           (size_t)EPAD * CC, CC, EE, CC, EPAD);
    transpose_cast_z<<<dim3(40, 32, 3), tblk, 0, stream>>>(rW2, kW2, vW2, W2T_all,
                                                           (size_t)CC * EPAD, EE, CC, EPAD, CC);
    transpose_cast_z<<<dim3(32, 4, 3), tblk, 0, stream>>>(gA, aA, dA, AT_all,
                                                          (size_t)LL * CC, CC, LL, CC, LL);
    transpose_cast_z<<<dim3(4, 32, 3), tblk, 0, stream>>>(gB, aB, dB, BT_all,
                                                          (size_t)CC * LL, LL, CC, LL, CC);

    // ---- cast q ----
    cast_f32_bf16<<<dim3(MM * CC / 4 / 256), blk, 0, stream>>>(q, qb, MM * CC / 4);

    // ---- LoRA A-stage fused (N=384) -> tgad (aliases Hb) ----
    gemm_mfma<0,1,0><<<dim3(3, 64, 1), blk, 0, stream>>>(qb, AT_all, nullptr, tgad,
                                                         MM, 384, CC, CC, CC, 384, 0, 0, 0, 0);
    // ---- LoRA B-stage: gate(sig,bf16), iclr(sig,bf16), decay(decay,bf16) ----
    gemm_mfma<2,1,0><<<dim3(8, 64, 1), blk, 0, stream>>>(tgad,       BT_all,               c2_all,          gbuf,
                                                         MM, CC, LL, 384, LL, CC, 0, 0, 0, 0);
    gemm_mfma<2,1,0><<<dim3(8, 64, 1), blk, 0, stream>>>(tgad + LL,  BT_all + (size_t)CC * LL,  c2_all + CC,     abuf,
                                                         MM, CC, LL, 384, LL, CC, 0, 0, 0, 0);
    gemm_mfma<3,1,0><<<dim3(8, 64, 1), blk, 0, stream>>>(tgad + 2 * LL, BT_all + (size_t)2 * CC * LL, c2_all + 2 * CC, dbuf,
                                                         MM, CC, LL, 384, LL, CC, 0, 0, 0, 0);

    // ---- MLP r,k fused stage-1 (N=2560), then z-batched stage-2 ----
    gemm_mfma<1,1,0><<<dim3(20, 64, 1), blk, 0, stream>>>(qb, W1T_all, fb_all, Hb,
                                                          MM, 2 * EPAD, CC, CC, CC, 2 * EPAD, 0, 0, 0, 0);
    gemm_mfma<0,0,0><<<dim3(8, 64, 2), blk, 0, stream>>>(Hb, W2T_all, cb2_all, rkv,
                                                         MM, CC, EPAD, 2 * EPAD, EPAD, CC,
                                                         EPAD, (size_t)CC * EPAD, CC, (size_t)MM * CC);
    // ---- MLP v: stage-1 into Hb slice0, stage-2 -> vbuf ----
    gemm_mfma<1,1,0><<<dim3(10, 64, 1), blk, 0, stream>>>(qb, W1T_all + (size_t)2 * EPAD * CC, fb_all + 2 * EPAD, Hb,
                                                          MM, EPAD, CC, CC, CC, EPAD, 0, 0, 0, 0);
    gemm_mfma<0,0,0><<<dim3(8, 64, 1), blk, 0, stream>>>(Hb, W2T_all + (size_t)2 * CC * EPAD, cb2_all + 2 * CC, vbuf,
                                                         MM, CC, EPAD, EPAD, EPAD, CC, 0, 0, 0, 0);

    // ---- recurrence (256 blocks x 512 threads) -> d_out scratch ----
    recurrence_chunked<<<dim3(BB * HH * NSEG), dim3(512), 0, stream>>>(
        kbuf, abuf, dbuf, vbuf, rbuf, rem_mult, iclr_mix, bonus_mult, out);

    // ---- o-weight transposes into rkv (r/k/v dead after recurrence) ----
    transpose_cast_z<<<dim3(32, 40, 1), tblk, 0, stream>>>(oW1, oW1, oW1, oW1T,
                                                           0, CC, EE, CC, EPAD);
    transpose_cast_z<<<dim3(40, 32, 1), tblk, 0, stream>>>(oW2, oW2, oW2, oW2T,
                                                           0, EE, CC, EPAD, CC);

    // ---- LN * gate -> qb (bf16) ----
    ln_gate_kernel<<<dim3(MM), blk, 0, stream>>>(out, gbuf, ln_g, ln_b, qb);

    // ---- output MLP ----
    gemm_mfma<1,1,1><<<dim3(10, 64, 1), blk, 0, stream>>>(qb, oW1T, ob1, Hb,
                                                          MM, EE, CC, CC, CC, EPAD, 0, 0, 0, 0);
    gemm_mfma<0,0,0><<<dim3(8, 64, 1), blk, 0, stream>>>(Hb, oW2T, ob2, out,
                                                         MM, CC, EPAD, EPAD, EPAD, CC, 0, 0, 0, 0);
}

// Round 9
// 939.665 us; speedup vs baseline: 1.7992x; 1.1670x over previous
//
#include <hip/hip_runtime.h>
#include <hip/hip_bf16.h>
#include <math.h>

// LinearAttentionLayerOptimized: B=4, T=2048, C=1024, H=16, N=64, L=128, E=1228
// Round 8: recurrence LDS-instruction diet on the proven 512-thread shape:
//  - GM1/phase3 micro-tiled (wave = 4 GM rows x 64 cols, float4 row reads of T0/RKM)
//  - phase6b de-transposed (KPT/NUT scalars + GM/RKM row reads); GMT/RKMT deleted
//  - norms merged with cumprod-p1 (one barrier fewer)
//  - WARMCH=2 (64 steps, attenuation ~3e-6), stagger {18,16,15,15} -> max 18 chunks

#define BB 4
#define TT 2048
#define CC 1024
#define HH 16
#define NN 64
#define LL 128
#define EE 1228
#define EPAD 1280
#define MM (BB*TT)          // 8192 rows
#define TCH 32
#define NSEG 4
#define WARMCH 2            // 64 warm-up steps; decay<=0.82 -> ~3e-6
#define DECAY_C_F 0.7408182206817179f

typedef __attribute__((ext_vector_type(8))) short s16x8;
typedef __attribute__((ext_vector_type(4))) float f32x4;

#define GLOAD_LDS16(gp, lp) \
    __builtin_amdgcn_global_load_lds((const __attribute__((address_space(1))) void*)(gp), \
                                     (__attribute__((address_space(3))) void*)(lp), 16, 0, 0)

// ---------------- z-batched two-pass bias folds ----------------
__global__ __launch_bounds__(256) void fold_pass1_z(
    const float* __restrict__ mu0, const float* __restrict__ mu1, const float* __restrict__ mu2,
    const float* __restrict__ W0,  const float* __restrict__ W1_, const float* __restrict__ W2_,
    float* __restrict__ partial, int ldW, int E, int ldP, int pslice) {
    const float* mu = blockIdx.z == 0 ? mu0 : (blockIdx.z == 1 ? mu1 : mu2);
    const float* W  = blockIdx.z == 0 ? W0  : (blockIdx.z == 1 ? W1_ : W2_);
    partial += (size_t)blockIdx.z * pslice;
    const int l = threadIdx.x & 63;
    const int e = blockIdx.x * 64 + l;
    const int pg = threadIdx.x >> 6;
    const int c0 = blockIdx.y * 64;
    float s = 0.f;
    if (e < E)
        for (int c = c0 + pg; c < c0 + 64; c += 4) s += mu[c] * W[(size_t)c * ldW + e];
    __shared__ float red[4][64];
    red[pg][l] = s;
    __syncthreads();
    if (pg == 0 && e < E)
        partial[(size_t)blockIdx.y * ldP + e] = red[0][l] + red[1][l] + red[2][l] + red[3][l];
}

__global__ void fold_pass2_z(const float* __restrict__ partial,
                             const float* b0, const float* b1, const float* b2,
                             float* __restrict__ outv,
                             int P, int ldP, int pslice, int E, int Epad, int oslice) {
    const float* bias = blockIdx.z == 0 ? b0 : (blockIdx.z == 1 ? b1 : b2);
    partial += (size_t)blockIdx.z * pslice;
    outv    += (size_t)blockIdx.z * oslice;
    int e = blockIdx.x * blockDim.x + threadIdx.x;
    if (e >= Epad) return;
    float s = 0.f;
    if (e < E) {
        s = bias ? bias[e] : 0.f;
        for (int p = 0; p < P; ++p) s += partial[(size_t)p * ldP + e];
    }
    outv[e] = s;
}

// ---------------- cast / z-batched transpose-cast ----------------
__global__ void cast_f32_bf16(const float* __restrict__ in, __hip_bfloat16* __restrict__ out, int n4) {
    int i = blockIdx.x * blockDim.x + threadIdx.x;
    if (i >= n4) return;
    float4 v = ((const float4*)in)[i];
    __hip_bfloat16 o[4] = {__float2bfloat16(v.x), __float2bfloat16(v.y),
                           __float2bfloat16(v.z), __float2bfloat16(v.w)};
    *(ulong1*)&out[i * 4] = *(ulong1*)o;
}

__global__ void transpose_cast_z(const float* s0, const float* s1, const float* s2,
                                 __hip_bfloat16* __restrict__ outT, size_t dslice,
                                 int Rin, int Cin, int Rpad, int Cpad) {
    const float* in = blockIdx.z == 0 ? s0 : (blockIdx.z == 1 ? s1 : s2);
    outT += (size_t)blockIdx.z * dslice;
    __shared__ float t[32][33];
    const int r0 = blockIdx.x * 32, c0 = blockIdx.y * 32;
    const int tx = threadIdx.x, ty = threadIdx.y;   // 32 x 8
    #pragma unroll
    for (int j = 0; j < 4; ++j) {
        int r = r0 + ty + j * 8, c = c0 + tx;
        t[ty + j * 8][tx] = (r < Rin && c < Cin) ? in[(size_t)r * Cin + c] : 0.f;
    }
    __syncthreads();
    #pragma unroll
    for (int j = 0; j < 4; ++j) {
        int c = c0 + ty + j * 8, r = r0 + tx;
        if (c < Cpad && r < Rpad) outT[(size_t)c * Rpad + r] = __float2bfloat16(t[tx][ty + j * 8]);
    }
}

// ---------------- bf16 MFMA GEMM (z-batched) ----------------
template<int ACT, int OBF, int PADZ>
__global__ __launch_bounds__(256) void gemm_mfma(const __hip_bfloat16* __restrict__ A,
                                                 const __hip_bfloat16* __restrict__ Bt,
                                                 const float* __restrict__ bias,
                                                 void* __restrict__ Cptr,
                                                 int M, int N, int K,
                                                 int ldA, int ldB, int ldC,
                                                 size_t zA, size_t zB, size_t zBias, size_t zC) {
    __shared__ __hip_bfloat16 As[128 * 32];
    __shared__ __hip_bfloat16 Bs[128 * 32];
    const int tid = threadIdx.x;
    const int wid = tid >> 6, lane = tid & 63;
    const int wm = wid >> 1, wn = wid & 1;
    const int bm = blockIdx.y * 128, bn = blockIdx.x * 128;
    A  += (size_t)blockIdx.z * zA;
    Bt += (size_t)blockIdx.z * zB;
    if (bias) bias += (size_t)blockIdx.z * zBias;
    const size_t zc = (size_t)blockIdx.z * zC;

    const __hip_bfloat16* srcA[2];
    const __hip_bfloat16* srcB[2];
    #pragma unroll
    for (int i = 0; i < 2; ++i) {
        int off = (wid * 2 + i) * 1024 + lane * 16;
        int r = off >> 6;
        int c = (off >> 4) & 3;
        int cs = c ^ ((r >> 1) & 3);
        srcA[i] = A  + (size_t)(bm + r) * ldA + cs * 8;
        srcB[i] = Bt + (size_t)(bn + r) * ldB + cs * 8;
    }

    f32x4 acc[4][4];
    #pragma unroll
    for (int i = 0; i < 4; ++i)
        #pragma unroll
        for (int j = 0; j < 4; ++j) acc[i][j] = (f32x4){0.f, 0.f, 0.f, 0.f};

    for (int k0 = 0; k0 < K; k0 += 32) {
        #pragma unroll
        for (int i = 0; i < 2; ++i) {
            GLOAD_LDS16(srcA[i] + k0, (char*)As + (wid * 2 + i) * 1024);
            GLOAD_LDS16(srcB[i] + k0, (char*)Bs + (wid * 2 + i) * 1024);
        }
        __syncthreads();
        s16x8 af[4], bfr[4];
        #pragma unroll
        for (int mi = 0; mi < 4; ++mi) {
            int r = wm * 64 + mi * 16 + (lane & 15);
            int c = (lane >> 4) ^ ((r >> 1) & 3);
            af[mi] = *(const s16x8*)((const char*)As + r * 64 + c * 16);
        }
        #pragma unroll
        for (int ni = 0; ni < 4; ++ni) {
            int r = wn * 64 + ni * 16 + (lane & 15);
            int c = (lane >> 4) ^ ((r >> 1) & 3);
            bfr[ni] = *(const s16x8*)((const char*)Bs + r * 64 + c * 16);
        }
        #pragma unroll
        for (int mi = 0; mi < 4; ++mi)
            #pragma unroll
            for (int ni = 0; ni < 4; ++ni)
                acc[mi][ni] = __builtin_amdgcn_mfma_f32_16x16x32_bf16(af[mi], bfr[ni], acc[mi][ni], 0, 0, 0);
        __syncthreads();
    }

    #pragma unroll
    for (int ni = 0; ni < 4; ++ni) {
        const int col = bn + wn * 64 + ni * 16 + (lane & 15);
        const bool valid = (col < N);
        const float bc = (valid && bias) ? bias[col] : 0.f;
        #pragma unroll
        for (int mi = 0; mi < 4; ++mi) {
            #pragma unroll
            for (int reg = 0; reg < 4; ++reg) {
                const int row = bm + wm * 64 + mi * 16 + (lane >> 4) * 4 + reg;
                float y = 0.f;
                if (valid) {
                    float x = acc[mi][ni][reg] + bc;
                    if (ACT == 1)      y = 0.5f * x * (1.0f + erff(x * 0.7071067811865475f));
                    else if (ACT == 2) y = 1.0f / (1.0f + expf(-x));
                    else if (ACT == 3) { float sg = 1.0f / (1.0f + expf(-tanhf(x))); y = expf(-DECAY_C_F * sg); }
                    else               y = x;
                }
                if (valid || PADZ) {
                    if (OBF) ((__hip_bfloat16*)Cptr)[zc + (size_t)row * ldC + col] = __float2bfloat16(y);
                    else     ((float*)Cptr)[zc + (size_t)row * ldC + col] = y;
                }
            }
        }
    }
}

// ---------------- segment-parallel chunked recurrence (512 threads, 8 waves) ----------------
#define P_T0(i,j)   pool[0     + (i)*68 + (j)]
#define P_WT(i,j)   pool[4352  + (i)*68 + (j)]
#define P_KP(i,j)   pool[6528  + (i)*68 + (j)]
#define P_P2t(i,j)  pool[6528  + (i)*36 + (j)]   // aliases KP (dead after phase2; 6b uses KPT)
#define P_NU(i,j)   pool[8704  + (i)*68 + (j)]
#define P_GRt(i,j)  pool[8704  + (i)*36 + (j)]   // aliases NU (dead after phase2; 6b uses NUT)
#define P_RKM(i,j)  pool[10880 + (i)*68 + (j)]
#define P_RRM(i,j)  pool[13056 + (i)*68 + (j)]
#define P_GM(i,j)   pool[15232 + (i)*68 + (j)]
// hole @17408 (was GMT - deleted)
#define P_KPT(i,j)  pool[19712 + (i)*36 + (j)]
#define P_NUT(i,j)  pool[22016 + (i)*36 + (j)]
// hole @24320 (was RKMT - deleted)
#define P_DCT(i,j)  pool[26624 + (i)*36 + (j)]
#define P_AT(i,j)   pool[28928 + (i)*36 + (j)]
#define P_BM(i,j)   pool[30080 + (i)*36 + (j)]
#define P_SEG(i,j)  pool[31232 + (i)*64 + (j)]
#define LD4(expr)   (*(const float4*)&(expr))
#define FMA4(acc, s, v) { (acc).x = fmaf((s), (v).x, (acc).x); (acc).y = fmaf((s), (v).y, (acc).y); \
                          (acc).z = fmaf((s), (v).z, (acc).z); (acc).w = fmaf((s), (v).w, (acc).w); }

__global__ __launch_bounds__(512) void recurrence_chunked(
    const float* __restrict__ kbuf, const __hip_bfloat16* __restrict__ iclr,
    const __hip_bfloat16* __restrict__ dbuf, const float* __restrict__ vbuf,
    const float* __restrict__ rbuf,
    const float* __restrict__ rem_mult, const float* __restrict__ iclr_mix,
    const float* __restrict__ bonus_mult, float* __restrict__ outb) {
    __shared__ float pool[31488];   // 123 KB
    const int bh = blockIdx.x & 63, seg = blockIdx.x >> 6;
    const int b = bh >> 4, h = bh & 15;
    const int tid = threadIdx.x, lane = tid & 63, wid = tid >> 6;
    const size_t gbase = ((size_t)b * TT) * CC + (size_t)h * NN;

    for (int i = tid; i < 4352; i += 512) pool[i] = 0.f;   // T0 = 0 at segment start
    const int c0 = tid & 63;
    const float remc = rem_mult[h * NN + c0];
    const float mixc = iclr_mix[h * NN + c0];
    __syncthreads();

    // stagger: outputs {18,16,15,15}, warm-up 2 chunks for seg>0 -> max 18 chunks/block
    const int cout0 = (seg == 0) ? 0 : (seg == 1) ? 18 : (seg == 2) ? 34 : 49;
    const int lenq  = (seg == 0) ? 18 : (seg == 1) ? 16 : 15;
    const int ce    = cout0 + lenq;
    const int cb    = (seg == 0) ? 0 : cout0 - WARMCH;

    for (int chk = cb; chk < ce; ++chk) {
        const bool emit = (chk >= cout0);
        const int tg0 = chk * TCH;
        // ---- load & elementwise ----
        #pragma unroll
        for (int i = 0; i < 4; ++i) {
            int idx = tid + 512 * i;
            int t = idx >> 6, c = idx & 63;
            size_t off = gbase + (size_t)(tg0 + t) * CC + c;
            float kx = kbuf[off];
            float ax = __bfloat162float(iclr[off]);
            float rk = kx * (1.f + (ax - 1.f) * mixc);
            P_WT(t, c) = ax;
            P_KP(t, c) = kx * remc;
            P_RKM(t, c) = rk;
            P_NU(t, c) = vbuf[off];
            if (emit) P_RRM(t, c) = rbuf[off];
            P_DCT(c, t) = __bfloat162float(dbuf[off]);
        }
        __syncthreads();
        // ---- merged: row norms (all waves) + cumprod part1 (tid<256) ----
        #pragma unroll
        for (int rr = 0; rr < 4; ++rr) {
            int t = wid + rr * 8;
            float v = P_KP(t, lane);
            float ss = v * v;
            #pragma unroll
            for (int s = 32; s; s >>= 1) ss += __shfl_xor(ss, s);
            float kn = v / fmaxf(sqrtf(ss), 1e-12f);
            P_KP(t, lane) = kn;
            P_WT(t, lane) = P_WT(t, lane) * kn;
        }
        float lc[8];
        const int ccs = tid & 63, sgm = tid >> 6, t0s = (sgm & 3) * 8;
        if (tid < 256) {
            float pp_ = 1.f;
            #pragma unroll
            for (int j = 0; j < 8; ++j) { pp_ *= P_DCT(ccs, t0s + j); lc[j] = pp_; }
            P_SEG(sgm, ccs) = pp_;
        }
        __syncthreads();
        // ---- cumprod part2 + scaled quantities (256 threads) ----
        if (tid < 256) {
            float m = 1.f;
            for (int s = 0; s < sgm; ++s) m *= P_SEG(s, ccs);
            float dcprev = m;
            #pragma unroll
            for (int j = 0; j < 8; ++j) {
                int t = t0s + j;
                float dcur = m * lc[j];
                P_WT(t, ccs) *= dcprev;
                float inv = 1.f / dcur;
                float kap = P_KP(t, ccs) * inv; P_KP(t, ccs) = kap; P_KPT(ccs, t) = kap;
                float nu  = P_NU(t, ccs) * inv; P_NU(t, ccs) = nu;  P_NUT(ccs, t) = nu;
                P_DCT(ccs, t) = dcur;
                dcprev = dcur;
            }
        }
        __syncthreads();
        // ---- phase2: AT (2 tiles/wave) + BM (2 tiles/wave) + GM1 slab (1/wave) ----
        #pragma unroll
        for (int u = 0; u < 2; ++u) {
            const int at = wid * 2 + u;   // 0..15
            const int s = (at >> 2) * 8 + (lane >> 3), t = (at & 3) * 8 + (lane & 7);
            float acc = 0.f;
            #pragma unroll
            for (int kc = 0; kc < 16; ++kc) {
                float4 a = LD4(P_KP(s, kc * 4));
                float4 bb = LD4(P_WT(t, kc * 4));
                acc += a.x * bb.x + a.y * bb.y + a.z * bb.z + a.w * bb.w;
            }
            P_AT(s, t) = (s < t) ? acc : 0.f;
        }
        #pragma unroll
        for (int u = 0; u < 2; ++u) {
            const int bt = wid * 2 + u;   // 0..15
            const int t = (bt >> 2) * 8 + (lane >> 3), s = (bt & 3) * 8 + (lane & 7);
            float acc = 0.f;
            #pragma unroll
            for (int kc = 0; kc < 16; ++kc) {
                float4 a = LD4(P_WT(t, kc * 4));
                float4 bb = LD4(P_NU(s, kc * 4));
                acc += a.x * bb.x + a.y * bb.y + a.z * bb.z + a.w * bb.w;
            }
            P_BM(t, s) = (s < t) ? acc : 0.f;
        }
        {   // GM1: wave owns GM rows [wid*4, wid*4+4) x all 64 q; float4 row reads of T0
            const int t = wid * 4 + (lane >> 4);
            const int q4 = (lane & 15) * 4;
            float4 acc = {0.f, 0.f, 0.f, 0.f};
            #pragma unroll
            for (int j4 = 0; j4 < 16; ++j4) {
                float4 w4 = LD4(P_WT(t, j4 * 4));
                float4 ta = LD4(P_T0(j4 * 4 + 0, q4));
                float4 tb = LD4(P_T0(j4 * 4 + 1, q4));
                float4 tc = LD4(P_T0(j4 * 4 + 2, q4));
                float4 td = LD4(P_T0(j4 * 4 + 3, q4));
                FMA4(acc, w4.x, ta); FMA4(acc, w4.y, tb);
                FMA4(acc, w4.z, tc); FMA4(acc, w4.w, td);
            }
            *(float4*)&P_GM(t, q4) = acc;
        }
        __syncthreads();
        // ---- phase3: GM += BM . RKM (same slab mapping, float4 row reads) ----
        {
            const int t = wid * 4 + (lane >> 4);
            const int q4 = (lane & 15) * 4;
            float4 acc = {0.f, 0.f, 0.f, 0.f};
            #pragma unroll
            for (int s4 = 0; s4 < 8; ++s4) {
                float4 bm4 = LD4(P_BM(t, s4 * 4));
                float4 ra = LD4(P_RKM(s4 * 4 + 0, q4));
                float4 rb = LD4(P_RKM(s4 * 4 + 1, q4));
                float4 rc = LD4(P_RKM(s4 * 4 + 2, q4));
                float4 rd = LD4(P_RKM(s4 * 4 + 3, q4));
                FMA4(acc, bm4.x, ra); FMA4(acc, bm4.y, rb);
                FMA4(acc, bm4.z, rc); FMA4(acc, bm4.w, rd);
            }
            float4 g = LD4(P_GM(t, q4));
            g.x += acc.x; g.y += acc.y; g.z += acc.z; g.w += acc.w;
            *(float4*)&P_GM(t, q4) = g;
        }
        __syncthreads();
        // ---- phase4: wave0 forward substitution (g[32], 128 VGPR -> no spill)
        //      || waves1-7: P2t (emit only) ----
        if (wid == 0) {
            float g[32];
            #pragma unroll
            for (int t = 0; t < 32; ++t) g[t] = P_GM(t, lane);
            #pragma unroll
            for (int s = 0; s < 31; ++s) {
                #pragma unroll
                for (int t = s + 1; t < 32; ++t) g[t] -= P_AT(s, t) * g[s];
            }
            #pragma unroll
            for (int t = 0; t < 32; ++t) P_GM(t, lane) = g[t];
        } else if (emit) {
            for (int tile = wid - 1; tile < 16; tile += 7) {
                int t = (tile >> 2) * 8 + (lane >> 3), s = (tile & 3) * 8 + (lane & 7);
                float acc = 0.f;
                #pragma unroll
                for (int kc = 0; kc < 16; ++kc) {
                    float4 a = LD4(P_RRM(t, kc * 4));
                    float4 bb = LD4(P_RKM(s, kc * 4));
                    acc += a.x * bb.x + a.y * bb.y + a.z * bb.z + a.w * bb.w;
                }
                P_P2t(t, s) = (s <= t) ? acc : 0.f;
            }
        }
        __syncthreads();
        if (emit) {
            // ---- phase5: GRt[t][s] = g_s . r_t (16 tiles) ----
            for (int tile = wid; tile < 16; tile += 8) {
                int t = (tile >> 2) * 8 + (lane >> 3), s = (tile & 3) * 8 + (lane & 7);
                float acc = 0.f;
                #pragma unroll
                for (int kc = 0; kc < 16; ++kc) {
                    float4 a = LD4(P_RRM(t, kc * 4));
                    float4 bb = LD4(P_GM(s, kc * 4));
                    acc += a.x * bb.x + a.y * bb.y + a.z * bb.z + a.w * bb.w;
                }
                P_GRt(t, s) = (s <= t) ? acc : 0.f;
            }
            __syncthreads();
            // ---- phase6a: outputs (32 tiles) ----
            for (int tile = wid; tile < 32; tile += 8) {
                int i = (tile >> 2) * 8 + (lane >> 3), t = (tile & 3) * 8 + (lane & 7);
                float a1 = 0.f, a2 = 0.f, a3 = 0.f;
                #pragma unroll
                for (int j4 = 0; j4 < 16; ++j4) {
                    float4 a = LD4(P_T0(i, j4 * 4));
                    float4 bb = LD4(P_RRM(t, j4 * 4));
                    a1 += a.x * bb.x + a.y * bb.y + a.z * bb.z + a.w * bb.w;
                }
                #pragma unroll
                for (int s4 = 0; s4 < 8; ++s4) {
                    float4 a = LD4(P_NUT(i, s4 * 4));
                    float4 bb = LD4(P_P2t(t, s4 * 4));
                    a2 += a.x * bb.x + a.y * bb.y + a.z * bb.z + a.w * bb.w;
                    float4 c = LD4(P_KPT(i, s4 * 4));
                    float4 d = LD4(P_GRt(t, s4 * 4));
                    a3 += c.x * d.x + c.y * d.y + c.z * d.z + c.w * d.w;
                }
                float diag = 0.2f * bonus_mult[h * NN + i] * P_NUT(i, t) * P_P2t(t, t);
                outb[gbase + (size_t)(tg0 + t) * CC + i] = P_DCT(i, t) * (a1 + a2 + diag - a3);
            }
            __syncthreads();
        }
        // ---- phase6b: T0 <- dc_end * (T0 - Kap^T G + Nu^T RK)
        //      de-transposed: KPT/NUT scalars + GM/RKM float4 row reads; 2 slabs/wave ----
        #pragma unroll
        for (int u = 0; u < 2; ++u) {
            const int m = wid * 2 + u;                       // 0..15
            const int pr = (m & 7) * 8 + (lane >> 3);        // 0..63
            const int q4 = (m >> 3) * 32 + (lane & 7) * 4;   // 0..60
            float4 a1 = {0.f, 0.f, 0.f, 0.f}, a2 = {0.f, 0.f, 0.f, 0.f};
            #pragma unroll
            for (int s = 0; s < 32; ++s) {
                const float kp = P_KPT(pr, s);
                const float nu = P_NUT(pr, s);
                float4 g4 = LD4(P_GM(s, q4));
                float4 rk4 = LD4(P_RKM(s, q4));
                FMA4(a1, kp, g4);
                FMA4(a2, nu, rk4);
            }
            const float dc = P_DCT(pr, 31);
            float4 t0 = LD4(P_T0(pr, q4));
            t0.x = dc * (t0.x - a1.x + a2.x);
            t0.y = dc * (t0.y - a1.y + a2.y);
            t0.z = dc * (t0.z - a1.z + a2.z);
            t0.w = dc * (t0.w - a1.w + a2.w);
            *(float4*)&P_T0(pr, q4) = t0;
        }
        __syncthreads();
    }
}

// ---------------- LayerNorm * gate (bf16 out) ----------------
__global__ __launch_bounds__(256) void ln_gate_kernel(const float* __restrict__ x,
                                                      const __hip_bfloat16* __restrict__ gate,
                                                      const float* __restrict__ g,
                                                      const float* __restrict__ bv,
                                                      __hip_bfloat16* __restrict__ y) {
    const int row = blockIdx.x;
    const float* xr = x + (size_t)row * CC;
    float v[4];
    float s = 0.f;
    #pragma unroll
    for (int j = 0; j < 4; ++j) { v[j] = xr[threadIdx.x + 256 * j]; s += v[j]; }
    __shared__ float red[4], red2[4];
    #pragma unroll
    for (int o = 32; o; o >>= 1) s += __shfl_xor(s, o);
    if ((threadIdx.x & 63) == 0) red[threadIdx.x >> 6] = s;
    __syncthreads();
    const float mean = (red[0] + red[1] + red[2] + red[3]) * (1.f / CC);
    float vs = 0.f;
    #pragma unroll
    for (int j = 0; j < 4; ++j) { float d = v[j] - mean; vs += d * d; }
    #pragma unroll
    for (int o = 32; o; o >>= 1) vs += __shfl_xor(vs, o);
    if ((threadIdx.x & 63) == 0) red2[threadIdx.x >> 6] = vs;
    __syncthreads();
    const float var = (red2[0] + red2[1] + red2[2] + red2[3]) * (1.f / CC);
    const float rstd = rsqrtf(var + 1e-6f);
    #pragma unroll
    for (int j = 0; j < 4; ++j) {
        const int cc = threadIdx.x + 256 * j;
        float o_ = (v[j] - mean) * rstd * g[cc] + bv[cc];
        float gt = __bfloat162float(gate[(size_t)row * CC + cc]);
        y[(size_t)row * CC + cc] = __float2bfloat16(o_ * gt);
    }
}

// ---------------- launch ----------------
extern "C" void kernel_launch(void* const* d_in, const int* in_sizes, int n_in,
                              void* d_out, int out_size, void* d_ws, size_t ws_size,
                              hipStream_t stream) {
    const float* q        = (const float*)d_in[0];
    const float* mu_r     = (const float*)d_in[4];
    const float* mu_k     = (const float*)d_in[5];
    const float* mu_v     = (const float*)d_in[6];
    const float* mu_g     = (const float*)d_in[7];
    const float* mu_a     = (const float*)d_in[8];
    const float* mu_d     = (const float*)d_in[9];
    const float* dA       = (const float*)d_in[10];
    const float* dB       = (const float*)d_in[11];
    const float* db       = (const float*)d_in[12];
    const float* aA       = (const float*)d_in[13];
    const float* aB       = (const float*)d_in[14];
    const float* ab       = (const float*)d_in[15];
    const float* gA       = (const float*)d_in[16];
    const float* gB       = (const float*)d_in[17];
    const float* rW1      = (const float*)d_in[18];
    const float* rb1      = (const float*)d_in[19];
    const float* rW2      = (const float*)d_in[20];
    const float* rb2      = (const float*)d_in[21];
    const float* kW1      = (const float*)d_in[22];
    const float* kb1      = (const float*)d_in[23];
    const float* kW2      = (const float*)d_in[24];
    const float* kb2      = (const float*)d_in[25];
    const float* vW1      = (const float*)d_in[26];
    const float* vb1      = (const float*)d_in[27];
    const float* vW2      = (const float*)d_in[28];
    const float* vb2      = (const float*)d_in[29];
    const float* oW1      = (const float*)d_in[30];
    const float* ob1      = (const float*)d_in[31];
    const float* oW2      = (const float*)d_in[32];
    const float* ob2      = (const float*)d_in[33];
    const float* rem_mult = (const float*)d_in[34];
    const float* iclr_mix = (const float*)d_in[35];
    const float* bonus_mult = (const float*)d_in[36];
    const float* ln_g     = (const float*)d_in[37];
    const float* ln_b     = (const float*)d_in[38];
    float* out = (float*)d_out;

    // ---- workspace arena (~225 MB) ----
    char* p = (char*)d_ws;
    auto alloc = [&](size_t bytes) { char* r = p; p += (bytes + 255) & ~(size_t)255; return r; };
    float* fb_all  = (float*)alloc((size_t)3 * EPAD * 4);   // folded stage-1 biases r,k,v (pad-zeroed)
    float* c2_all  = (float*)alloc((size_t)3 * CC * 4);     // folded LoRA-B biases g,a,d
    float* lt_all  = (float*)alloc((size_t)3 * LL * 4);     // folded LoRA-A temps
    float* cb2_all = (float*)alloc((size_t)3 * CC * 4);     // rb2,kb2,vb2 gathered
    __hip_bfloat16* qb      = (__hip_bfloat16*)alloc((size_t)MM * CC * 2);       // q bf16; later ln_out
    __hip_bfloat16* W1T_all = (__hip_bfloat16*)alloc((size_t)3 * EPAD * CC * 2); // r,k,v W1^T
    __hip_bfloat16* W2T_all = (__hip_bfloat16*)alloc((size_t)3 * CC * EPAD * 2); // r,k,v W2^T
    __hip_bfloat16* Hb      = (__hip_bfloat16*)alloc((size_t)MM * 2 * EPAD * 2); // fused H (r,k); v reuses slice0
    float*          rkv     = (float*)alloc((size_t)3 * MM * CC * 4);            // r,k,v fp32
    __hip_bfloat16* abuf    = (__hip_bfloat16*)alloc((size_t)MM * CC * 2);       // iclr bf16
    __hip_bfloat16* dbuf    = (__hip_bfloat16*)alloc((size_t)MM * CC * 2);       // decay bf16
    __hip_bfloat16* gbuf    = (__hip_bfloat16*)alloc((size_t)MM * CC * 2);       // gate bf16
    float* rbuf = rkv;
    float* kbuf = rkv + (size_t)MM * CC;
    float* vbuf = rkv + (size_t)2 * MM * CC;
    // time-multiplexed tenants of the rkv arena:
    float*          pp      = rkv;                                         // fold partials (240 KB, dies before AT/BT)
    __hip_bfloat16* AT_all  = (__hip_bfloat16*)((char*)rkv + (1 << 18));   // LoRA A^T
    __hip_bfloat16* BT_all  = (__hip_bfloat16*)((char*)rkv + (1 << 18) + 786432);
    __hip_bfloat16* oW1T    = (__hip_bfloat16*)rkv;                        // written after recurrence
    __hip_bfloat16* oW2T    = (__hip_bfloat16*)((char*)rkv + 4194304);
    __hip_bfloat16* tgad    = Hb;                                          // LoRA intermediates [M][384]

    const dim3 blk(256);
    const dim3 tblk(32, 8);

    // gather stage-2 biases (device-to-device, capture-safe)
    hipMemcpyAsync(cb2_all,          rb2, CC * 4, hipMemcpyDeviceToDevice, stream);
    hipMemcpyAsync(cb2_all + CC,     kb2, CC * 4, hipMemcpyDeviceToDevice, stream);
    hipMemcpyAsync(cb2_all + 2 * CC, vb2, CC * 4, hipMemcpyDeviceToDevice, stream);

    // ---- folds (use pp scratch inside rkv; must precede AT/BT transposes) ----
    fold_pass1_z<<<dim3(20, 16, 3), blk, 0, stream>>>(mu_r, mu_k, mu_v, rW1, kW1, vW1,
                                                      pp, EE, EE, EPAD, 16 * EPAD);
    fold_pass2_z<<<dim3(5, 1, 3), blk, 0, stream>>>(pp, rb1, kb1, vb1, fb_all,
                                                    16, EPAD, 16 * EPAD, EE, EPAD, EPAD);
    fold_pass1_z<<<dim3(2, 16, 3), blk, 0, stream>>>(mu_g, mu_a, mu_d, gA, aA, dA,
                                                     pp, LL, LL, EPAD, 16 * EPAD);
    fold_pass2_z<<<dim3(1, 1, 3), dim3(128), 0, stream>>>(pp, nullptr, nullptr, nullptr, lt_all,
                                                          16, EPAD, 16 * EPAD, LL, LL, LL);
    fold_pass1_z<<<dim3(16, 2, 3), blk, 0, stream>>>(lt_all, lt_all + LL, lt_all + 2 * LL, gB, aB, dB,
                                                     pp, CC, CC, EPAD, 16 * EPAD);
    fold_pass2_z<<<dim3(4, 1, 3), blk, 0, stream>>>(pp, nullptr, ab, db, c2_all,
                                                    2, EPAD, 16 * EPAD, CC, CC, CC);

    // ---- transposes (AT/BT land in rkv after pp is dead) ----
    transpose_cast_z<<<dim3(32, 40, 3), tblk, 0, stream>>>(rW1, kW1, vW1, W1T_all,
                                                           (size_t)EPAD * CC, CC, EE, CC, EPAD);
    transpose_cast_z<<<dim3(40, 32, 3), tblk, 0, stream>>>(rW2, kW2, vW2, W2T_all,
                                                           (size_t)CC * EPAD, EE, CC, EPAD, CC);
    transpose_cast_z<<<dim3(32, 4, 3), tblk, 0, stream>>>(gA, aA, dA, AT_all,
                                                          (size_t)LL * CC, CC, LL, CC, LL);
    transpose_cast_z<<<dim3(4, 32, 3), tblk, 0, stream>>>(gB, aB, dB, BT_all,
                                                          (size_t)CC * LL, LL, CC, LL, CC);

    // ---- cast q ----
    cast_f32_bf16<<<dim3(MM * CC / 4 / 256), blk, 0, stream>>>(q, qb, MM * CC / 4);

    // ---- LoRA A-stage fused (N=384) -> tgad (aliases Hb) ----
    gemm_mfma<0,1,0><<<dim3(3, 64, 1), blk, 0, stream>>>(qb, AT_all, nullptr, tgad,
                                                         MM, 384, CC, CC, CC, 384, 0, 0, 0, 0);
    // ---- LoRA B-stage: gate(sig,bf16), iclr(sig,bf16), decay(decay,bf16) ----
    gemm_mfma<2,1,0><<<dim3(8, 64, 1), blk, 0, stream>>>(tgad,       BT_all,               c2_all,          gbuf,
                                                         MM, CC, LL, 384, LL, CC, 0, 0, 0, 0);
    gemm_mfma<2,1,0><<<dim3(8, 64, 1), blk, 0, stream>>>(tgad + LL,  BT_all + (size_t)CC * LL,  c2_all + CC,     abuf,
                                                         MM, CC, LL, 384, LL, CC, 0, 0, 0, 0);
    gemm_mfma<3,1,0><<<dim3(8, 64, 1), blk, 0, stream>>>(tgad + 2 * LL, BT_all + (size_t)2 * CC * LL, c2_all + 2 * CC, dbuf,
                                                         MM, CC, LL, 384, LL, CC, 0, 0, 0, 0);

    // ---- MLP r,k fused stage-1 (N=2560), then z-batched stage-2 ----
    gemm_mfma<1,1,0><<<dim3(20, 64, 1), blk, 0, stream>>>(qb, W1T_all, fb_all, Hb,
                                                          MM, 2 * EPAD, CC, CC, CC, 2 * EPAD, 0, 0, 0, 0);
    gemm_mfma<0,0,0><<<dim3(8, 64, 2), blk, 0, stream>>>(Hb, W2T_all, cb2_all, rkv,
                                                         MM, CC, EPAD, 2 * EPAD, EPAD, CC,
                                                         EPAD, (size_t)CC * EPAD, CC, (size_t)MM * CC);
    // ---- MLP v: stage-1 into Hb slice0, stage-2 -> vbuf ----
    gemm_mfma<1,1,0><<<dim3(10, 64, 1), blk, 0, stream>>>(qb, W1T_all + (size_t)2 * EPAD * CC, fb_all + 2 * EPAD, Hb,
                                                          MM, EPAD, CC, CC, CC, EPAD, 0, 0, 0, 0);
    gemm_mfma<0,0,0><<<dim3(8, 64, 1), blk, 0, stream>>>(Hb, W2T_all + (size_t)2 * CC * EPAD, cb2_all + 2 * CC, vbuf,
                                                         MM, CC, EPAD, EPAD, EPAD, CC, 0, 0, 0, 0);

    // ---- recurrence (256 blocks x 512 threads) -> d_out scratch ----
    recurrence_chunked<<<dim3(BB * HH * NSEG), dim3(512), 0, stream>>>(
        kbuf, abuf, dbuf, vbuf, rbuf, rem_mult, iclr_mix, bonus_mult, out);

    // ---- o-weight transposes into rkv (r/k/v dead after recurrence) ----
    transpose_cast_z<<<dim3(32, 40, 1), tblk, 0, stream>>>(oW1, oW1, oW1, oW1T,
                                                           0, CC, EE, CC, EPAD);
    transpose_cast_z<<<dim3(40, 32, 1), tblk, 0, stream>>>(oW2, oW2, oW2, oW2T,
                                                           0, EE, CC, EPAD, CC);

    // ---- LN * gate -> qb (bf16) ----
    ln_gate_kernel<<<dim3(MM), blk, 0, stream>>>(out, gbuf, ln_g, ln_b, qb);

    // ---- output MLP ----
    gemm_mfma<1,1,1><<<dim3(10, 64, 1), blk, 0, stream>>>(qb, oW1T, ob1, Hb,
                                                          MM, EE, CC, CC, CC, EPAD, 0, 0, 0, 0);
    gemm_mfma<0,0,0><<<dim3(8, 64, 1), blk, 0, stream>>>(Hb, oW2T, ob2, out,
                                                         MM, CC, EPAD, EPAD, EPAD, CC, 0, 0, 0, 0);
}

// Round 10
// 909.722 us; speedup vs baseline: 1.8584x; 1.0329x over previous
//
#include <hip/hip_runtime.h>
#include <hip/hip_bf16.h>
#include <math.h>

// LinearAttentionLayerOptimized: B=4, T=2048, C=1024, H=16, N=64, L=128, E=1228
// Round 9: GEMM round. BK=64 (half the barriers/K-step, per-half fragment loads
// to hold VGPR), fused stage-1 r/k/v (N=3840), z=3 stage-2 and z=3 LoRA-B (per-z
// activation). Recurrence identical to round 8 (439us proven).

#define BB 4
#define TT 2048
#define CC 1024
#define HH 16
#define NN 64
#define LL 128
#define EE 1228
#define EPAD 1280
#define MM (BB*TT)          // 8192 rows
#define TCH 32
#define NSEG 4
#define WARMCH 2            // 64 warm-up steps; decay<=0.82 -> ~3e-6
#define DECAY_C_F 0.7408182206817179f

typedef __attribute__((ext_vector_type(8))) short s16x8;
typedef __attribute__((ext_vector_type(4))) float f32x4;

#define GLOAD_LDS16(gp, lp) \
    __builtin_amdgcn_global_load_lds((const __attribute__((address_space(1))) void*)(gp), \
                                     (__attribute__((address_space(3))) void*)(lp), 16, 0, 0)

// ---------------- z-batched two-pass bias folds ----------------
__global__ __launch_bounds__(256) void fold_pass1_z(
    const float* __restrict__ mu0, const float* __restrict__ mu1, const float* __restrict__ mu2,
    const float* __restrict__ W0,  const float* __restrict__ W1_, const float* __restrict__ W2_,
    float* __restrict__ partial, int ldW, int E, int ldP, int pslice) {
    const float* mu = blockIdx.z == 0 ? mu0 : (blockIdx.z == 1 ? mu1 : mu2);
    const float* W  = blockIdx.z == 0 ? W0  : (blockIdx.z == 1 ? W1_ : W2_);
    partial += (size_t)blockIdx.z * pslice;
    const int l = threadIdx.x & 63;
    const int e = blockIdx.x * 64 + l;
    const int pg = threadIdx.x >> 6;
    const int c0 = blockIdx.y * 64;
    float s = 0.f;
    if (e < E)
        for (int c = c0 + pg; c < c0 + 64; c += 4) s += mu[c] * W[(size_t)c * ldW + e];
    __shared__ float red[4][64];
    red[pg][l] = s;
    __syncthreads();
    if (pg == 0 && e < E)
        partial[(size_t)blockIdx.y * ldP + e] = red[0][l] + red[1][l] + red[2][l] + red[3][l];
}

__global__ void fold_pass2_z(const float* __restrict__ partial,
                             const float* b0, const float* b1, const float* b2,
                             float* __restrict__ outv,
                             int P, int ldP, int pslice, int E, int Epad, int oslice) {
    const float* bias = blockIdx.z == 0 ? b0 : (blockIdx.z == 1 ? b1 : b2);
    partial += (size_t)blockIdx.z * pslice;
    outv    += (size_t)blockIdx.z * oslice;
    int e = blockIdx.x * blockDim.x + threadIdx.x;
    if (e >= Epad) return;
    float s = 0.f;
    if (e < E) {
        s = bias ? bias[e] : 0.f;
        for (int p = 0; p < P; ++p) s += partial[(size_t)p * ldP + e];
    }
    outv[e] = s;
}

// ---------------- cast / z-batched transpose-cast ----------------
__global__ void cast_f32_bf16(const float* __restrict__ in, __hip_bfloat16* __restrict__ out, int n4) {
    int i = blockIdx.x * blockDim.x + threadIdx.x;
    if (i >= n4) return;
    float4 v = ((const float4*)in)[i];
    __hip_bfloat16 o[4] = {__float2bfloat16(v.x), __float2bfloat16(v.y),
                           __float2bfloat16(v.z), __float2bfloat16(v.w)};
    *(ulong1*)&out[i * 4] = *(ulong1*)o;
}

__global__ void transpose_cast_z(const float* s0, const float* s1, const float* s2,
                                 __hip_bfloat16* __restrict__ outT, size_t dslice,
                                 int Rin, int Cin, int Rpad, int Cpad) {
    const float* in = blockIdx.z == 0 ? s0 : (blockIdx.z == 1 ? s1 : s2);
    outT += (size_t)blockIdx.z * dslice;
    __shared__ float t[32][33];
    const int r0 = blockIdx.x * 32, c0 = blockIdx.y * 32;
    const int tx = threadIdx.x, ty = threadIdx.y;   // 32 x 8
    #pragma unroll
    for (int j = 0; j < 4; ++j) {
        int r = r0 + ty + j * 8, c = c0 + tx;
        t[ty + j * 8][tx] = (r < Rin && c < Cin) ? in[(size_t)r * Cin + c] : 0.f;
    }
    __syncthreads();
    #pragma unroll
    for (int j = 0; j < 4; ++j) {
        int c = c0 + ty + j * 8, r = r0 + tx;
        if (c < Cpad && r < Rpad) outT[(size_t)c * Rpad + r] = __float2bfloat16(t[tx][ty + j * 8]);
    }
}

// ---------------- bf16 MFMA GEMM, BK=64 (z-batched, per-z activation) ----------------
// C[M,N] = act(A[M,K] @ Bt[N,K]^T + bias[N]); act = ACTZ2 for blockIdx.z==2 if ACTZ2>=0.
// LDS chunk swizzle: row r (128B = 8 chunks of 16B), source chunk k stored at
// position k ^ (r&7); read back at the same XOR (per-row involution, cancels
// identically for A- and B-fragments).
template<int ACT, int ACTZ2, int OBF, int PADZ>
__global__ __launch_bounds__(256) void gemm_mfma(const __hip_bfloat16* __restrict__ A,
                                                 const __hip_bfloat16* __restrict__ Bt,
                                                 const float* __restrict__ bias,
                                                 void* __restrict__ Cptr,
                                                 int M, int N, int K,
                                                 int ldA, int ldB, int ldC,
                                                 size_t zA, size_t zB, size_t zBias, size_t zC) {
    __shared__ __hip_bfloat16 As[128 * 64];   // 16 KB
    __shared__ __hip_bfloat16 Bs[128 * 64];   // 16 KB
    const int tid = threadIdx.x;
    const int wid = tid >> 6, lane = tid & 63;
    const int wm = wid >> 1, wn = wid & 1;
    const int bm = blockIdx.y * 128, bn = blockIdx.x * 128;
    A  += (size_t)blockIdx.z * zA;
    Bt += (size_t)blockIdx.z * zB;
    if (bias) bias += (size_t)blockIdx.z * zBias;
    const size_t zc = (size_t)blockIdx.z * zC;
    const int act = (ACTZ2 >= 0 && blockIdx.z == 2) ? ACTZ2 : ACT;

    // staging: 16 regions of 1 KB per matrix; wave stages 4 each.
    const __hip_bfloat16* srcA[4];
    const __hip_bfloat16* srcB[4];
    #pragma unroll
    for (int i = 0; i < 4; ++i) {
        int off = (wid * 4 + i) * 1024 + lane * 16;
        int r = off >> 7;            // 128 B rows
        int c = (off >> 4) & 7;      // chunk position
        int cs = c ^ (r & 7);        // source chunk
        srcA[i] = A  + (size_t)(bm + r) * ldA + cs * 8;
        srcB[i] = Bt + (size_t)(bn + r) * ldB + cs * 8;
    }

    f32x4 acc[4][4];
    #pragma unroll
    for (int i = 0; i < 4; ++i)
        #pragma unroll
        for (int j = 0; j < 4; ++j) acc[i][j] = (f32x4){0.f, 0.f, 0.f, 0.f};

    const int ra = wm * 64 + (lane & 15);   // fragment row bases
    const int rb = wn * 64 + (lane & 15);

    for (int k0 = 0; k0 < K; k0 += 64) {
        #pragma unroll
        for (int i = 0; i < 4; ++i) {
            GLOAD_LDS16(srcA[i] + k0, (char*)As + (wid * 4 + i) * 1024);
            GLOAD_LDS16(srcB[i] + k0, (char*)Bs + (wid * 4 + i) * 1024);
        }
        __syncthreads();
        #pragma unroll
        for (int h = 0; h < 2; ++h) {
            s16x8 af[4], bfr[4];
            const int kc = (lane >> 4) + h * 4;
            #pragma unroll
            for (int mi = 0; mi < 4; ++mi) {
                int r = ra + mi * 16;
                af[mi] = *(const s16x8*)((const char*)As + r * 128 + (kc ^ (r & 7)) * 16);
            }
            #pragma unroll
            for (int ni = 0; ni < 4; ++ni) {
                int r = rb + ni * 16;
                bfr[ni] = *(const s16x8*)((const char*)Bs + r * 128 + (kc ^ (r & 7)) * 16);
            }
            #pragma unroll
            for (int mi = 0; mi < 4; ++mi)
                #pragma unroll
                for (int ni = 0; ni < 4; ++ni)
                    acc[mi][ni] = __builtin_amdgcn_mfma_f32_16x16x32_bf16(af[mi], bfr[ni], acc[mi][ni], 0, 0, 0);
        }
        __syncthreads();
    }

    #pragma unroll
    for (int ni = 0; ni < 4; ++ni) {
        const int col = bn + wn * 64 + ni * 16 + (lane & 15);
        const bool valid = (col < N);
        const float bc = (valid && bias) ? bias[col] : 0.f;
        #pragma unroll
        for (int mi = 0; mi < 4; ++mi) {
            #pragma unroll
            for (int reg = 0; reg < 4; ++reg) {
                const int row = bm + wm * 64 + mi * 16 + (lane >> 4) * 4 + reg;
                float y = 0.f;
                if (valid) {
                    float x = acc[mi][ni][reg] + bc;
                    if (act == 1)      y = 0.5f * x * (1.0f + erff(x * 0.7071067811865475f));
                    else if (act == 2) y = 1.0f / (1.0f + expf(-x));
                    else if (act == 3) { float sg = 1.0f / (1.0f + expf(-tanhf(x))); y = expf(-DECAY_C_F * sg); }
                    else               y = x;
                }
                if (valid || PADZ) {
                    if (OBF) ((__hip_bfloat16*)Cptr)[zc + (size_t)row * ldC + col] = __float2bfloat16(y);
                    else     ((float*)Cptr)[zc + (size_t)row * ldC + col] = y;
                }
            }
        }
    }
}

// ---------------- segment-parallel chunked recurrence (512 threads, 8 waves) ----------------
#define P_T0(i,j)   pool[0     + (i)*68 + (j)]
#define P_WT(i,j)   pool[4352  + (i)*68 + (j)]
#define P_KP(i,j)   pool[6528  + (i)*68 + (j)]
#define P_P2t(i,j)  pool[6528  + (i)*36 + (j)]   // aliases KP (dead after phase2; 6b uses KPT)
#define P_NU(i,j)   pool[8704  + (i)*68 + (j)]
#define P_GRt(i,j)  pool[8704  + (i)*36 + (j)]   // aliases NU (dead after phase2; 6b uses NUT)
#define P_RKM(i,j)  pool[10880 + (i)*68 + (j)]
#define P_RRM(i,j)  pool[13056 + (i)*68 + (j)]
#define P_GM(i,j)   pool[15232 + (i)*68 + (j)]
// hole @17408 (was GMT - deleted)
#define P_KPT(i,j)  pool[19712 + (i)*36 + (j)]
#define P_NUT(i,j)  pool[22016 + (i)*36 + (j)]
// hole @24320 (was RKMT - deleted)
#define P_DCT(i,j)  pool[26624 + (i)*36 + (j)]
#define P_AT(i,j)   pool[28928 + (i)*36 + (j)]
#define P_BM(i,j)   pool[30080 + (i)*36 + (j)]
#define P_SEG(i,j)  pool[31232 + (i)*64 + (j)]
#define LD4(expr)   (*(const float4*)&(expr))
#define FMA4(acc, s, v) { (acc).x = fmaf((s), (v).x, (acc).x); (acc).y = fmaf((s), (v).y, (acc).y); \
                          (acc).z = fmaf((s), (v).z, (acc).z); (acc).w = fmaf((s), (v).w, (acc).w); }

__global__ __launch_bounds__(512) void recurrence_chunked(
    const float* __restrict__ kbuf, const __hip_bfloat16* __restrict__ iclr,
    const __hip_bfloat16* __restrict__ dbuf, const float* __restrict__ vbuf,
    const float* __restrict__ rbuf,
    const float* __restrict__ rem_mult, const float* __restrict__ iclr_mix,
    const float* __restrict__ bonus_mult, float* __restrict__ outb) {
    __shared__ float pool[31488];   // 123 KB
    const int bh = blockIdx.x & 63, seg = blockIdx.x >> 6;
    const int b = bh >> 4, h = bh & 15;
    const int tid = threadIdx.x, lane = tid & 63, wid = tid >> 6;
    const size_t gbase = ((size_t)b * TT) * CC + (size_t)h * NN;

    for (int i = tid; i < 4352; i += 512) pool[i] = 0.f;   // T0 = 0 at segment start
    const int c0 = tid & 63;
    const float remc = rem_mult[h * NN + c0];
    const float mixc = iclr_mix[h * NN + c0];
    __syncthreads();

    // stagger: outputs {18,16,15,15}, warm-up 2 chunks for seg>0 -> max 18 chunks/block
    const int cout0 = (seg == 0) ? 0 : (seg == 1) ? 18 : (seg == 2) ? 34 : 49;
    const int lenq  = (seg == 0) ? 18 : (seg == 1) ? 16 : 15;
    const int ce    = cout0 + lenq;
    const int cb    = (seg == 0) ? 0 : cout0 - WARMCH;

    for (int chk = cb; chk < ce; ++chk) {
        const bool emit = (chk >= cout0);
        const int tg0 = chk * TCH;
        // ---- load & elementwise ----
        #pragma unroll
        for (int i = 0; i < 4; ++i) {
            int idx = tid + 512 * i;
            int t = idx >> 6, c = idx & 63;
            size_t off = gbase + (size_t)(tg0 + t) * CC + c;
            float kx = kbuf[off];
            float ax = __bfloat162float(iclr[off]);
            float rk = kx * (1.f + (ax - 1.f) * mixc);
            P_WT(t, c) = ax;
            P_KP(t, c) = kx * remc;
            P_RKM(t, c) = rk;
            P_NU(t, c) = vbuf[off];
            if (emit) P_RRM(t, c) = rbuf[off];
            P_DCT(c, t) = __bfloat162float(dbuf[off]);
        }
        __syncthreads();
        // ---- merged: row norms (all waves) + cumprod part1 (tid<256) ----
        #pragma unroll
        for (int rr = 0; rr < 4; ++rr) {
            int t = wid + rr * 8;
            float v = P_KP(t, lane);
            float ss = v * v;
            #pragma unroll
            for (int s = 32; s; s >>= 1) ss += __shfl_xor(ss, s);
            float kn = v / fmaxf(sqrtf(ss), 1e-12f);
            P_KP(t, lane) = kn;
            P_WT(t, lane) = P_WT(t, lane) * kn;
        }
        float lc[8];
        const int ccs = tid & 63, sgm = tid >> 6, t0s = (sgm & 3) * 8;
        if (tid < 256) {
            float pp_ = 1.f;
            #pragma unroll
            for (int j = 0; j < 8; ++j) { pp_ *= P_DCT(ccs, t0s + j); lc[j] = pp_; }
            P_SEG(sgm, ccs) = pp_;
        }
        __syncthreads();
        // ---- cumprod part2 + scaled quantities (256 threads) ----
        if (tid < 256) {
            float m = 1.f;
            for (int s = 0; s < sgm; ++s) m *= P_SEG(s, ccs);
            float dcprev = m;
            #pragma unroll
            for (int j = 0; j < 8; ++j) {
                int t = t0s + j;
                float dcur = m * lc[j];
                P_WT(t, ccs) *= dcprev;
                float inv = 1.f / dcur;
                float kap = P_KP(t, ccs) * inv; P_KP(t, ccs) = kap; P_KPT(ccs, t) = kap;
                float nu  = P_NU(t, ccs) * inv; P_NU(t, ccs) = nu;  P_NUT(ccs, t) = nu;
                P_DCT(ccs, t) = dcur;
                dcprev = dcur;
            }
        }
        __syncthreads();
        // ---- phase2: AT (2 tiles/wave) + BM (2 tiles/wave) + GM1 slab (1/wave) ----
        #pragma unroll
        for (int u = 0; u < 2; ++u) {
            const int at = wid * 2 + u;   // 0..15
            const int s = (at >> 2) * 8 + (lane >> 3), t = (at & 3) * 8 + (lane & 7);
            float acc = 0.f;
            #pragma unroll
            for (int kc = 0; kc < 16; ++kc) {
                float4 a = LD4(P_KP(s, kc * 4));
                float4 bb = LD4(P_WT(t, kc * 4));
                acc += a.x * bb.x + a.y * bb.y + a.z * bb.z + a.w * bb.w;
            }
            P_AT(s, t) = (s < t) ? acc : 0.f;
        }
        #pragma unroll
        for (int u = 0; u < 2; ++u) {
            const int bt = wid * 2 + u;   // 0..15
            const int t = (bt >> 2) * 8 + (lane >> 3), s = (bt & 3) * 8 + (lane & 7);
            float acc = 0.f;
            #pragma unroll
            for (int kc = 0; kc < 16; ++kc) {
                float4 a = LD4(P_WT(t, kc * 4));
                float4 bb = LD4(P_NU(s, kc * 4));
                acc += a.x * bb.x + a.y * bb.y + a.z * bb.z + a.w * bb.w;
            }
            P_BM(t, s) = (s < t) ? acc : 0.f;
        }
        {   // GM1: wave owns GM rows [wid*4, wid*4+4) x all 64 q; float4 row reads of T0
            const int t = wid * 4 + (lane >> 4);
            const int q4 = (lane & 15) * 4;
            float4 acc = {0.f, 0.f, 0.f, 0.f};
            #pragma unroll
            for (int j4 = 0; j4 < 16; ++j4) {
                float4 w4 = LD4(P_WT(t, j4 * 4));
                float4 ta = LD4(P_T0(j4 * 4 + 0, q4));
                float4 tb = LD4(P_T0(j4 * 4 + 1, q4));
                float4 tc = LD4(P_T0(j4 * 4 + 2, q4));
                float4 td = LD4(P_T0(j4 * 4 + 3, q4));
                FMA4(acc, w4.x, ta); FMA4(acc, w4.y, tb);
                FMA4(acc, w4.z, tc); FMA4(acc, w4.w, td);
            }
            *(float4*)&P_GM(t, q4) = acc;
        }
        __syncthreads();
        // ---- phase3: GM += BM . RKM (same slab mapping, float4 row reads) ----
        {
            const int t = wid * 4 + (lane >> 4);
            const int q4 = (lane & 15) * 4;
            float4 acc = {0.f, 0.f, 0.f, 0.f};
            #pragma unroll
            for (int s4 = 0; s4 < 8; ++s4) {
                float4 bm4 = LD4(P_BM(t, s4 * 4));
                float4 ra = LD4(P_RKM(s4 * 4 + 0, q4));
                float4 rb = LD4(P_RKM(s4 * 4 + 1, q4));
                float4 rc = LD4(P_RKM(s4 * 4 + 2, q4));
                float4 rd = LD4(P_RKM(s4 * 4 + 3, q4));
                FMA4(acc, bm4.x, ra); FMA4(acc, bm4.y, rb);
                FMA4(acc, bm4.z, rc); FMA4(acc, bm4.w, rd);
            }
            float4 g = LD4(P_GM(t, q4));
            g.x += acc.x; g.y += acc.y; g.z += acc.z; g.w += acc.w;
            *(float4*)&P_GM(t, q4) = g;
        }
        __syncthreads();
        // ---- phase4: wave0 forward substitution (g[32], 128 VGPR -> no spill)
        //      || waves1-7: P2t (emit only) ----
        if (wid == 0) {
            float g[32];
            #pragma unroll
            for (int t = 0; t < 32; ++t) g[t] = P_GM(t, lane);
            #pragma unroll
            for (int s = 0; s < 31; ++s) {
                #pragma unroll
                for (int t = s + 1; t < 32; ++t) g[t] -= P_AT(s, t) * g[s];
            }
            #pragma unroll
            for (int t = 0; t < 32; ++t) P_GM(t, lane) = g[t];
        } else if (emit) {
            for (int tile = wid - 1; tile < 16; tile += 7) {
                int t = (tile >> 2) * 8 + (lane >> 3), s = (tile & 3) * 8 + (lane & 7);
                float acc = 0.f;
                #pragma unroll
                for (int kc = 0; kc < 16; ++kc) {
                    float4 a = LD4(P_RRM(t, kc * 4));
                    float4 bb = LD4(P_RKM(s, kc * 4));
                    acc += a.x * bb.x + a.y * bb.y + a.z * bb.z + a.w * bb.w;
                }
                P_P2t(t, s) = (s <= t) ? acc : 0.f;
            }
        }
        __syncthreads();
        if (emit) {
            // ---- phase5: GRt[t][s] = g_s . r_t (16 tiles) ----
            for (int tile = wid; tile < 16; tile += 8) {
                int t = (tile >> 2) * 8 + (lane >> 3), s = (tile & 3) * 8 + (lane & 7);
                float acc = 0.f;
                #pragma unroll
                for (int kc = 0; kc < 16; ++kc) {
                    float4 a = LD4(P_RRM(t, kc * 4));
                    float4 bb = LD4(P_GM(s, kc * 4));
                    acc += a.x * bb.x + a.y * bb.y + a.z * bb.z + a.w * bb.w;
                }
                P_GRt(t, s) = (s <= t) ? acc : 0.f;
            }
            __syncthreads();
            // ---- phase6a: outputs (32 tiles) ----
            for (int tile = wid; tile < 32; tile += 8) {
                int i = (tile >> 2) * 8 + (lane >> 3), t = (tile & 3) * 8 + (lane & 7);
                float a1 = 0.f, a2 = 0.f, a3 = 0.f;
                #pragma unroll
                for (int j4 = 0; j4 < 16; ++j4) {
                    float4 a = LD4(P_T0(i, j4 * 4));
                    float4 bb = LD4(P_RRM(t, j4 * 4));
                    a1 += a.x * bb.x + a.y * bb.y + a.z * bb.z + a.w * bb.w;
                }
                #pragma unroll
                for (int s4 = 0; s4 < 8; ++s4) {
                    float4 a = LD4(P_NUT(i, s4 * 4));
                    float4 bb = LD4(P_P2t(t, s4 * 4));
                    a2 += a.x * bb.x + a.y * bb.y + a.z * bb.z + a.w * bb.w;
                    float4 c = LD4(P_KPT(i, s4 * 4));
                    float4 d = LD4(P_GRt(t, s4 * 4));
                    a3 += c.x * d.x + c.y * d.y + c.z * d.z + c.w * d.w;
                }
                float diag = 0.2f * bonus_mult[h * NN + i] * P_NUT(i, t) * P_P2t(t, t);
                outb[gbase + (size_t)(tg0 + t) * CC + i] = P_DCT(i, t) * (a1 + a2 + diag - a3);
            }
            __syncthreads();
        }
        // ---- phase6b: T0 <- dc_end * (T0 - Kap^T G + Nu^T RK) (de-transposed slabs) ----
        #pragma unroll
        for (int u = 0; u < 2; ++u) {
            const int m = wid * 2 + u;                       // 0..15
            const int pr = (m & 7) * 8 + (lane >> 3);        // 0..63
            const int q4 = (m >> 3) * 32 + (lane & 7) * 4;   // 0..60
            float4 a1 = {0.f, 0.f, 0.f, 0.f}, a2 = {0.f, 0.f, 0.f, 0.f};
            #pragma unroll
            for (int s = 0; s < 32; ++s) {
                const float kp = P_KPT(pr, s);
                const float nu = P_NUT(pr, s);
                float4 g4 = LD4(P_GM(s, q4));
                float4 rk4 = LD4(P_RKM(s, q4));
                FMA4(a1, kp, g4);
                FMA4(a2, nu, rk4);
            }
            const float dc = P_DCT(pr, 31);
            float4 t0 = LD4(P_T0(pr, q4));
            t0.x = dc * (t0.x - a1.x + a2.x);
            t0.y = dc * (t0.y - a1.y + a2.y);
            t0.z = dc * (t0.z - a1.z + a2.z);
            t0.w = dc * (t0.w - a1.w + a2.w);
            *(float4*)&P_T0(pr, q4) = t0;
        }
        __syncthreads();
    }
}

// ---------------- LayerNorm * gate (bf16 out) ----------------
__global__ __launch_bounds__(256) void ln_gate_kernel(const float* __restrict__ x,
                                                      const __hip_bfloat16* __restrict__ gate,
                                                      const float* __restrict__ g,
                                                      const float* __restrict__ bv,
                                                      __hip_bfloat16* __restrict__ y) {
    const int row = blockIdx.x;
    const float* xr = x + (size_t)row * CC;
    float v[4];
    float s = 0.f;
    #pragma unroll
    for (int j = 0; j < 4; ++j) { v[j] = xr[threadIdx.x + 256 * j]; s += v[j]; }
    __shared__ float red[4], red2[4];
    #pragma unroll
    for (int o = 32; o; o >>= 1) s += __shfl_xor(s, o);
    if ((threadIdx.x & 63) == 0) red[threadIdx.x >> 6] = s;
    __syncthreads();
    const float mean = (red[0] + red[1] + red[2] + red[3]) * (1.f / CC);
    float vs = 0.f;
    #pragma unroll
    for (int j = 0; j < 4; ++j) { float d = v[j] - mean; vs += d * d; }
    #pragma unroll
    for (int o = 32; o; o >>= 1) vs += __shfl_xor(vs, o);
    if ((threadIdx.x & 63) == 0) red2[threadIdx.x >> 6] = vs;
    __syncthreads();
    const float var = (red2[0] + red2[1] + red2[2] + red2[3]) * (1.f / CC);
    const float rstd = rsqrtf(var + 1e-6f);
    #pragma unroll
    for (int j = 0; j < 4; ++j) {
        const int cc = threadIdx.x + 256 * j;
        float o_ = (v[j] - mean) * rstd * g[cc] + bv[cc];
        float gt = __bfloat162float(gate[(size_t)row * CC + cc]);
        y[(size_t)row * CC + cc] = __float2bfloat16(o_ * gt);
    }
}

// ---------------- launch ----------------
extern "C" void kernel_launch(void* const* d_in, const int* in_sizes, int n_in,
                              void* d_out, int out_size, void* d_ws, size_t ws_size,
                              hipStream_t stream) {
    const float* q        = (const float*)d_in[0];
    const float* mu_r     = (const float*)d_in[4];
    const float* mu_k     = (const float*)d_in[5];
    const float* mu_v     = (const float*)d_in[6];
    const float* mu_g     = (const float*)d_in[7];
    const float* mu_a     = (const float*)d_in[8];
    const float* mu_d     = (const float*)d_in[9];
    const float* dA       = (const float*)d_in[10];
    const float* dB       = (const float*)d_in[11];
    const float* db       = (const float*)d_in[12];
    const float* aA       = (const float*)d_in[13];
    const float* aB       = (const float*)d_in[14];
    const float* ab       = (const float*)d_in[15];
    const float* gA       = (const float*)d_in[16];
    const float* gB       = (const float*)d_in[17];
    const float* rW1      = (const float*)d_in[18];
    const float* rb1      = (const float*)d_in[19];
    const float* rW2      = (const float*)d_in[20];
    const float* rb2      = (const float*)d_in[21];
    const float* kW1      = (const float*)d_in[22];
    const float* kb1      = (const float*)d_in[23];
    const float* kW2      = (const float*)d_in[24];
    const float* kb2      = (const float*)d_in[25];
    const float* vW1      = (const float*)d_in[26];
    const float* vb1      = (const float*)d_in[27];
    const float* vW2      = (const float*)d_in[28];
    const float* vb2      = (const float*)d_in[29];
    const float* oW1      = (const float*)d_in[30];
    const float* ob1      = (const float*)d_in[31];
    const float* oW2      = (const float*)d_in[32];
    const float* ob2      = (const float*)d_in[33];
    const float* rem_mult = (const float*)d_in[34];
    const float* iclr_mix = (const float*)d_in[35];
    const float* bonus_mult = (const float*)d_in[36];
    const float* ln_g     = (const float*)d_in[37];
    const float* ln_b     = (const float*)d_in[38];
    float* out = (float*)d_out;

    // ---- workspace arena (~270 MB; <= 277 MB proven in round 3) ----
    char* p = (char*)d_ws;
    auto alloc = [&](size_t bytes) { char* r = p; p += (bytes + 255) & ~(size_t)255; return r; };
    float* fb_all  = (float*)alloc((size_t)3 * EPAD * 4);   // folded stage-1 biases r,k,v (pad-zeroed)
    float* c2_all  = (float*)alloc((size_t)3 * CC * 4);     // folded LoRA-B biases g,a,d
    float* lt_all  = (float*)alloc((size_t)3 * LL * 4);     // folded LoRA-A temps
    float* cb2_all = (float*)alloc((size_t)3 * CC * 4);     // rb2,kb2,vb2 gathered
    __hip_bfloat16* qb      = (__hip_bfloat16*)alloc((size_t)MM * CC * 2);       // q bf16; later ln_out
    __hip_bfloat16* W1T_all = (__hip_bfloat16*)alloc((size_t)3 * EPAD * CC * 2); // r,k,v W1^T
    __hip_bfloat16* W2T_all = (__hip_bfloat16*)alloc((size_t)3 * CC * EPAD * 2); // r,k,v W2^T
    __hip_bfloat16* Hb      = (__hip_bfloat16*)alloc((size_t)MM * 3 * EPAD * 2); // fused H (r,k,v)
    float*          rkv     = (float*)alloc((size_t)3 * MM * CC * 4);            // r,k,v fp32
    __hip_bfloat16* gadbuf  = (__hip_bfloat16*)alloc((size_t)3 * MM * CC * 2);   // gate, iclr, decay (contiguous, z-order)
    __hip_bfloat16* gbuf = gadbuf;
    __hip_bfloat16* abuf = gadbuf + (size_t)MM * CC;
    __hip_bfloat16* dbuf = gadbuf + (size_t)2 * MM * CC;
    float* rbuf = rkv;
    float* kbuf = rkv + (size_t)MM * CC;
    float* vbuf = rkv + (size_t)2 * MM * CC;
    // time-multiplexed tenants of the rkv arena:
    float*          pp      = rkv;                                         // fold partials (240 KB, dies before AT/BT)
    __hip_bfloat16* AT_all  = (__hip_bfloat16*)((char*)rkv + (1 << 18));   // LoRA A^T
    __hip_bfloat16* BT_all  = (__hip_bfloat16*)((char*)rkv + (1 << 18) + 786432);
    __hip_bfloat16* oW1T    = (__hip_bfloat16*)rkv;                        // written after recurrence
    __hip_bfloat16* oW2T    = (__hip_bfloat16*)((char*)rkv + 4194304);
    __hip_bfloat16* tgad    = Hb;                                          // LoRA intermediates [M][384]

    const dim3 blk(256);
    const dim3 tblk(32, 8);

    // gather stage-2 biases (device-to-device, capture-safe)
    hipMemcpyAsync(cb2_all,          rb2, CC * 4, hipMemcpyDeviceToDevice, stream);
    hipMemcpyAsync(cb2_all + CC,     kb2, CC * 4, hipMemcpyDeviceToDevice, stream);
    hipMemcpyAsync(cb2_all + 2 * CC, vb2, CC * 4, hipMemcpyDeviceToDevice, stream);

    // ---- folds (use pp scratch inside rkv; must precede AT/BT transposes) ----
    fold_pass1_z<<<dim3(20, 16, 3), blk, 0, stream>>>(mu_r, mu_k, mu_v, rW1, kW1, vW1,
                                                      pp, EE, EE, EPAD, 16 * EPAD);
    fold_pass2_z<<<dim3(5, 1, 3), blk, 0, stream>>>(pp, rb1, kb1, vb1, fb_all,
                                                    16, EPAD, 16 * EPAD, EE, EPAD, EPAD);
    fold_pass1_z<<<dim3(2, 16, 3), blk, 0, stream>>>(mu_g, mu_a, mu_d, gA, aA, dA,
                                                     pp, LL, LL, EPAD, 16 * EPAD);
    fold_pass2_z<<<dim3(1, 1, 3), dim3(128), 0, stream>>>(pp, nullptr, nullptr, nullptr, lt_all,
                                                          16, EPAD, 16 * EPAD, LL, LL, LL);
    fold_pass1_z<<<dim3(16, 2, 3), blk, 0, stream>>>(lt_all, lt_all + LL, lt_all + 2 * LL, gB, aB, dB,
                                                     pp, CC, CC, EPAD, 16 * EPAD);
    fold_pass2_z<<<dim3(4, 1, 3), blk, 0, stream>>>(pp, nullptr, ab, db, c2_all,
                                                    2, EPAD, 16 * EPAD, CC, CC, CC);

    // ---- transposes (AT/BT land in rkv after pp is dead) ----
    transpose_cast_z<<<dim3(32, 40, 3), tblk, 0, stream>>>(rW1, kW1, vW1, W1T_all,
                                                           (size_t)EPAD * CC, CC, EE, CC, EPAD);
    transpose_cast_z<<<dim3(40, 32, 3), tblk, 0, stream>>>(rW2, kW2, vW2, W2T_all,
                                                           (size_t)CC * EPAD, EE, CC, EPAD, CC);
    transpose_cast_z<<<dim3(32, 4, 3), tblk, 0, stream>>>(gA, aA, dA, AT_all,
                                                          (size_t)LL * CC, CC, LL, CC, LL);
    transpose_cast_z<<<dim3(4, 32, 3), tblk, 0, stream>>>(gB, aB, dB, BT_all,
                                                          (size_t)CC * LL, LL, CC, LL, CC);

    // ---- cast q ----
    cast_f32_bf16<<<dim3(MM * CC / 4 / 256), blk, 0, stream>>>(q, qb, MM * CC / 4);

    // ---- LoRA A-stage fused (N=384) -> tgad (aliases Hb) ----
    gemm_mfma<0,-1,1,0><<<dim3(3, 64, 1), blk, 0, stream>>>(qb, AT_all, nullptr, tgad,
                                                            MM, 384, CC, CC, CC, 384, 0, 0, 0, 0);
    // ---- LoRA B-stage fused z=3: gate(sig), iclr(sig), decay(decay); bf16 out ----
    gemm_mfma<2,3,1,0><<<dim3(8, 64, 3), blk, 0, stream>>>(tgad, BT_all, c2_all, gadbuf,
                                                           MM, CC, LL, 384, LL, CC,
                                                           LL, (size_t)CC * LL, CC, (size_t)MM * CC);

    // ---- MLP r,k,v fused stage-1 (N=3840) ----
    gemm_mfma<1,-1,1,0><<<dim3(30, 64, 1), blk, 0, stream>>>(qb, W1T_all, fb_all, Hb,
                                                             MM, 3 * EPAD, CC, CC, CC, 3 * EPAD, 0, 0, 0, 0);
    // ---- stage-2 fused z=3 -> rkv fp32 ----
    gemm_mfma<0,-1,0,0><<<dim3(8, 64, 3), blk, 0, stream>>>(Hb, W2T_all, cb2_all, rkv,
                                                            MM, CC, EPAD, 3 * EPAD, EPAD, CC,
                                                            EPAD, (size_t)CC * EPAD, CC, (size_t)MM * CC);

    // ---- recurrence (256 blocks x 512 threads) -> d_out scratch ----
    recurrence_chunked<<<dim3(BB * HH * NSEG), dim3(512), 0, stream>>>(
        kbuf, abuf, dbuf, vbuf, rbuf, rem_mult, iclr_mix, bonus_mult, out);

    // ---- o-weight transposes into rkv (r/k/v dead after recurrence) ----
    transpose_cast_z<<<dim3(32, 40, 1), tblk, 0, stream>>>(oW1, oW1, oW1, oW1T,
                                                           0, CC, EE, CC, EPAD);
    transpose_cast_z<<<dim3(40, 32, 1), tblk, 0, stream>>>(oW2, oW2, oW2, oW2T,
                                                           0, EE, CC, EPAD, CC);

    // ---- LN * gate -> qb (bf16) ----
    ln_gate_kernel<<<dim3(MM), blk, 0, stream>>>(out, gbuf, ln_g, ln_b, qb);

    // ---- output MLP ----
    gemm_mfma<1,-1,1,1><<<dim3(10, 64, 1), blk, 0, stream>>>(qb, oW1T, ob1, Hb,
                                                             MM, EE, CC, CC, CC, EPAD, 0, 0, 0, 0);
    gemm_mfma<0,-1,0,0><<<dim3(8, 64, 1), blk, 0, stream>>>(Hb, oW2T, ob2, out,
                                                            MM, CC, EPAD, EPAD, EPAD, CC, 0, 0, 0, 0);
}